// Round 8
// baseline (2354.791 us; speedup 1.0000x reference)
//
#include <hip/hip_runtime.h>
#include <math.h>

#define TT 1024
#define DD 1024
#define NH 16
#define NB 2
#define NL 12
#define RR 32
#define MM (NB * TT)  // 2048

typedef __attribute__((ext_vector_type(8))) short bf16x8;
typedef __attribute__((ext_vector_type(4))) float f32x4;

__device__ __forceinline__ unsigned short f2bf(float f) {
  unsigned int u = __float_as_uint(f);
  u = (u + 0x7FFFu + ((u >> 16) & 1u)) >> 16;
  return (unsigned short)u;
}
__device__ __forceinline__ float bf2f(unsigned short u) {
  return __uint_as_float((unsigned int)u << 16);
}

typedef __attribute__((address_space(1))) void gvoid;
typedef __attribute__((address_space(3))) void lvoid;
__device__ __forceinline__ void gload_lds16(const void* g, void* l) {
  __builtin_amdgcn_global_load_lds((gvoid*)g, (lvoid*)l, 16, 0, 0);
}

// ---------------------------------------------------------------- embed
__global__ __launch_bounds__(256) void embed_k(const int* __restrict__ ids,
                                               const float* __restrict__ wte,
                                               const float* __restrict__ wpe,
                                               float* __restrict__ h) {
  const int i = blockIdx.x * 256 + threadIdx.x;
  const int row = i >> 10;
  const int d = i & 1023;
  const int t = row & (TT - 1);
  const int id = ids[row];
  h[i] = wte[(size_t)id * DD + d] + wpe[(size_t)t * DD + d];
}

// ---------------------------------------------------------------- layernorm (fp32 in, bf16 out)
__global__ __launch_bounds__(256) void ln_bf_k(const float* __restrict__ x,
                                               const float* __restrict__ w,
                                               const float* __restrict__ b,
                                               unsigned short* __restrict__ out) {
  const int row = blockIdx.x;
  const float* xr = x + (size_t)row * DD;
  const float4 v = *(const float4*)(xr + threadIdx.x * 4);
  float s = v.x + v.y + v.z + v.w;
  float ss = v.x * v.x + v.y * v.y + v.z * v.z + v.w * v.w;
#pragma unroll
  for (int off = 32; off > 0; off >>= 1) {
    s += __shfl_down(s, off);
    ss += __shfl_down(ss, off);
  }
  __shared__ float rs[4], rss[4];
  const int wid = threadIdx.x >> 6;
  if ((threadIdx.x & 63) == 0) { rs[wid] = s; rss[wid] = ss; }
  __syncthreads();
  s = rs[0] + rs[1] + rs[2] + rs[3];
  ss = rss[0] + rss[1] + rss[2] + rss[3];
  const float mean = s * (1.f / DD);
  const float var = ss * (1.f / DD) - mean * mean;
  const float rstd = rsqrtf(var + 1e-5f);
  const float4 wv = *(const float4*)(w + threadIdx.x * 4);
  const float4 bv = *(const float4*)(b + threadIdx.x * 4);
  ushort4 o;
  o.x = f2bf((v.x - mean) * rstd * wv.x + bv.x);
  o.y = f2bf((v.y - mean) * rstd * wv.y + bv.y);
  o.z = f2bf((v.z - mean) * rstd * wv.z + bv.z);
  o.w = f2bf((v.w - mean) * rstd * wv.w + bv.w);
  *(ushort4*)(out + (size_t)row * DD + threadIdx.x * 4) = o;
}

// final layernorm fp32 out
__global__ __launch_bounds__(256) void ln_f_k(const float* __restrict__ x,
                                              const float* __restrict__ w,
                                              const float* __restrict__ b,
                                              float* __restrict__ out) {
  const int row = blockIdx.x;
  const float* xr = x + (size_t)row * DD;
  const float4 v = *(const float4*)(xr + threadIdx.x * 4);
  float s = v.x + v.y + v.z + v.w;
  float ss = v.x * v.x + v.y * v.y + v.z * v.z + v.w * v.w;
#pragma unroll
  for (int off = 32; off > 0; off >>= 1) {
    s += __shfl_down(s, off);
    ss += __shfl_down(ss, off);
  }
  __shared__ float rs[4], rss[4];
  const int wid = threadIdx.x >> 6;
  if ((threadIdx.x & 63) == 0) { rs[wid] = s; rss[wid] = ss; }
  __syncthreads();
  s = rs[0] + rs[1] + rs[2] + rs[3];
  ss = rss[0] + rss[1] + rss[2] + rss[3];
  const float mean = s * (1.f / DD);
  const float var = ss * (1.f / DD) - mean * mean;
  const float rstd = rsqrtf(var + 1e-5f);
  const float4 wv = *(const float4*)(w + threadIdx.x * 4);
  const float4 bv = *(const float4*)(b + threadIdx.x * 4);
  float4 o;
  o.x = (v.x - mean) * rstd * wv.x + bv.x;
  o.y = (v.y - mean) * rstd * wv.y + bv.y;
  o.z = (v.z - mean) * rstd * wv.z + bv.z;
  o.w = (v.w - mean) * rstd * wv.w + bv.w;
  *(float4*)(out + (size_t)row * DD + threadIdx.x * 4) = o;
}

// ---------------------------------------------------------------- LoRA cvt: pack all A^T and B as bf16
__global__ __launch_bounds__(256) void cvt_lora_k(
    const float* __restrict__ ala, const float* __restrict__ alb,
    const float* __restrict__ pla, const float* __restrict__ plb,
    const float* __restrict__ fla, const float* __restrict__ flb,
    const float* __restrict__ mla, const float* __restrict__ mlb,
    unsigned short* __restrict__ out) {
  const int g = blockIdx.x * 256 + threadIdx.x;  // over NL*16384*32
  const int layer = g >> 19;
  const int rem = g & 524287;
  const int row = rem >> 5;
  const int r = rem & 31;
  float v;
  if (row < 1024)       v = ala[(size_t)layer * 32 * 1024 + r * 1024 + row];
  else if (row < 4096)  v = alb[(size_t)layer * 3072 * 32 + (row - 1024) * 32 + r];
  else if (row < 5120)  v = pla[(size_t)layer * 32 * 1024 + r * 1024 + (row - 4096)];
  else if (row < 6144)  v = plb[(size_t)layer * 1024 * 32 + (row - 5120) * 32 + r];
  else if (row < 7168)  v = fla[(size_t)layer * 32 * 1024 + r * 1024 + (row - 6144)];
  else if (row < 11264) v = flb[(size_t)layer * 4096 * 32 + (row - 7168) * 32 + r];
  else if (row < 15360) v = mla[(size_t)layer * 32 * 4096 + r * 4096 + (row - 11264)];
  else                  v = mlb[(size_t)layer * 1024 * 32 + (row - 15360) * 32 + r];
  out[g] = f2bf(v);
}

// ---------------------------------------------------------------- LoRA fold v3: MFMA -> LDS -> coalesced stream
// swizzle: byte ^= ((row>>2)&3)<<5  (32B shifts -> disjoint windows for the 4 colliding lg rows)
__global__ __launch_bounds__(256) void fusew3_k(
    const float* __restrict__ aw, const float* __restrict__ pw,
    const float* __restrict__ fw, const float* __restrict__ mw,
    const unsigned short* __restrict__ lora,
    unsigned short* __restrict__ oq, unsigned short* __restrict__ op_,
    unsigned short* __restrict__ of, unsigned short* __restrict__ om) {
  const int g = blockIdx.x;
  const int layer = g / 768;
  const int lid = g - layer * 768;
  const unsigned short* Lb = lora + (size_t)layer * 16384 * 32;
  const float* W;
  unsigned short* out;
  const unsigned short *Bl, *Al;
  int K, n0, kblk;
  if (lid < 192) {
    W = aw + (size_t)layer * 3 * DD * DD; out = oq + (size_t)layer * 3 * DD * DD;
    Bl = Lb + 1024 * 32; Al = Lb;
    K = DD; n0 = (lid >> 2) * 64; kblk = (lid & 3) * 256;
  } else if (lid < 256) {
    const int t = lid - 192;
    W = pw + (size_t)layer * DD * DD; out = op_ + (size_t)layer * DD * DD;
    Bl = Lb + 5120 * 32; Al = Lb + 4096 * 32;
    K = DD; n0 = (t >> 2) * 64; kblk = (t & 3) * 256;
  } else if (lid < 512) {
    const int t = lid - 256;
    W = fw + (size_t)layer * 4 * DD * DD; out = of + (size_t)layer * 4 * DD * DD;
    Bl = Lb + 7168 * 32; Al = Lb + 6144 * 32;
    K = DD; n0 = (t >> 2) * 64; kblk = (t & 3) * 256;
  } else {
    const int t = lid - 512;
    W = mw + (size_t)layer * DD * 4 * DD; out = om + (size_t)layer * DD * 4 * DD;
    Bl = Lb + 15360 * 32; Al = Lb + 11264 * 32;
    K = 4 * DD; n0 = (t >> 4) * 64; kblk = (t & 15) * 256;
  }
  __shared__ unsigned short dl[64 * 256];  // 32KB
  const int tid = threadIdx.x;
  const int w = tid >> 6, l = tid & 63;
  const int lr16 = l & 15, lg = l >> 4;
  // phase 1: MFMA delta -> swizzled LDS
  const bf16x8 bfrag = *(const bf16x8*)(Bl + (size_t)(n0 + w * 16 + lr16) * 32 + lg * 8);
#pragma unroll
  for (int kc = 0; kc < 16; ++kc) {
    const bf16x8 afr = *(const bf16x8*)(Al + (size_t)(kblk + kc * 16 + lr16) * 32 + lg * 8);
    f32x4 acc = {};
    acc = __builtin_amdgcn_mfma_f32_16x16x32_bf16(bfrag, afr, acc, 0, 0, 0);
#pragma unroll
    for (int rr = 0; rr < 4; ++rr) {
      const int row = w * 16 + lg * 4 + rr;
      const unsigned int byte = ((unsigned)(row * 512 + (kc * 16 + lr16) * 2)) ^
                                (((unsigned)(row >> 2) & 3u) << 5);
      *(unsigned short*)((char*)dl + byte) = f2bf(2.f * acc[rr]);
    }
  }
  __syncthreads();
  // phase 2: coalesced stream W + delta -> out
#pragma unroll
  for (int it = 0; it < 16; ++it) {
    const int flat = it * 1024 + tid * 4;  // over 64*256
    const int row = flat >> 8;
    const int k = flat & 255;
    const float4 wv = *(const float4*)(W + (size_t)(n0 + row) * K + kblk + k);
    const unsigned int byte = ((unsigned)(row * 512 + k * 2)) ^
                              (((unsigned)(row >> 2) & 3u) << 5);
    const ushort4 dv = *(const ushort4*)((const char*)dl + byte);
    ushort4 o;
    o.x = f2bf(wv.x + bf2f(dv.x));
    o.y = f2bf(wv.y + bf2f(dv.y));
    o.z = f2bf(wv.z + bf2f(dv.z));
    o.w = f2bf(wv.w + bf2f(dv.w));
    *(ushort4*)(out + (size_t)(n0 + row) * K + kblk + k) = o;
  }
}

// ---------------------------------------------------------------- unified bf16 MFMA GEMM
// BK=64, 4 waves (2x2), XOR-swizzled LDS, TRUE double-buffer (stage k+1 || compute k).
// MODE 1: fp32 out = acc+bias+res; MODE 2: gelu->bf16; MODE 3: qkv split.
template <int BMt, int BNt, int MODE>
__global__ __launch_bounds__(256) void gemm_t(const unsigned short* __restrict__ A,
                                              const unsigned short* __restrict__ Wt,
                                              const float* __restrict__ bias,
                                              const float* __restrict__ res,
                                              float* __restrict__ Cf,
                                              unsigned short* __restrict__ Cb,
                                              unsigned short* __restrict__ vt,
                                              int M, int N, int K) {
  constexpr int BKt = 64;
  constexpr int MI2 = BMt / 32, NJ2 = BNt / 32;
  constexpr int CA = BMt / 32;
  constexpr int CB = BNt / 32;
  __shared__ unsigned short As[2][BMt * BKt];
  __shared__ unsigned short Bs[2][BNt * BKt];
  const int tid = threadIdx.x;
  const int w = tid >> 6, l = tid & 63;
  const int bm = blockIdx.y * BMt, bn = blockIdx.x * BNt;
  const int wr = w >> 1, wc = w & 1;
  const int lr16 = l & 15, lg = l >> 4, l7 = l & 7;
  const int crow = l >> 3;
  const int csrc = ((l & 7) ^ (crow & 7)) * 8;

  auto stage = [&](int buf, int k0) {
#pragma unroll
    for (int i = 0; i < CA; ++i) {
      const int ch = w * CA + i;
      gload_lds16(A + (size_t)(bm + ch * 8 + crow) * K + k0 + csrc,
                  (char*)&As[buf][0] + ch * 1024);
    }
#pragma unroll
    for (int i = 0; i < CB; ++i) {
      const int ch = w * CB + i;
      gload_lds16(Wt + (size_t)(bn + ch * 8 + crow) * K + k0 + csrc,
                  (char*)&Bs[buf][0] + ch * 1024);
    }
  };

  f32x4 acc[MI2][NJ2] = {};
  stage(0, 0);
  int cur = 0;
  for (int k0 = 0; k0 < K; k0 += BKt) {
    __syncthreads();  // drains prior stage (vmcnt) + prior reads (lgkmcnt)
    if (k0 + BKt < K) stage(cur ^ 1, k0 + BKt);
    bf16x8 af[MI2][2], bfr[NJ2][2];
#pragma unroll
    for (int mi = 0; mi < MI2; ++mi)
#pragma unroll
      for (int kk = 0; kk < 2; ++kk)
        af[mi][kk] = *(const bf16x8*)((const char*)&As[cur][0] +
            (wr * (BMt / 2) + mi * 16 + lr16) * 128 + (((kk * 4 + lg) ^ l7) * 16));
#pragma unroll
    for (int nj = 0; nj < NJ2; ++nj)
#pragma unroll
      for (int kk = 0; kk < 2; ++kk)
        bfr[nj][kk] = *(const bf16x8*)((const char*)&Bs[cur][0] +
            (wc * (BNt / 2) + nj * 16 + lr16) * 128 + (((kk * 4 + lg) ^ l7) * 16));
#pragma unroll
    for (int kk = 0; kk < 2; ++kk)
#pragma unroll
      for (int mi = 0; mi < MI2; ++mi)
#pragma unroll
        for (int nj = 0; nj < NJ2; ++nj)
          acc[mi][nj] = __builtin_amdgcn_mfma_f32_16x16x32_bf16(
              af[mi][kk], bfr[nj][kk], acc[mi][nj], 0, 0, 0);
    cur ^= 1;
  }
  const int cr = lg * 4;
  const int cc = lr16;
#pragma unroll
  for (int mi = 0; mi < MI2; ++mi) {
    const int gr0 = bm + wr * (BMt / 2) + mi * 16 + cr;
#pragma unroll
    for (int nj = 0; nj < NJ2; ++nj) {
      const int gc = bn + wc * (BNt / 2) + nj * 16 + cc;
      const float bv = bias[gc];
      if (MODE == 3) {
        if (gc < 2048) {
#pragma unroll
          for (int r = 0; r < 4; ++r)
            Cb[(size_t)(gr0 + r) * 2048 + gc] = f2bf(acc[mi][nj][r] + bv);
        } else {
          const int hv = gc - 2048;
          const int b_ = gr0 >> 10, t0 = gr0 & 1023;
          ushort4 u;
          u.x = f2bf(acc[mi][nj][0] + bv); u.y = f2bf(acc[mi][nj][1] + bv);
          u.z = f2bf(acc[mi][nj][2] + bv); u.w = f2bf(acc[mi][nj][3] + bv);
          *(ushort4*)(vt + ((size_t)(b_ * 1024 + hv)) * 1024 + t0) = u;
        }
      } else if (MODE == 1) {
#pragma unroll
        for (int r = 0; r < 4; ++r) {
          const size_t idx = (size_t)(gr0 + r) * N + gc;
          Cf[idx] = acc[mi][nj][r] + bv + res[idx];
        }
      } else {  // MODE 2
#pragma unroll
        for (int r = 0; r < 4; ++r) {
          float v = acc[mi][nj][r] + bv;
          v = 0.5f * v * (1.f + erff(v * 0.70710678118654752f));
          Cb[(size_t)(gr0 + r) * N + gc] = f2bf(v);
        }
      }
    }
  }
}

// ---------------------------------------------------------------- MFMA flash attention
#define SM_SCALE_LOG2E 0.18033688011112042f  // log2(e)/8
__global__ __launch_bounds__(256) void attn3_k(const unsigned short* __restrict__ qk,
                                               const unsigned short* __restrict__ vt,
                                               unsigned short* __restrict__ out) {
  const int qt = blockIdx.x;
  const int bh = blockIdx.y;
  const int b = bh >> 4, hh = bh & 15;
  const int tid = threadIdx.x;
  const int w = tid >> 6, l = tid & 63;
  const int lg = l >> 4;
  const int lr = l & 15;

  __shared__ unsigned short Kt[2][64 * 64];
  __shared__ unsigned short Vb[2][64 * 64];
  __shared__ unsigned short Pb[4][16 * 64];

  bf16x8 qf[2];
  {
    const unsigned short* qp =
        qk + ((size_t)(b * TT + qt * 64 + w * 16 + lr)) * 2048 + hh * 64 + lg * 8;
    qf[0] = *(const bf16x8*)(qp);
    qf[1] = *(const bf16x8*)(qp + 32);
  }
  f32x4 oacc[4] = {};
  float mrow[4] = {-1e30f, -1e30f, -1e30f, -1e30f};
  float lrow[4] = {0.f, 0.f, 0.f, 0.f};

  auto stage = [&](int buf, int kt) {
#pragma unroll
    for (int oo = 0; oo < 2; ++oo) {
      const int o = w + oo * 4;
      const int row = o * 8 + (l >> 3);
      const int sc = ((l & 7) ^ (l >> 3)) * 8;
      const unsigned short* ks =
          qk + ((size_t)(b * TT + kt * 64 + row)) * 2048 + 1024 + hh * 64 + sc;
      gload_lds16(ks, (char*)&Kt[buf][0] + o * 1024);
      const unsigned short* vs =
          vt + ((size_t)(bh * 64 + row)) * 1024 + kt * 64 + sc;
      gload_lds16(vs, (char*)&Vb[buf][0] + o * 1024);
    }
  };

  stage(0, 0);
  int cur = 0;
  unsigned short* Pw = &Pb[w][0];
  const int qlocal = w * 16 + lg * 4;

  for (int kt = 0; kt <= qt; ++kt) {
    __syncthreads();
    if (kt < qt) stage(cur ^ 1, kt + 1);
    const unsigned short* Kb_ = &Kt[cur][0];
    const unsigned short* Vb_ = &Vb[cur][0];
    const int effc = lr & 7;

    f32x4 s[4];
#pragma unroll
    for (int j = 0; j < 4; ++j) {
      f32x4 sj = {};
#pragma unroll
      for (int ks = 0; ks < 2; ++ks) {
        const bf16x8 kf = *(const bf16x8*)((const char*)Kb_ + (j * 16 + lr) * 128 +
                                           (((ks * 4 + lg) ^ effc) * 16));
        sj = __builtin_amdgcn_mfma_f32_16x16x32_bf16(qf[ks], kf, sj, 0, 0, 0);
      }
      s[j] = sj;
    }

    const bool last = (kt == qt);
    float tv[4][4];
#pragma unroll
    for (int j = 0; j < 4; ++j)
#pragma unroll
      for (int r = 0; r < 4; ++r) {
        float v = s[j][r] * SM_SCALE_LOG2E;
        if (last && (j * 16 + lr > qlocal + r)) v = -1e30f;
        tv[j][r] = v;
      }
    float corr[4];
#pragma unroll
    for (int r = 0; r < 4; ++r) {
      float mx = fmaxf(fmaxf(tv[0][r], tv[1][r]), fmaxf(tv[2][r], tv[3][r]));
      mx = fmaxf(mx, __shfl_xor(mx, 1));
      mx = fmaxf(mx, __shfl_xor(mx, 2));
      mx = fmaxf(mx, __shfl_xor(mx, 4));
      mx = fmaxf(mx, __shfl_xor(mx, 8));
      const float mn = fmaxf(mrow[r], mx);
      corr[r] = exp2f(mrow[r] - mn);
      mrow[r] = mn;
      lrow[r] *= corr[r];
    }
#pragma unroll
    for (int dt = 0; dt < 4; ++dt) {
      oacc[dt][0] *= corr[0]; oacc[dt][1] *= corr[1];
      oacc[dt][2] *= corr[2]; oacc[dt][3] *= corr[3];
    }
#pragma unroll
    for (int j = 0; j < 4; ++j)
#pragma unroll
      for (int r = 0; r < 4; ++r) {
        const float p = exp2f(tv[j][r] - mrow[r]);
        lrow[r] += p;
        const int q = lg * 4 + r;
        const int kv = j * 16 + lr;
        *(unsigned short*)((char*)Pw + q * 128 + ((kv * 2) ^ ((q & 7) << 4))) = f2bf(p);
      }
    asm volatile("s_waitcnt lgkmcnt(0)" ::: "memory");
    __builtin_amdgcn_sched_barrier(0);

#pragma unroll
    for (int ks = 0; ks < 2; ++ks) {
      const bf16x8 pf = *(const bf16x8*)((const char*)Pw + lr * 128 +
                                         (((ks * 4 + lg) ^ effc) * 16));
#pragma unroll
      for (int dt = 0; dt < 4; ++dt) {
        const bf16x8 vf = *(const bf16x8*)((const char*)Vb_ + (dt * 16 + lr) * 128 +
                                           (((ks * 4 + lg) ^ effc) * 16));
        oacc[dt] = __builtin_amdgcn_mfma_f32_16x16x32_bf16(pf, vf, oacc[dt], 0, 0, 0);
      }
    }
    cur ^= 1;
  }

#pragma unroll
  for (int r = 0; r < 4; ++r) {
    float lv = lrow[r];
    lv += __shfl_xor(lv, 1);
    lv += __shfl_xor(lv, 2);
    lv += __shfl_xor(lv, 4);
    lv += __shfl_xor(lv, 8);
    lrow[r] = 1.f / lv;
  }
  unsigned short* ob = out + ((size_t)(b * TT + qt * 64 + w * 16 + lg * 4)) * 1024 + hh * 64 + lr;
#pragma unroll
  for (int r = 0; r < 4; ++r)
#pragma unroll
    for (int dt = 0; dt < 4; ++dt)
      ob[(size_t)r * 1024 + dt * 16] = f2bf(oacc[dt][r] * lrow[r]);
}

// ---------------------------------------------------------------- host
extern "C" void kernel_launch(void* const* d_in, const int* in_sizes, int n_in,
                              void* d_out, int out_size, void* d_ws, size_t ws_size,
                              hipStream_t stream) {
  (void)in_sizes; (void)n_in; (void)out_size; (void)ws_size;
  const int* ids = (const int*)d_in[0];
  const float* wte = (const float*)d_in[1];
  const float* wpe = (const float*)d_in[2];
  const float* ln1w = (const float*)d_in[3];
  const float* ln1b = (const float*)d_in[4];
  const float* attnw = (const float*)d_in[5];
  const float* attnb = (const float*)d_in[6];
  const float* attnla = (const float*)d_in[7];
  const float* attnlb = (const float*)d_in[8];
  const float* projw = (const float*)d_in[9];
  const float* projb = (const float*)d_in[10];
  const float* projla = (const float*)d_in[11];
  const float* projlb = (const float*)d_in[12];
  const float* ln2w = (const float*)d_in[13];
  const float* ln2b = (const float*)d_in[14];
  const float* fcw = (const float*)d_in[15];
  const float* fcb = (const float*)d_in[16];
  const float* fcla = (const float*)d_in[17];
  const float* fclb = (const float*)d_in[18];
  const float* mpw = (const float*)d_in[19];
  const float* mpb = (const float*)d_in[20];
  const float* mpla = (const float*)d_in[21];
  const float* mplb = (const float*)d_in[22];
  const float* lnfw = (const float*)d_in[23];
  const float* lnfb = (const float*)d_in[24];

  char* ws = (char*)d_ws;
  float* h = (float*)ws;                        ws += (size_t)MM * DD * 4;       // 8MB
  unsigned short* x = (unsigned short*)ws;      ws += (size_t)MM * DD * 2;       // 4MB
  unsigned short* qkb = (unsigned short*)ws;    ws += (size_t)MM * 2 * DD * 2;   // 8MB
  unsigned short* vtb = (unsigned short*)ws;    ws += (size_t)MM * DD * 2;       // 4MB
  unsigned short* ho = (unsigned short*)ws;     ws += (size_t)MM * DD * 2;       // 4MB
  unsigned short* hm = (unsigned short*)ws;     ws += (size_t)MM * 4 * DD * 2;   // 16MB
  unsigned short* wqkvA = (unsigned short*)ws;  ws += (size_t)NL * 3 * DD * DD * 2;  // 72MB
  unsigned short* wprojA = (unsigned short*)ws; ws += (size_t)NL * DD * DD * 2;      // 24MB
  unsigned short* wfcA = (unsigned short*)ws;   ws += (size_t)NL * 4 * DD * DD * 2;  // 96MB
  unsigned short* wmpA = (unsigned short*)ws;   ws += (size_t)NL * DD * 4 * DD * 2;  // 96MB
  unsigned short* loraP = (unsigned short*)ws;  ws += (size_t)NL * 16384 * 32 * 2;   // 12.6MB

  hipLaunchKernelGGL(embed_k, dim3(MM * DD / 256), dim3(256), 0, stream, ids, wte, wpe, h);

  hipLaunchKernelGGL(cvt_lora_k, dim3(NL * 16384 * 32 / 256), dim3(256), 0, stream,
                     attnla, attnlb, projla, projlb, fcla, fclb, mpla, mplb, loraP);
  hipLaunchKernelGGL(fusew3_k, dim3(NL * 768), dim3(256), 0, stream,
                     attnw, projw, fcw, mpw, loraP, wqkvA, wprojA, wfcA, wmpA);

  for (int l = 0; l < NL; ++l) {
    const float* ab = attnb + (size_t)l * 3 * DD;
    const float* pb = projb + (size_t)l * DD;
    const float* fb = fcb + (size_t)l * 4 * DD;
    const float* mb = mpb + (size_t)l * DD;
    const unsigned short* wqkv = wqkvA + (size_t)l * 3 * DD * DD;
    const unsigned short* wproj = wprojA + (size_t)l * DD * DD;
    const unsigned short* wfc = wfcA + (size_t)l * 4 * DD * DD;
    const unsigned short* wmp = wmpA + (size_t)l * DD * 4 * DD;

    // x = LN1(h)
    hipLaunchKernelGGL(ln_bf_k, dim3(MM), dim3(256), 0, stream, h,
                       ln1w + (size_t)l * DD, ln1b + (size_t)l * DD, x);
    // qkv = x @ wqkv^T + ab -> qkb (Q,K) + vtb (V transposed)
    hipLaunchKernelGGL((gemm_t<128, 64, 3>), dim3(3 * DD / 64, MM / 128), dim3(256), 0,
                       stream, x, wqkv, ab, (const float*)nullptr, (float*)nullptr,
                       qkb, vtb, MM, 3 * DD, DD);
    // o = attention
    hipLaunchKernelGGL(attn3_k, dim3(TT / 64, NB * NH), dim3(256), 0, stream, qkb, vtb, ho);
    // h = h + o @ wproj^T + pb
    hipLaunchKernelGGL((gemm_t<64, 64, 1>), dim3(DD / 64, MM / 64), dim3(256), 0,
                       stream, ho, wproj, pb, h, h, (unsigned short*)nullptr,
                       (unsigned short*)nullptr, MM, DD, DD);
    // x = LN2(h)
    hipLaunchKernelGGL(ln_bf_k, dim3(MM), dim3(256), 0, stream, h,
                       ln2w + (size_t)l * DD, ln2b + (size_t)l * DD, x);
    // m = gelu(x @ wfc^T + fb)
    hipLaunchKernelGGL((gemm_t<128, 64, 2>), dim3(4 * DD / 64, MM / 128), dim3(256), 0,
                       stream, x, wfc, fb, (const float*)nullptr, (float*)nullptr, hm,
                       (unsigned short*)nullptr, MM, 4 * DD, DD);
    // h = h + m @ wmp^T + mb
    hipLaunchKernelGGL((gemm_t<64, 64, 1>), dim3(DD / 64, MM / 64), dim3(256), 0,
                       stream, hm, wmp, mb, h, h, (unsigned short*)nullptr,
                       (unsigned short*)nullptr, MM, DD, 4 * DD);
  }

  hipLaunchKernelGGL(ln_f_k, dim3(MM), dim3(256), 0, stream, h, lnfw, lnfb, (float*)d_out);
}

// Round 9
// 2280.960 us; speedup vs baseline: 1.0324x; 1.0324x over previous
//
#include <hip/hip_runtime.h>
#include <math.h>

#define TT 1024
#define DD 1024
#define NH 16
#define NB 2
#define NL 12
#define RR 32
#define MM (NB * TT)  // 2048

typedef __attribute__((ext_vector_type(8))) short bf16x8;
typedef __attribute__((ext_vector_type(4))) float f32x4;

__device__ __forceinline__ unsigned short f2bf(float f) {
  unsigned int u = __float_as_uint(f);
  u = (u + 0x7FFFu + ((u >> 16) & 1u)) >> 16;
  return (unsigned short)u;
}
__device__ __forceinline__ float bf2f(unsigned short u) {
  return __uint_as_float((unsigned int)u << 16);
}

typedef __attribute__((address_space(1))) void gvoid;
typedef __attribute__((address_space(3))) void lvoid;
__device__ __forceinline__ void gload_lds16(const void* g, void* l) {
  __builtin_amdgcn_global_load_lds((gvoid*)g, (lvoid*)l, 16, 0, 0);
}

// ---------------------------------------------------------------- embed
__global__ __launch_bounds__(256) void embed_k(const int* __restrict__ ids,
                                               const float* __restrict__ wte,
                                               const float* __restrict__ wpe,
                                               float* __restrict__ h) {
  const int i = blockIdx.x * 256 + threadIdx.x;
  const int row = i >> 10;
  const int d = i & 1023;
  const int t = row & (TT - 1);
  const int id = ids[row];
  h[i] = wte[(size_t)id * DD + d] + wpe[(size_t)t * DD + d];
}

// ---------------------------------------------------------------- layernorm (fp32 in, bf16 out)
__global__ __launch_bounds__(256) void ln_bf_k(const float* __restrict__ x,
                                               const float* __restrict__ w,
                                               const float* __restrict__ b,
                                               unsigned short* __restrict__ out) {
  const int row = blockIdx.x;
  const float* xr = x + (size_t)row * DD;
  const float4 v = *(const float4*)(xr + threadIdx.x * 4);
  float s = v.x + v.y + v.z + v.w;
  float ss = v.x * v.x + v.y * v.y + v.z * v.z + v.w * v.w;
#pragma unroll
  for (int off = 32; off > 0; off >>= 1) {
    s += __shfl_down(s, off);
    ss += __shfl_down(ss, off);
  }
  __shared__ float rs[4], rss[4];
  const int wid = threadIdx.x >> 6;
  if ((threadIdx.x & 63) == 0) { rs[wid] = s; rss[wid] = ss; }
  __syncthreads();
  s = rs[0] + rs[1] + rs[2] + rs[3];
  ss = rss[0] + rss[1] + rss[2] + rss[3];
  const float mean = s * (1.f / DD);
  const float var = ss * (1.f / DD) - mean * mean;
  const float rstd = rsqrtf(var + 1e-5f);
  const float4 wv = *(const float4*)(w + threadIdx.x * 4);
  const float4 bv = *(const float4*)(b + threadIdx.x * 4);
  ushort4 o;
  o.x = f2bf((v.x - mean) * rstd * wv.x + bv.x);
  o.y = f2bf((v.y - mean) * rstd * wv.y + bv.y);
  o.z = f2bf((v.z - mean) * rstd * wv.z + bv.z);
  o.w = f2bf((v.w - mean) * rstd * wv.w + bv.w);
  *(ushort4*)(out + (size_t)row * DD + threadIdx.x * 4) = o;
}

// final layernorm fp32 out
__global__ __launch_bounds__(256) void ln_f_k(const float* __restrict__ x,
                                              const float* __restrict__ w,
                                              const float* __restrict__ b,
                                              float* __restrict__ out) {
  const int row = blockIdx.x;
  const float* xr = x + (size_t)row * DD;
  const float4 v = *(const float4*)(xr + threadIdx.x * 4);
  float s = v.x + v.y + v.z + v.w;
  float ss = v.x * v.x + v.y * v.y + v.z * v.z + v.w * v.w;
#pragma unroll
  for (int off = 32; off > 0; off >>= 1) {
    s += __shfl_down(s, off);
    ss += __shfl_down(ss, off);
  }
  __shared__ float rs[4], rss[4];
  const int wid = threadIdx.x >> 6;
  if ((threadIdx.x & 63) == 0) { rs[wid] = s; rss[wid] = ss; }
  __syncthreads();
  s = rs[0] + rs[1] + rs[2] + rs[3];
  ss = rss[0] + rss[1] + rss[2] + rss[3];
  const float mean = s * (1.f / DD);
  const float var = ss * (1.f / DD) - mean * mean;
  const float rstd = rsqrtf(var + 1e-5f);
  const float4 wv = *(const float4*)(w + threadIdx.x * 4);
  const float4 bv = *(const float4*)(b + threadIdx.x * 4);
  float4 o;
  o.x = (v.x - mean) * rstd * wv.x + bv.x;
  o.y = (v.y - mean) * rstd * wv.y + bv.y;
  o.z = (v.z - mean) * rstd * wv.z + bv.z;
  o.w = (v.w - mean) * rstd * wv.w + bv.w;
  *(float4*)(out + (size_t)row * DD + threadIdx.x * 4) = o;
}

// ---------------------------------------------------------------- LoRA cvt: pack all A^T and B as bf16
__global__ __launch_bounds__(256) void cvt_lora_k(
    const float* __restrict__ ala, const float* __restrict__ alb,
    const float* __restrict__ pla, const float* __restrict__ plb,
    const float* __restrict__ fla, const float* __restrict__ flb,
    const float* __restrict__ mla, const float* __restrict__ mlb,
    unsigned short* __restrict__ out) {
  const int g = blockIdx.x * 256 + threadIdx.x;  // over NL*16384*32
  const int layer = g >> 19;
  const int rem = g & 524287;
  const int row = rem >> 5;
  const int r = rem & 31;
  float v;
  if (row < 1024)       v = ala[(size_t)layer * 32 * 1024 + r * 1024 + row];
  else if (row < 4096)  v = alb[(size_t)layer * 3072 * 32 + (row - 1024) * 32 + r];
  else if (row < 5120)  v = pla[(size_t)layer * 32 * 1024 + r * 1024 + (row - 4096)];
  else if (row < 6144)  v = plb[(size_t)layer * 1024 * 32 + (row - 5120) * 32 + r];
  else if (row < 7168)  v = fla[(size_t)layer * 32 * 1024 + r * 1024 + (row - 6144)];
  else if (row < 11264) v = flb[(size_t)layer * 4096 * 32 + (row - 7168) * 32 + r];
  else if (row < 15360) v = mla[(size_t)layer * 32 * 4096 + r * 4096 + (row - 11264)];
  else                  v = mlb[(size_t)layer * 1024 * 32 + (row - 15360) * 32 + r];
  out[g] = f2bf(v);
}

// ---------------------------------------------------------------- LoRA fold v4
// out = bf16(W + 2*B@A). Tile: 64 n x 128 k. LDS 16KB.
// Phase 1: swapped MFMA  mfma(A_loraT, B) -> lane holds 4 consecutive k for one n
//          -> ds_write_b64 (uniform banks via ^(n&3)<<5).
// Phase 2: 8-deep W float4 prefetch, then add+cvt+ushort4 store (coalesced).
__global__ __launch_bounds__(256) void fusew4_k(
    const float* __restrict__ aw, const float* __restrict__ pw,
    const float* __restrict__ fw, const float* __restrict__ mw,
    const unsigned short* __restrict__ lora,
    unsigned short* __restrict__ oq, unsigned short* __restrict__ op_,
    unsigned short* __restrict__ of, unsigned short* __restrict__ om) {
  const int g = blockIdx.x;
  const int layer = g / 1536;
  const int lid = g - layer * 1536;
  const unsigned short* Lb = lora + (size_t)layer * 16384 * 32;
  const float* W;
  unsigned short* out;
  const unsigned short *Bl, *Al;
  int K, n0, kblk;
  if (lid < 384) {  // qkv: 48 n-tiles x 8 k-tiles
    W = aw + (size_t)layer * 3 * DD * DD; out = oq + (size_t)layer * 3 * DD * DD;
    Bl = Lb + 1024 * 32; Al = Lb;
    K = DD; n0 = (lid >> 3) * 64; kblk = (lid & 7) * 128;
  } else if (lid < 512) {  // proj: 16 x 8
    const int t = lid - 384;
    W = pw + (size_t)layer * DD * DD; out = op_ + (size_t)layer * DD * DD;
    Bl = Lb + 5120 * 32; Al = Lb + 4096 * 32;
    K = DD; n0 = (t >> 3) * 64; kblk = (t & 7) * 128;
  } else if (lid < 1024) {  // fc: 64 x 8
    const int t = lid - 512;
    W = fw + (size_t)layer * 4 * DD * DD; out = of + (size_t)layer * 4 * DD * DD;
    Bl = Lb + 7168 * 32; Al = Lb + 6144 * 32;
    K = DD; n0 = (t >> 3) * 64; kblk = (t & 7) * 128;
  } else {  // mp: 16 x 32
    const int t = lid - 1024;
    W = mw + (size_t)layer * DD * 4 * DD; out = om + (size_t)layer * DD * 4 * DD;
    Bl = Lb + 15360 * 32; Al = Lb + 11264 * 32;
    K = 4 * DD; n0 = (t >> 5) * 64; kblk = (t & 31) * 128;
  }
  __shared__ unsigned short dl[64 * 128];  // 16KB: [n][k], byte ^= (n&3)<<5
  const int tid = threadIdx.x;
  const int w = tid >> 6, l = tid & 63;
  const int lr16 = l & 15, lg = l >> 4;
  // phase 1: delta = (B@A)[n][k] via swapped MFMA
  const int nloc = w * 16 + lr16;
  const bf16x8 bfrag = *(const bf16x8*)(Bl + (size_t)(n0 + nloc) * 32 + lg * 8);
#pragma unroll
  for (int kc = 0; kc < 8; ++kc) {
    const bf16x8 afr = *(const bf16x8*)(Al + (size_t)(kblk + kc * 16 + lr16) * 32 + lg * 8);
    f32x4 acc = {};
    acc = __builtin_amdgcn_mfma_f32_16x16x32_bf16(afr, bfrag, acc, 0, 0, 0);
    // lane holds delta[n0+w*16+lr16][kblk + kc*16 + lg*4 + rr], rr=0..3
    ushort4 dv;
    dv.x = f2bf(2.f * acc[0]); dv.y = f2bf(2.f * acc[1]);
    dv.z = f2bf(2.f * acc[2]); dv.w = f2bf(2.f * acc[3]);
    const unsigned int byte = ((unsigned)(nloc * 256 + kc * 32 + lg * 8)) ^
                              (((unsigned)nloc & 3u) << 5);
    *(ushort4*)((char*)dl + byte) = dv;
  }
  __syncthreads();
  // phase 2: prefetch 8 W float4, then combine + store
  float4 wv[8];
#pragma unroll
  for (int it = 0; it < 8; ++it) {
    const int flat = it * 1024 + tid * 4;  // over 64*128
    const int row = flat >> 7;
    const int k = flat & 127;
    wv[it] = *(const float4*)(W + (size_t)(n0 + row) * K + kblk + k);
  }
#pragma unroll
  for (int it = 0; it < 8; ++it) {
    const int flat = it * 1024 + tid * 4;
    const int row = flat >> 7;
    const int k = flat & 127;
    const unsigned int byte = ((unsigned)(row * 256 + k * 2)) ^
                              (((unsigned)row & 3u) << 5);
    const ushort4 dv = *(const ushort4*)((const char*)dl + byte);
    ushort4 o;
    o.x = f2bf(wv[it].x + bf2f(dv.x));
    o.y = f2bf(wv[it].y + bf2f(dv.y));
    o.z = f2bf(wv[it].z + bf2f(dv.z));
    o.w = f2bf(wv[it].w + bf2f(dv.w));
    *(ushort4*)(out + (size_t)(n0 + row) * K + kblk + k) = o;
  }
}

// ---------------------------------------------------------------- unified bf16 MFMA GEMM
// Single-buffer (R7 proven), BK=64, 4 waves (2x2), XOR-swizzled LDS, XCD chunk swizzle.
// MODE 1: fp32 out = acc+bias+res; MODE 2: gelu->bf16; MODE 3: qkv split.
template <int BMt, int BNt, int MODE>
__global__ __launch_bounds__(256) void gemm_t(const unsigned short* __restrict__ A,
                                              const unsigned short* __restrict__ Wt,
                                              const float* __restrict__ bias,
                                              const float* __restrict__ res,
                                              float* __restrict__ Cf,
                                              unsigned short* __restrict__ Cb,
                                              unsigned short* __restrict__ vt,
                                              int M, int N, int K) {
  constexpr int BKt = 64;
  constexpr int MI2 = BMt / 32, NJ2 = BNt / 32;
  constexpr int CA = BMt / 32;
  constexpr int CB = BNt / 32;
  __shared__ unsigned short As[BMt * BKt];
  __shared__ unsigned short Bs[BNt * BKt];
  const int tid = threadIdx.x;
  const int w = tid >> 6, l = tid & 63;
  // XCD-aware chunk swizzle (all grids %8 == 0): same-bm blocks cluster per XCD
  const int gx = gridDim.x;
  const int bid = blockIdx.y * gx + blockIdx.x;
  const int cpx = (gx * gridDim.y) >> 3;
  const int logical = (bid & 7) * cpx + (bid >> 3);
  const int bm = (logical / gx) * BMt, bn = (logical % gx) * BNt;
  const int wr = w >> 1, wc = w & 1;
  const int lr16 = l & 15, lg = l >> 4, l7 = l & 7;
  const int crow = l >> 3;
  const int csrc = ((l & 7) ^ (crow & 7)) * 8;
  f32x4 acc[MI2][NJ2] = {};
  for (int k0 = 0; k0 < K; k0 += BKt) {
    __syncthreads();
#pragma unroll
    for (int i = 0; i < CA; ++i) {
      const int ch = w * CA + i;
      gload_lds16(A + (size_t)(bm + ch * 8 + crow) * K + k0 + csrc,
                  (char*)As + ch * 1024);
    }
#pragma unroll
    for (int i = 0; i < CB; ++i) {
      const int ch = w * CB + i;
      gload_lds16(Wt + (size_t)(bn + ch * 8 + crow) * K + k0 + csrc,
                  (char*)Bs + ch * 1024);
    }
    __syncthreads();
    bf16x8 af[MI2][2], bfr[NJ2][2];
#pragma unroll
    for (int mi = 0; mi < MI2; ++mi)
#pragma unroll
      for (int kk = 0; kk < 2; ++kk)
        af[mi][kk] = *(const bf16x8*)((const char*)As +
            (wr * (BMt / 2) + mi * 16 + lr16) * 128 + (((kk * 4 + lg) ^ l7) * 16));
#pragma unroll
    for (int nj = 0; nj < NJ2; ++nj)
#pragma unroll
      for (int kk = 0; kk < 2; ++kk)
        bfr[nj][kk] = *(const bf16x8*)((const char*)Bs +
            (wc * (BNt / 2) + nj * 16 + lr16) * 128 + (((kk * 4 + lg) ^ l7) * 16));
#pragma unroll
    for (int kk = 0; kk < 2; ++kk)
#pragma unroll
      for (int mi = 0; mi < MI2; ++mi)
#pragma unroll
        for (int nj = 0; nj < NJ2; ++nj)
          acc[mi][nj] = __builtin_amdgcn_mfma_f32_16x16x32_bf16(
              af[mi][kk], bfr[nj][kk], acc[mi][nj], 0, 0, 0);
  }
  const int cr = lg * 4;
  const int cc = lr16;
#pragma unroll
  for (int mi = 0; mi < MI2; ++mi) {
    const int gr0 = bm + wr * (BMt / 2) + mi * 16 + cr;
#pragma unroll
    for (int nj = 0; nj < NJ2; ++nj) {
      const int gc = bn + wc * (BNt / 2) + nj * 16 + cc;
      const float bv = bias[gc];
      if (MODE == 3) {
        if (gc < 2048) {
#pragma unroll
          for (int r = 0; r < 4; ++r)
            Cb[(size_t)(gr0 + r) * 2048 + gc] = f2bf(acc[mi][nj][r] + bv);
        } else {
          const int hv = gc - 2048;
          const int b_ = gr0 >> 10, t0 = gr0 & 1023;
          ushort4 u;
          u.x = f2bf(acc[mi][nj][0] + bv); u.y = f2bf(acc[mi][nj][1] + bv);
          u.z = f2bf(acc[mi][nj][2] + bv); u.w = f2bf(acc[mi][nj][3] + bv);
          *(ushort4*)(vt + ((size_t)(b_ * 1024 + hv)) * 1024 + t0) = u;
        }
      } else if (MODE == 1) {
#pragma unroll
        for (int r = 0; r < 4; ++r) {
          const size_t idx = (size_t)(gr0 + r) * N + gc;
          Cf[idx] = acc[mi][nj][r] + bv + res[idx];
        }
      } else {  // MODE 2
#pragma unroll
        for (int r = 0; r < 4; ++r) {
          float v = acc[mi][nj][r] + bv;
          v = 0.5f * v * (1.f + erff(v * 0.70710678118654752f));
          Cb[(size_t)(gr0 + r) * N + gc] = f2bf(v);
        }
      }
    }
  }
}

// ---------------------------------------------------------------- MFMA flash attention
#define SM_SCALE_LOG2E 0.18033688011112042f  // log2(e)/8
__global__ __launch_bounds__(256) void attn3_k(const unsigned short* __restrict__ qk,
                                               const unsigned short* __restrict__ vt,
                                               unsigned short* __restrict__ out) {
  const int qt = 15 - blockIdx.x;  // heavy tiles dispatch first
  const int bh = blockIdx.y;
  const int b = bh >> 4, hh = bh & 15;
  const int tid = threadIdx.x;
  const int w = tid >> 6, l = tid & 63;
  const int lg = l >> 4;
  const int lr = l & 15;

  __shared__ unsigned short Kt[2][64 * 64];
  __shared__ unsigned short Vb[2][64 * 64];
  __shared__ unsigned short Pb[4][16 * 64];

  bf16x8 qf[2];
  {
    const unsigned short* qp =
        qk + ((size_t)(b * TT + qt * 64 + w * 16 + lr)) * 2048 + hh * 64 + lg * 8;
    qf[0] = *(const bf16x8*)(qp);
    qf[1] = *(const bf16x8*)(qp + 32);
  }
  f32x4 oacc[4] = {};
  float mrow[4] = {-1e30f, -1e30f, -1e30f, -1e30f};
  float lrow[4] = {0.f, 0.f, 0.f, 0.f};

  auto stage = [&](int buf, int kt) {
#pragma unroll
    for (int oo = 0; oo < 2; ++oo) {
      const int o = w + oo * 4;
      const int row = o * 8 + (l >> 3);
      const int sc = ((l & 7) ^ (l >> 3)) * 8;
      const unsigned short* ks =
          qk + ((size_t)(b * TT + kt * 64 + row)) * 2048 + 1024 + hh * 64 + sc;
      gload_lds16(ks, (char*)&Kt[buf][0] + o * 1024);
      const unsigned short* vs =
          vt + ((size_t)(bh * 64 + row)) * 1024 + kt * 64 + sc;
      gload_lds16(vs, (char*)&Vb[buf][0] + o * 1024);
    }
  };

  stage(0, 0);
  int cur = 0;
  unsigned short* Pw = &Pb[w][0];
  const int qlocal = w * 16 + lg * 4;

  for (int kt = 0; kt <= qt; ++kt) {
    __syncthreads();
    if (kt < qt) stage(cur ^ 1, kt + 1);
    const unsigned short* Kb_ = &Kt[cur][0];
    const unsigned short* Vb_ = &Vb[cur][0];
    const int effc = lr & 7;

    f32x4 s[4];
#pragma unroll
    for (int j = 0; j < 4; ++j) {
      f32x4 sj = {};
#pragma unroll
      for (int ks = 0; ks < 2; ++ks) {
        const bf16x8 kf = *(const bf16x8*)((const char*)Kb_ + (j * 16 + lr) * 128 +
                                           (((ks * 4 + lg) ^ effc) * 16));
        sj = __builtin_amdgcn_mfma_f32_16x16x32_bf16(qf[ks], kf, sj, 0, 0, 0);
      }
      s[j] = sj;
    }

    const bool last = (kt == qt);
    float tv[4][4];
#pragma unroll
    for (int j = 0; j < 4; ++j)
#pragma unroll
      for (int r = 0; r < 4; ++r) {
        float v = s[j][r] * SM_SCALE_LOG2E;
        if (last && (j * 16 + lr > qlocal + r)) v = -1e30f;
        tv[j][r] = v;
      }
    float corr[4];
#pragma unroll
    for (int r = 0; r < 4; ++r) {
      float mx = fmaxf(fmaxf(tv[0][r], tv[1][r]), fmaxf(tv[2][r], tv[3][r]));
      mx = fmaxf(mx, __shfl_xor(mx, 1));
      mx = fmaxf(mx, __shfl_xor(mx, 2));
      mx = fmaxf(mx, __shfl_xor(mx, 4));
      mx = fmaxf(mx, __shfl_xor(mx, 8));
      const float mn = fmaxf(mrow[r], mx);
      corr[r] = exp2f(mrow[r] - mn);
      mrow[r] = mn;
      lrow[r] *= corr[r];
    }
#pragma unroll
    for (int dt = 0; dt < 4; ++dt) {
      oacc[dt][0] *= corr[0]; oacc[dt][1] *= corr[1];
      oacc[dt][2] *= corr[2]; oacc[dt][3] *= corr[3];
    }
#pragma unroll
    for (int j = 0; j < 4; ++j)
#pragma unroll
      for (int r = 0; r < 4; ++r) {
        const float p = exp2f(tv[j][r] - mrow[r]);
        lrow[r] += p;
        const int q = lg * 4 + r;
        const int kv = j * 16 + lr;
        *(unsigned short*)((char*)Pw + q * 128 + ((kv * 2) ^ ((q & 7) << 4))) = f2bf(p);
      }
    asm volatile("s_waitcnt lgkmcnt(0)" ::: "memory");
    __builtin_amdgcn_sched_barrier(0);

#pragma unroll
    for (int ks = 0; ks < 2; ++ks) {
      const bf16x8 pf = *(const bf16x8*)((const char*)Pw + lr * 128 +
                                         (((ks * 4 + lg) ^ effc) * 16));
#pragma unroll
      for (int dt = 0; dt < 4; ++dt) {
        const bf16x8 vf = *(const bf16x8*)((const char*)Vb_ + (dt * 16 + lr) * 128 +
                                           (((ks * 4 + lg) ^ effc) * 16));
        oacc[dt] = __builtin_amdgcn_mfma_f32_16x16x32_bf16(pf, vf, oacc[dt], 0, 0, 0);
      }
    }
    cur ^= 1;
  }

#pragma unroll
  for (int r = 0; r < 4; ++r) {
    float lv = lrow[r];
    lv += __shfl_xor(lv, 1);
    lv += __shfl_xor(lv, 2);
    lv += __shfl_xor(lv, 4);
    lv += __shfl_xor(lv, 8);
    lrow[r] = 1.f / lv;
  }
  unsigned short* ob = out + ((size_t)(b * TT + qt * 64 + w * 16 + lg * 4)) * 1024 + hh * 64 + lr;
#pragma unroll
  for (int r = 0; r < 4; ++r)
#pragma unroll
    for (int dt = 0; dt < 4; ++dt)
      ob[(size_t)r * 1024 + dt * 16] = f2bf(oacc[dt][r] * lrow[r]);
}

// ---------------------------------------------------------------- host
extern "C" void kernel_launch(void* const* d_in, const int* in_sizes, int n_in,
                              void* d_out, int out_size, void* d_ws, size_t ws_size,
                              hipStream_t stream) {
  (void)in_sizes; (void)n_in; (void)out_size; (void)ws_size;
  const int* ids = (const int*)d_in[0];
  const float* wte = (const float*)d_in[1];
  const float* wpe = (const float*)d_in[2];
  const float* ln1w = (const float*)d_in[3];
  const float* ln1b = (const float*)d_in[4];
  const float* attnw = (const float*)d_in[5];
  const float* attnb = (const float*)d_in[6];
  const float* attnla = (const float*)d_in[7];
  const float* attnlb = (const float*)d_in[8];
  const float* projw = (const float*)d_in[9];
  const float* projb = (const float*)d_in[10];
  const float* projla = (const float*)d_in[11];
  const float* projlb = (const float*)d_in[12];
  const float* ln2w = (const float*)d_in[13];
  const float* ln2b = (const float*)d_in[14];
  const float* fcw = (const float*)d_in[15];
  const float* fcb = (const float*)d_in[16];
  const float* fcla = (const float*)d_in[17];
  const float* fclb = (const float*)d_in[18];
  const float* mpw = (const float*)d_in[19];
  const float* mpb = (const float*)d_in[20];
  const float* mpla = (const float*)d_in[21];
  const float* mplb = (const float*)d_in[22];
  const float* lnfw = (const float*)d_in[23];
  const float* lnfb = (const float*)d_in[24];

  char* ws = (char*)d_ws;
  float* h = (float*)ws;                        ws += (size_t)MM * DD * 4;       // 8MB
  unsigned short* x = (unsigned short*)ws;      ws += (size_t)MM * DD * 2;       // 4MB
  unsigned short* qkb = (unsigned short*)ws;    ws += (size_t)MM * 2 * DD * 2;   // 8MB
  unsigned short* vtb = (unsigned short*)ws;    ws += (size_t)MM * DD * 2;       // 4MB
  unsigned short* ho = (unsigned short*)ws;     ws += (size_t)MM * DD * 2;       // 4MB
  unsigned short* hm = (unsigned short*)ws;     ws += (size_t)MM * 4 * DD * 2;   // 16MB
  unsigned short* wqkvA = (unsigned short*)ws;  ws += (size_t)NL * 3 * DD * DD * 2;  // 72MB
  unsigned short* wprojA = (unsigned short*)ws; ws += (size_t)NL * DD * DD * 2;      // 24MB
  unsigned short* wfcA = (unsigned short*)ws;   ws += (size_t)NL * 4 * DD * DD * 2;  // 96MB
  unsigned short* wmpA = (unsigned short*)ws;   ws += (size_t)NL * DD * 4 * DD * 2;  // 96MB
  unsigned short* loraP = (unsigned short*)ws;  ws += (size_t)NL * 16384 * 32 * 2;   // 12.6MB

  hipLaunchKernelGGL(embed_k, dim3(MM * DD / 256), dim3(256), 0, stream, ids, wte, wpe, h);

  hipLaunchKernelGGL(cvt_lora_k, dim3(NL * 16384 * 32 / 256), dim3(256), 0, stream,
                     attnla, attnlb, projla, projlb, fcla, fclb, mpla, mplb, loraP);
  hipLaunchKernelGGL(fusew4_k, dim3(NL * 1536), dim3(256), 0, stream,
                     attnw, projw, fcw, mpw, loraP, wqkvA, wprojA, wfcA, wmpA);

  for (int l = 0; l < NL; ++l) {
    const float* ab = attnb + (size_t)l * 3 * DD;
    const float* pb = projb + (size_t)l * DD;
    const float* fb = fcb + (size_t)l * 4 * DD;
    const float* mb = mpb + (size_t)l * DD;
    const unsigned short* wqkv = wqkvA + (size_t)l * 3 * DD * DD;
    const unsigned short* wproj = wprojA + (size_t)l * DD * DD;
    const unsigned short* wfc = wfcA + (size_t)l * 4 * DD * DD;
    const unsigned short* wmp = wmpA + (size_t)l * DD * 4 * DD;

    // x = LN1(h)
    hipLaunchKernelGGL(ln_bf_k, dim3(MM), dim3(256), 0, stream, h,
                       ln1w + (size_t)l * DD, ln1b + (size_t)l * DD, x);
    // qkv = x @ wqkv^T + ab -> qkb (Q,K) + vtb (V transposed)
    hipLaunchKernelGGL((gemm_t<128, 64, 3>), dim3(3 * DD / 64, MM / 128), dim3(256), 0,
                       stream, x, wqkv, ab, (const float*)nullptr, (float*)nullptr,
                       qkb, vtb, MM, 3 * DD, DD);
    // o = attention
    hipLaunchKernelGGL(attn3_k, dim3(TT / 64, NB * NH), dim3(256), 0, stream, qkb, vtb, ho);
    // h = h + o @ wproj^T + pb
    hipLaunchKernelGGL((gemm_t<64, 64, 1>), dim3(DD / 64, MM / 64), dim3(256), 0,
                       stream, ho, wproj, pb, h, h, (unsigned short*)nullptr,
                       (unsigned short*)nullptr, MM, DD, DD);
    // x = LN2(h)
    hipLaunchKernelGGL(ln_bf_k, dim3(MM), dim3(256), 0, stream, h,
                       ln2w + (size_t)l * DD, ln2b + (size_t)l * DD, x);
    // m = gelu(x @ wfc^T + fb)
    hipLaunchKernelGGL((gemm_t<128, 64, 2>), dim3(4 * DD / 64, MM / 128), dim3(256), 0,
                       stream, x, wfc, fb, (const float*)nullptr, (float*)nullptr, hm,
                       (unsigned short*)nullptr, MM, 4 * DD, DD);
    // h = h + m @ wmp^T + mb
    hipLaunchKernelGGL((gemm_t<64, 64, 1>), dim3(DD / 64, MM / 64), dim3(256), 0,
                       stream, hm, wmp, mb, h, h, (unsigned short*)nullptr,
                       (unsigned short*)nullptr, MM, DD, 4 * DD);
  }

  hipLaunchKernelGGL(ln_f_k, dim3(MM), dim3(256), 0, stream, h, lnfw, lnfb, (float*)d_out);
}

// Round 10
// 2003.184 us; speedup vs baseline: 1.1755x; 1.1387x over previous
//
#include <hip/hip_runtime.h>
#include <math.h>

#define TT 1024
#define DD 1024
#define NH 16
#define NB 2
#define NL 12
#define RR 32
#define MM (NB * TT)  // 2048

typedef __attribute__((ext_vector_type(8))) short bf16x8;
typedef __attribute__((ext_vector_type(4))) float f32x4;

__device__ __forceinline__ unsigned short f2bf(float f) {
  unsigned int u = __float_as_uint(f);
  u = (u + 0x7FFFu + ((u >> 16) & 1u)) >> 16;
  return (unsigned short)u;
}
__device__ __forceinline__ float bf2f(unsigned short u) {
  return __uint_as_float((unsigned int)u << 16);
}

typedef __attribute__((address_space(1))) void gvoid;
typedef __attribute__((address_space(3))) void lvoid;
__device__ __forceinline__ void gload_lds16(const void* g, void* l) {
  __builtin_amdgcn_global_load_lds((gvoid*)g, (lvoid*)l, 16, 0, 0);
}

// ---------------------------------------------------------------- embed
__global__ __launch_bounds__(256) void embed_k(const int* __restrict__ ids,
                                               const float* __restrict__ wte,
                                               const float* __restrict__ wpe,
                                               float* __restrict__ h) {
  const int i = blockIdx.x * 256 + threadIdx.x;
  const int row = i >> 10;
  const int d = i & 1023;
  const int t = row & (TT - 1);
  const int id = ids[row];
  h[i] = wte[(size_t)id * DD + d] + wpe[(size_t)t * DD + d];
}

// ---------------------------------------------------------------- layernorm (fp32 in, bf16 out)
__global__ __launch_bounds__(256) void ln_bf_k(const float* __restrict__ x,
                                               const float* __restrict__ w,
                                               const float* __restrict__ b,
                                               unsigned short* __restrict__ out) {
  const int row = blockIdx.x;
  const float* xr = x + (size_t)row * DD;
  const float4 v = *(const float4*)(xr + threadIdx.x * 4);
  float s = v.x + v.y + v.z + v.w;
  float ss = v.x * v.x + v.y * v.y + v.z * v.z + v.w * v.w;
#pragma unroll
  for (int off = 32; off > 0; off >>= 1) {
    s += __shfl_down(s, off);
    ss += __shfl_down(ss, off);
  }
  __shared__ float rs[4], rss[4];
  const int wid = threadIdx.x >> 6;
  if ((threadIdx.x & 63) == 0) { rs[wid] = s; rss[wid] = ss; }
  __syncthreads();
  s = rs[0] + rs[1] + rs[2] + rs[3];
  ss = rss[0] + rss[1] + rss[2] + rss[3];
  const float mean = s * (1.f / DD);
  const float var = ss * (1.f / DD) - mean * mean;
  const float rstd = rsqrtf(var + 1e-5f);
  const float4 wv = *(const float4*)(w + threadIdx.x * 4);
  const float4 bv = *(const float4*)(b + threadIdx.x * 4);
  ushort4 o;
  o.x = f2bf((v.x - mean) * rstd * wv.x + bv.x);
  o.y = f2bf((v.y - mean) * rstd * wv.y + bv.y);
  o.z = f2bf((v.z - mean) * rstd * wv.z + bv.z);
  o.w = f2bf((v.w - mean) * rstd * wv.w + bv.w);
  *(ushort4*)(out + (size_t)row * DD + threadIdx.x * 4) = o;
}

// final layernorm fp32 out
__global__ __launch_bounds__(256) void ln_f_k(const float* __restrict__ x,
                                              const float* __restrict__ w,
                                              const float* __restrict__ b,
                                              float* __restrict__ out) {
  const int row = blockIdx.x;
  const float* xr = x + (size_t)row * DD;
  const float4 v = *(const float4*)(xr + threadIdx.x * 4);
  float s = v.x + v.y + v.z + v.w;
  float ss = v.x * v.x + v.y * v.y + v.z * v.z + v.w * v.w;
#pragma unroll
  for (int off = 32; off > 0; off >>= 1) {
    s += __shfl_down(s, off);
    ss += __shfl_down(ss, off);
  }
  __shared__ float rs[4], rss[4];
  const int wid = threadIdx.x >> 6;
  if ((threadIdx.x & 63) == 0) { rs[wid] = s; rss[wid] = ss; }
  __syncthreads();
  s = rs[0] + rs[1] + rs[2] + rs[3];
  ss = rss[0] + rss[1] + rss[2] + rss[3];
  const float mean = s * (1.f / DD);
  const float var = ss * (1.f / DD) - mean * mean;
  const float rstd = rsqrtf(var + 1e-5f);
  const float4 wv = *(const float4*)(w + threadIdx.x * 4);
  const float4 bv = *(const float4*)(b + threadIdx.x * 4);
  float4 o;
  o.x = (v.x - mean) * rstd * wv.x + bv.x;
  o.y = (v.y - mean) * rstd * wv.y + bv.y;
  o.z = (v.z - mean) * rstd * wv.z + bv.z;
  o.w = (v.w - mean) * rstd * wv.w + bv.w;
  *(float4*)(out + (size_t)row * DD + threadIdx.x * 4) = o;
}

// ---------------------------------------------------------------- LoRA cvt: pack all A^T and B as bf16
__global__ __launch_bounds__(256) void cvt_lora_k(
    const float* __restrict__ ala, const float* __restrict__ alb,
    const float* __restrict__ pla, const float* __restrict__ plb,
    const float* __restrict__ fla, const float* __restrict__ flb,
    const float* __restrict__ mla, const float* __restrict__ mlb,
    unsigned short* __restrict__ out) {
  const int g = blockIdx.x * 256 + threadIdx.x;  // over NL*16384*32
  const int layer = g >> 19;
  const int rem = g & 524287;
  const int row = rem >> 5;
  const int r = rem & 31;
  float v;
  if (row < 1024)       v = ala[(size_t)layer * 32 * 1024 + r * 1024 + row];
  else if (row < 4096)  v = alb[(size_t)layer * 3072 * 32 + (row - 1024) * 32 + r];
  else if (row < 5120)  v = pla[(size_t)layer * 32 * 1024 + r * 1024 + (row - 4096)];
  else if (row < 6144)  v = plb[(size_t)layer * 1024 * 32 + (row - 5120) * 32 + r];
  else if (row < 7168)  v = fla[(size_t)layer * 32 * 1024 + r * 1024 + (row - 6144)];
  else if (row < 11264) v = flb[(size_t)layer * 4096 * 32 + (row - 7168) * 32 + r];
  else if (row < 15360) v = mla[(size_t)layer * 32 * 4096 + r * 4096 + (row - 11264)];
  else                  v = mlb[(size_t)layer * 1024 * 32 + (row - 15360) * 32 + r];
  out[g] = f2bf(v);
}

// ---------------------------------------------------------------- LoRA fold v4
__global__ __launch_bounds__(256) void fusew4_k(
    const float* __restrict__ aw, const float* __restrict__ pw,
    const float* __restrict__ fw, const float* __restrict__ mw,
    const unsigned short* __restrict__ lora,
    unsigned short* __restrict__ oq, unsigned short* __restrict__ op_,
    unsigned short* __restrict__ of, unsigned short* __restrict__ om) {
  const int g = blockIdx.x;
  const int layer = g / 1536;
  const int lid = g - layer * 1536;
  const unsigned short* Lb = lora + (size_t)layer * 16384 * 32;
  const float* W;
  unsigned short* out;
  const unsigned short *Bl, *Al;
  int K, n0, kblk;
  if (lid < 384) {
    W = aw + (size_t)layer * 3 * DD * DD; out = oq + (size_t)layer * 3 * DD * DD;
    Bl = Lb + 1024 * 32; Al = Lb;
    K = DD; n0 = (lid >> 3) * 64; kblk = (lid & 7) * 128;
  } else if (lid < 512) {
    const int t = lid - 384;
    W = pw + (size_t)layer * DD * DD; out = op_ + (size_t)layer * DD * DD;
    Bl = Lb + 5120 * 32; Al = Lb + 4096 * 32;
    K = DD; n0 = (t >> 3) * 64; kblk = (t & 7) * 128;
  } else if (lid < 1024) {
    const int t = lid - 512;
    W = fw + (size_t)layer * 4 * DD * DD; out = of + (size_t)layer * 4 * DD * DD;
    Bl = Lb + 7168 * 32; Al = Lb + 6144 * 32;
    K = DD; n0 = (t >> 3) * 64; kblk = (t & 7) * 128;
  } else {
    const int t = lid - 1024;
    W = mw + (size_t)layer * DD * 4 * DD; out = om + (size_t)layer * DD * 4 * DD;
    Bl = Lb + 15360 * 32; Al = Lb + 11264 * 32;
    K = 4 * DD; n0 = (t >> 5) * 64; kblk = (t & 31) * 128;
  }
  __shared__ unsigned short dl[64 * 128];  // 16KB
  const int tid = threadIdx.x;
  const int w = tid >> 6, l = tid & 63;
  const int lr16 = l & 15, lg = l >> 4;
  const int nloc = w * 16 + lr16;
  const bf16x8 bfrag = *(const bf16x8*)(Bl + (size_t)(n0 + nloc) * 32 + lg * 8);
#pragma unroll
  for (int kc = 0; kc < 8; ++kc) {
    const bf16x8 afr = *(const bf16x8*)(Al + (size_t)(kblk + kc * 16 + lr16) * 32 + lg * 8);
    f32x4 acc = {};
    acc = __builtin_amdgcn_mfma_f32_16x16x32_bf16(afr, bfrag, acc, 0, 0, 0);
    ushort4 dv;
    dv.x = f2bf(2.f * acc[0]); dv.y = f2bf(2.f * acc[1]);
    dv.z = f2bf(2.f * acc[2]); dv.w = f2bf(2.f * acc[3]);
    const unsigned int byte = ((unsigned)(nloc * 256 + kc * 32 + lg * 8)) ^
                              (((unsigned)nloc & 3u) << 5);
    *(ushort4*)((char*)dl + byte) = dv;
  }
  __syncthreads();
  float4 wv[8];
#pragma unroll
  for (int it = 0; it < 8; ++it) {
    const int flat = it * 1024 + tid * 4;
    const int row = flat >> 7;
    const int k = flat & 127;
    wv[it] = *(const float4*)(W + (size_t)(n0 + row) * K + kblk + k);
  }
#pragma unroll
  for (int it = 0; it < 8; ++it) {
    const int flat = it * 1024 + tid * 4;
    const int row = flat >> 7;
    const int k = flat & 127;
    const unsigned int byte = ((unsigned)(row * 256 + k * 2)) ^
                              (((unsigned)row & 3u) << 5);
    const ushort4 dv = *(const ushort4*)((const char*)dl + byte);
    ushort4 o;
    o.x = f2bf(wv[it].x + bf2f(dv.x));
    o.y = f2bf(wv[it].y + bf2f(dv.y));
    o.z = f2bf(wv[it].z + bf2f(dv.z));
    o.w = f2bf(wv[it].w + bf2f(dv.w));
    *(ushort4*)(out + (size_t)(n0 + row) * K + kblk + k) = o;
  }
}

// ---------------------------------------------------------------- unified bf16 MFMA GEMM
// Single-buffer, templated BK (64 or 128), 4 waves (2x2), XOR-swizzled LDS, XCD chunk swizzle.
// MODE 1: fp32 out = acc+bias+res; MODE 2: gelu->bf16; MODE 3: qkv split.
template <int BMt, int BNt, int BKt, int MODE>
__global__ __launch_bounds__(256) void gemm_t(const unsigned short* __restrict__ A,
                                              const unsigned short* __restrict__ Wt,
                                              const float* __restrict__ bias,
                                              const float* __restrict__ res,
                                              float* __restrict__ Cf,
                                              unsigned short* __restrict__ Cb,
                                              unsigned short* __restrict__ vt,
                                              int M, int N, int K) {
  constexpr int MI2 = BMt / 32, NJ2 = BNt / 32;
  constexpr int SB = BKt * 2;          // row stride bytes
  constexpr int SL = BKt / 8;          // 16B slots per row
  constexpr int RC = 1024 / SB;        // rows per 1KB chunk
  constexpr int CAw = BMt / RC / 4;    // A chunks per wave
  constexpr int CBw = BNt / RC / 4;
  __shared__ unsigned short As[BMt * BKt];
  __shared__ unsigned short Bs[BNt * BKt];
  const int tid = threadIdx.x;
  const int w = tid >> 6, l = tid & 63;
  // XCD-aware chunk swizzle (all grids %8 == 0)
  const int gx = gridDim.x;
  const int bid = blockIdx.y * gx + blockIdx.x;
  const int cpx = (gx * gridDim.y) >> 3;
  const int logical = (bid & 7) * cpx + (bid >> 3);
  const int bm = (logical / gx) * BMt, bn = (logical % gx) * BNt;
  const int wr = w >> 1, wc = w & 1;
  const int lr16 = l & 15, lg = l >> 4, l7 = l & 7;
  const int rin = l / SL;              // row within chunk
  const int slot = l % SL;
  f32x4 acc[MI2][NJ2] = {};
  for (int k0 = 0; k0 < K; k0 += BKt) {
    __syncthreads();
#pragma unroll
    for (int i = 0; i < CAw; ++i) {
      const int ch = w * CAw + i;
      const int row = ch * RC + rin;
      gload_lds16(A + (size_t)(bm + row) * K + k0 + ((slot ^ (row & 7)) * 8),
                  (char*)As + ch * 1024);
    }
#pragma unroll
    for (int i = 0; i < CBw; ++i) {
      const int ch = w * CBw + i;
      const int row = ch * RC + rin;
      gload_lds16(Wt + (size_t)(bn + row) * K + k0 + ((slot ^ (row & 7)) * 8),
                  (char*)Bs + ch * 1024);
    }
    __syncthreads();
#pragma unroll
    for (int kk = 0; kk < BKt / 32; ++kk) {
      bf16x8 af[MI2], bfr[NJ2];
      const int q = (kk * 4 + lg) ^ l7;
#pragma unroll
      for (int mi = 0; mi < MI2; ++mi)
        af[mi] = *(const bf16x8*)((const char*)As +
            (wr * (BMt / 2) + mi * 16 + lr16) * SB + q * 16);
#pragma unroll
      for (int nj = 0; nj < NJ2; ++nj)
        bfr[nj] = *(const bf16x8*)((const char*)Bs +
            (wc * (BNt / 2) + nj * 16 + lr16) * SB + q * 16);
#pragma unroll
      for (int mi = 0; mi < MI2; ++mi)
#pragma unroll
        for (int nj = 0; nj < NJ2; ++nj)
          acc[mi][nj] = __builtin_amdgcn_mfma_f32_16x16x32_bf16(
              af[mi], bfr[nj], acc[mi][nj], 0, 0, 0);
    }
  }
  const int cr = lg * 4;
  const int cc = lr16;
#pragma unroll
  for (int mi = 0; mi < MI2; ++mi) {
    const int gr0 = bm + wr * (BMt / 2) + mi * 16 + cr;
#pragma unroll
    for (int nj = 0; nj < NJ2; ++nj) {
      const int gc = bn + wc * (BNt / 2) + nj * 16 + cc;
      const float bv = bias[gc];
      if (MODE == 3) {
        if (gc < 2048) {
#pragma unroll
          for (int r = 0; r < 4; ++r)
            Cb[(size_t)(gr0 + r) * 2048 + gc] = f2bf(acc[mi][nj][r] + bv);
        } else {
          const int hv = gc - 2048;
          const int b_ = gr0 >> 10, t0 = gr0 & 1023;
          ushort4 u;
          u.x = f2bf(acc[mi][nj][0] + bv); u.y = f2bf(acc[mi][nj][1] + bv);
          u.z = f2bf(acc[mi][nj][2] + bv); u.w = f2bf(acc[mi][nj][3] + bv);
          *(ushort4*)(vt + ((size_t)(b_ * 1024 + hv)) * 1024 + t0) = u;
        }
      } else if (MODE == 1) {
#pragma unroll
        for (int r = 0; r < 4; ++r) {
          const size_t idx = (size_t)(gr0 + r) * N + gc;
          Cf[idx] = acc[mi][nj][r] + bv + res[idx];
        }
      } else {  // MODE 2
#pragma unroll
        for (int r = 0; r < 4; ++r) {
          float v = acc[mi][nj][r] + bv;
          v = 0.5f * v * (1.f + erff(v * 0.70710678118654752f));
          Cb[(size_t)(gr0 + r) * N + gc] = f2bf(v);
        }
      }
    }
  }
}

// ---------------------------------------------------------------- MFMA flash attention
#define SM_SCALE_LOG2E 0.18033688011112042f  // log2(e)/8
__global__ __launch_bounds__(256) void attn3_k(const unsigned short* __restrict__ qk,
                                               const unsigned short* __restrict__ vt,
                                               unsigned short* __restrict__ out) {
  const int qt = 15 - blockIdx.x;  // heavy tiles dispatch first
  const int bh = blockIdx.y;
  const int b = bh >> 4, hh = bh & 15;
  const int tid = threadIdx.x;
  const int w = tid >> 6, l = tid & 63;
  const int lg = l >> 4;
  const int lr = l & 15;

  __shared__ unsigned short Kt[2][64 * 64];
  __shared__ unsigned short Vb[2][64 * 64];
  __shared__ unsigned short Pb[4][16 * 64];

  bf16x8 qf[2];
  {
    const unsigned short* qp =
        qk + ((size_t)(b * TT + qt * 64 + w * 16 + lr)) * 2048 + hh * 64 + lg * 8;
    qf[0] = *(const bf16x8*)(qp);
    qf[1] = *(const bf16x8*)(qp + 32);
  }
  f32x4 oacc[4] = {};
  float mrow[4] = {-1e30f, -1e30f, -1e30f, -1e30f};
  float lrow[4] = {0.f, 0.f, 0.f, 0.f};

  auto stage = [&](int buf, int kt) {
#pragma unroll
    for (int oo = 0; oo < 2; ++oo) {
      const int o = w + oo * 4;
      const int row = o * 8 + (l >> 3);
      const int sc = ((l & 7) ^ (l >> 3)) * 8;
      const unsigned short* ks =
          qk + ((size_t)(b * TT + kt * 64 + row)) * 2048 + 1024 + hh * 64 + sc;
      gload_lds16(ks, (char*)&Kt[buf][0] + o * 1024);
      const unsigned short* vs =
          vt + ((size_t)(bh * 64 + row)) * 1024 + kt * 64 + sc;
      gload_lds16(vs, (char*)&Vb[buf][0] + o * 1024);
    }
  };

  stage(0, 0);
  int cur = 0;
  unsigned short* Pw = &Pb[w][0];
  const int qlocal = w * 16 + lg * 4;

  for (int kt = 0; kt <= qt; ++kt) {
    __syncthreads();
    if (kt < qt) stage(cur ^ 1, kt + 1);
    const unsigned short* Kb_ = &Kt[cur][0];
    const unsigned short* Vb_ = &Vb[cur][0];
    const int effc = lr & 7;

    f32x4 s[4];
#pragma unroll
    for (int j = 0; j < 4; ++j) {
      f32x4 sj = {};
#pragma unroll
      for (int ks = 0; ks < 2; ++ks) {
        const bf16x8 kf = *(const bf16x8*)((const char*)Kb_ + (j * 16 + lr) * 128 +
                                           (((ks * 4 + lg) ^ effc) * 16));
        sj = __builtin_amdgcn_mfma_f32_16x16x32_bf16(qf[ks], kf, sj, 0, 0, 0);
      }
      s[j] = sj;
    }

    const bool last = (kt == qt);
    float tv[4][4];
#pragma unroll
    for (int j = 0; j < 4; ++j)
#pragma unroll
      for (int r = 0; r < 4; ++r) {
        float v = s[j][r] * SM_SCALE_LOG2E;
        if (last && (j * 16 + lr > qlocal + r)) v = -1e30f;
        tv[j][r] = v;
      }
    float corr[4];
#pragma unroll
    for (int r = 0; r < 4; ++r) {
      float mx = fmaxf(fmaxf(tv[0][r], tv[1][r]), fmaxf(tv[2][r], tv[3][r]));
      mx = fmaxf(mx, __shfl_xor(mx, 1));
      mx = fmaxf(mx, __shfl_xor(mx, 2));
      mx = fmaxf(mx, __shfl_xor(mx, 4));
      mx = fmaxf(mx, __shfl_xor(mx, 8));
      const float mn = fmaxf(mrow[r], mx);
      corr[r] = exp2f(mrow[r] - mn);
      mrow[r] = mn;
      lrow[r] *= corr[r];
    }
#pragma unroll
    for (int dt = 0; dt < 4; ++dt) {
      oacc[dt][0] *= corr[0]; oacc[dt][1] *= corr[1];
      oacc[dt][2] *= corr[2]; oacc[dt][3] *= corr[3];
    }
#pragma unroll
    for (int j = 0; j < 4; ++j)
#pragma unroll
      for (int r = 0; r < 4; ++r) {
        const float p = exp2f(tv[j][r] - mrow[r]);
        lrow[r] += p;
        const int q = lg * 4 + r;
        const int kv = j * 16 + lr;
        *(unsigned short*)((char*)Pw + q * 128 + ((kv * 2) ^ ((q & 7) << 4))) = f2bf(p);
      }
    asm volatile("s_waitcnt lgkmcnt(0)" ::: "memory");
    __builtin_amdgcn_sched_barrier(0);

#pragma unroll
    for (int ks = 0; ks < 2; ++ks) {
      const bf16x8 pf = *(const bf16x8*)((const char*)Pw + lr * 128 +
                                         (((ks * 4 + lg) ^ effc) * 16));
#pragma unroll
      for (int dt = 0; dt < 4; ++dt) {
        const bf16x8 vf = *(const bf16x8*)((const char*)Vb_ + (dt * 16 + lr) * 128 +
                                           (((ks * 4 + lg) ^ effc) * 16));
        oacc[dt] = __builtin_amdgcn_mfma_f32_16x16x32_bf16(pf, vf, oacc[dt], 0, 0, 0);
      }
    }
    cur ^= 1;
  }

#pragma unroll
  for (int r = 0; r < 4; ++r) {
    float lv = lrow[r];
    lv += __shfl_xor(lv, 1);
    lv += __shfl_xor(lv, 2);
    lv += __shfl_xor(lv, 4);
    lv += __shfl_xor(lv, 8);
    lrow[r] = 1.f / lv;
  }
  unsigned short* ob = out + ((size_t)(b * TT + qt * 64 + w * 16 + lg * 4)) * 1024 + hh * 64 + lr;
#pragma unroll
  for (int r = 0; r < 4; ++r)
#pragma unroll
    for (int dt = 0; dt < 4; ++dt)
      ob[(size_t)r * 1024 + dt * 16] = f2bf(oacc[dt][r] * lrow[r]);
}

// ---------------------------------------------------------------- host
extern "C" void kernel_launch(void* const* d_in, const int* in_sizes, int n_in,
                              void* d_out, int out_size, void* d_ws, size_t ws_size,
                              hipStream_t stream) {
  (void)in_sizes; (void)n_in; (void)out_size; (void)ws_size;
  const int* ids = (const int*)d_in[0];
  const float* wte = (const float*)d_in[1];
  const float* wpe = (const float*)d_in[2];
  const float* ln1w = (const float*)d_in[3];
  const float* ln1b = (const float*)d_in[4];
  const float* attnw = (const float*)d_in[5];
  const float* attnb = (const float*)d_in[6];
  const float* attnla = (const float*)d_in[7];
  const float* attnlb = (const float*)d_in[8];
  const float* projw = (const float*)d_in[9];
  const float* projb = (const float*)d_in[10];
  const float* projla = (const float*)d_in[11];
  const float* projlb = (const float*)d_in[12];
  const float* ln2w = (const float*)d_in[13];
  const float* ln2b = (const float*)d_in[14];
  const float* fcw = (const float*)d_in[15];
  const float* fcb = (const float*)d_in[16];
  const float* fcla = (const float*)d_in[17];
  const float* fclb = (const float*)d_in[18];
  const float* mpw = (const float*)d_in[19];
  const float* mpb = (const float*)d_in[20];
  const float* mpla = (const float*)d_in[21];
  const float* mplb = (const float*)d_in[22];
  const float* lnfw = (const float*)d_in[23];
  const float* lnfb = (const float*)d_in[24];

  char* ws = (char*)d_ws;
  float* h = (float*)ws;                        ws += (size_t)MM * DD * 4;       // 8MB
  unsigned short* x = (unsigned short*)ws;      ws += (size_t)MM * DD * 2;       // 4MB
  unsigned short* qkb = (unsigned short*)ws;    ws += (size_t)MM * 2 * DD * 2;   // 8MB
  unsigned short* vtb = (unsigned short*)ws;    ws += (size_t)MM * DD * 2;       // 4MB
  unsigned short* ho = (unsigned short*)ws;     ws += (size_t)MM * DD * 2;       // 4MB
  unsigned short* hm = (unsigned short*)ws;     ws += (size_t)MM * 4 * DD * 2;   // 16MB
  unsigned short* wqkvA = (unsigned short*)ws;  ws += (size_t)NL * 3 * DD * DD * 2;  // 72MB
  unsigned short* wprojA = (unsigned short*)ws; ws += (size_t)NL * DD * DD * 2;      // 24MB
  unsigned short* wfcA = (unsigned short*)ws;   ws += (size_t)NL * 4 * DD * DD * 2;  // 96MB
  unsigned short* wmpA = (unsigned short*)ws;   ws += (size_t)NL * DD * 4 * DD * 2;  // 96MB
  unsigned short* loraP = (unsigned short*)ws;  ws += (size_t)NL * 16384 * 32 * 2;   // 12.6MB

  hipLaunchKernelGGL(embed_k, dim3(MM * DD / 256), dim3(256), 0, stream, ids, wte, wpe, h);

  hipLaunchKernelGGL(cvt_lora_k, dim3(NL * 16384 * 32 / 256), dim3(256), 0, stream,
                     attnla, attnlb, projla, projlb, fcla, fclb, mpla, mplb, loraP);
  hipLaunchKernelGGL(fusew4_k, dim3(NL * 1536), dim3(256), 0, stream,
                     attnw, projw, fcw, mpw, loraP, wqkvA, wprojA, wfcA, wmpA);

  for (int l = 0; l < NL; ++l) {
    const float* ab = attnb + (size_t)l * 3 * DD;
    const float* pb = projb + (size_t)l * DD;
    const float* fb = fcb + (size_t)l * 4 * DD;
    const float* mb = mpb + (size_t)l * DD;
    const unsigned short* wqkv = wqkvA + (size_t)l * 3 * DD * DD;
    const unsigned short* wproj = wprojA + (size_t)l * DD * DD;
    const unsigned short* wfc = wfcA + (size_t)l * 4 * DD * DD;
    const unsigned short* wmp = wmpA + (size_t)l * DD * 4 * DD;

    // x = LN1(h)
    hipLaunchKernelGGL(ln_bf_k, dim3(MM), dim3(256), 0, stream, h,
                       ln1w + (size_t)l * DD, ln1b + (size_t)l * DD, x);
    // qkv = x @ wqkv^T + ab -> qkb (Q,K) + vtb (V transposed)   [BK=128]
    hipLaunchKernelGGL((gemm_t<128, 64, 128, 3>), dim3(3 * DD / 64, MM / 128), dim3(256), 0,
                       stream, x, wqkv, ab, (const float*)nullptr, (float*)nullptr,
                       qkb, vtb, MM, 3 * DD, DD);
    // o = attention
    hipLaunchKernelGGL(attn3_k, dim3(TT / 64, NB * NH), dim3(256), 0, stream, qkb, vtb, ho);
    // h = h + o @ wproj^T + pb   [BK=128]
    hipLaunchKernelGGL((gemm_t<64, 64, 128, 1>), dim3(DD / 64, MM / 64), dim3(256), 0,
                       stream, ho, wproj, pb, h, h, (unsigned short*)nullptr,
                       (unsigned short*)nullptr, MM, DD, DD);
    // x = LN2(h)
    hipLaunchKernelGGL(ln_bf_k, dim3(MM), dim3(256), 0, stream, h,
                       ln2w + (size_t)l * DD, ln2b + (size_t)l * DD, x);
    // m = gelu(x @ wfc^T + fb)   [BK=64, grid 4/CU]
    hipLaunchKernelGGL((gemm_t<128, 64, 64, 2>), dim3(4 * DD / 64, MM / 128), dim3(256), 0,
                       stream, x, wfc, fb, (const float*)nullptr, (float*)nullptr, hm,
                       (unsigned short*)nullptr, MM, 4 * DD, DD);
    // h = h + m @ wmp^T + mb   [BK=128]
    hipLaunchKernelGGL((gemm_t<64, 64, 128, 1>), dim3(DD / 64, MM / 64), dim3(256), 0,
                       stream, hm, wmp, mb, h, h, (unsigned short*)nullptr,
                       (unsigned short*)nullptr, MM, DD, 4 * DD);
  }

  hipLaunchKernelGGL(ln_f_k, dim3(MM), dim3(256), 0, stream, h, lnfw, lnfb, (float*)d_out);
}

// Round 11
// 1867.548 us; speedup vs baseline: 1.2609x; 1.0726x over previous
//
#include <hip/hip_runtime.h>
#include <math.h>

#define TT 1024
#define DD 1024
#define NH 16
#define NB 2
#define NL 12
#define RR 32
#define MM (NB * TT)  // 2048

typedef __attribute__((ext_vector_type(8))) short bf16x8;
typedef __attribute__((ext_vector_type(4))) float f32x4;

__device__ __forceinline__ unsigned short f2bf(float f) {
  unsigned int u = __float_as_uint(f);
  u = (u + 0x7FFFu + ((u >> 16) & 1u)) >> 16;
  return (unsigned short)u;
}
__device__ __forceinline__ float bf2f(unsigned short u) {
  return __uint_as_float((unsigned int)u << 16);
}

typedef __attribute__((address_space(1))) void gvoid;
typedef __attribute__((address_space(3))) void lvoid;
__device__ __forceinline__ void gload_lds16(const void* g, void* l) {
  __builtin_amdgcn_global_load_lds((gvoid*)g, (lvoid*)l, 16, 0, 0);
}

// ---------------------------------------------------------------- embed
__global__ __launch_bounds__(256) void embed_k(const int* __restrict__ ids,
                                               const float* __restrict__ wte,
                                               const float* __restrict__ wpe,
                                               float* __restrict__ h) {
  const int i = blockIdx.x * 256 + threadIdx.x;
  const int row = i >> 10;
  const int d = i & 1023;
  const int t = row & (TT - 1);
  const int id = ids[row];
  h[i] = wte[(size_t)id * DD + d] + wpe[(size_t)t * DD + d];
}

// ---------------------------------------------------------------- layernorm (fp32 in, bf16 out)
__global__ __launch_bounds__(256) void ln_bf_k(const float* __restrict__ x,
                                               const float* __restrict__ w,
                                               const float* __restrict__ b,
                                               unsigned short* __restrict__ out) {
  const int row = blockIdx.x;
  const float* xr = x + (size_t)row * DD;
  const float4 v = *(const float4*)(xr + threadIdx.x * 4);
  float s = v.x + v.y + v.z + v.w;
  float ss = v.x * v.x + v.y * v.y + v.z * v.z + v.w * v.w;
#pragma unroll
  for (int off = 32; off > 0; off >>= 1) {
    s += __shfl_down(s, off);
    ss += __shfl_down(ss, off);
  }
  __shared__ float rs[4], rss[4];
  const int wid = threadIdx.x >> 6;
  if ((threadIdx.x & 63) == 0) { rs[wid] = s; rss[wid] = ss; }
  __syncthreads();
  s = rs[0] + rs[1] + rs[2] + rs[3];
  ss = rss[0] + rss[1] + rss[2] + rss[3];
  const float mean = s * (1.f / DD);
  const float var = ss * (1.f / DD) - mean * mean;
  const float rstd = rsqrtf(var + 1e-5f);
  const float4 wv = *(const float4*)(w + threadIdx.x * 4);
  const float4 bv = *(const float4*)(b + threadIdx.x * 4);
  ushort4 o;
  o.x = f2bf((v.x - mean) * rstd * wv.x + bv.x);
  o.y = f2bf((v.y - mean) * rstd * wv.y + bv.y);
  o.z = f2bf((v.z - mean) * rstd * wv.z + bv.z);
  o.w = f2bf((v.w - mean) * rstd * wv.w + bv.w);
  *(ushort4*)(out + (size_t)row * DD + threadIdx.x * 4) = o;
}

// final layernorm fp32 out
__global__ __launch_bounds__(256) void ln_f_k(const float* __restrict__ x,
                                              const float* __restrict__ w,
                                              const float* __restrict__ b,
                                              float* __restrict__ out) {
  const int row = blockIdx.x;
  const float* xr = x + (size_t)row * DD;
  const float4 v = *(const float4*)(xr + threadIdx.x * 4);
  float s = v.x + v.y + v.z + v.w;
  float ss = v.x * v.x + v.y * v.y + v.z * v.z + v.w * v.w;
#pragma unroll
  for (int off = 32; off > 0; off >>= 1) {
    s += __shfl_down(s, off);
    ss += __shfl_down(ss, off);
  }
  __shared__ float rs[4], rss[4];
  const int wid = threadIdx.x >> 6;
  if ((threadIdx.x & 63) == 0) { rs[wid] = s; rss[wid] = ss; }
  __syncthreads();
  s = rs[0] + rs[1] + rs[2] + rs[3];
  ss = rss[0] + rss[1] + rss[2] + rss[3];
  const float mean = s * (1.f / DD);
  const float var = ss * (1.f / DD) - mean * mean;
  const float rstd = rsqrtf(var + 1e-5f);
  const float4 wv = *(const float4*)(w + threadIdx.x * 4);
  const float4 bv = *(const float4*)(b + threadIdx.x * 4);
  float4 o;
  o.x = (v.x - mean) * rstd * wv.x + bv.x;
  o.y = (v.y - mean) * rstd * wv.y + bv.y;
  o.z = (v.z - mean) * rstd * wv.z + bv.z;
  o.w = (v.w - mean) * rstd * wv.w + bv.w;
  *(float4*)(out + (size_t)row * DD + threadIdx.x * 4) = o;
}

// ---------------------------------------------------------------- LoRA cvt: pack all A^T and B as bf16
__global__ __launch_bounds__(256) void cvt_lora_k(
    const float* __restrict__ ala, const float* __restrict__ alb,
    const float* __restrict__ pla, const float* __restrict__ plb,
    const float* __restrict__ fla, const float* __restrict__ flb,
    const float* __restrict__ mla, const float* __restrict__ mlb,
    unsigned short* __restrict__ out) {
  const int g = blockIdx.x * 256 + threadIdx.x;  // over NL*16384*32
  const int layer = g >> 19;
  const int rem = g & 524287;
  const int row = rem >> 5;
  const int r = rem & 31;
  float v;
  if (row < 1024)       v = ala[(size_t)layer * 32 * 1024 + r * 1024 + row];
  else if (row < 4096)  v = alb[(size_t)layer * 3072 * 32 + (row - 1024) * 32 + r];
  else if (row < 5120)  v = pla[(size_t)layer * 32 * 1024 + r * 1024 + (row - 4096)];
  else if (row < 6144)  v = plb[(size_t)layer * 1024 * 32 + (row - 5120) * 32 + r];
  else if (row < 7168)  v = fla[(size_t)layer * 32 * 1024 + r * 1024 + (row - 6144)];
  else if (row < 11264) v = flb[(size_t)layer * 4096 * 32 + (row - 7168) * 32 + r];
  else if (row < 15360) v = mla[(size_t)layer * 32 * 4096 + r * 4096 + (row - 11264)];
  else                  v = mlb[(size_t)layer * 1024 * 32 + (row - 15360) * 32 + r];
  out[g] = f2bf(v);
}

// ---------------------------------------------------------------- LoRA fold v5 (per-layer JIT)
// out = bf16(W + 2*B@A). Tile 64n x 128k, LDS 16KB.
// Phase 1: swapped MFMA -> swizzled LDS (ds_write_b64).
// Phase 2: 8 float4 W loads, vmcnt(0) fence (forces true 8-deep MLP), then combine+store.
__global__ __launch_bounds__(256) void fusew5_k(
    const float* __restrict__ aw, const float* __restrict__ pw,
    const float* __restrict__ fw, const float* __restrict__ mw,
    const unsigned short* __restrict__ Lb,  // this layer's packed lora
    unsigned short* __restrict__ oq, unsigned short* __restrict__ op_,
    unsigned short* __restrict__ of, unsigned short* __restrict__ om) {
  const int lid = blockIdx.x;  // 0..1535
  const float* W;
  unsigned short* out;
  const unsigned short *Bl, *Al;
  int K, n0, kblk;
  if (lid < 384) {  // qkv: 48 n-tiles x 8 k-tiles
    W = aw; out = oq; Bl = Lb + 1024 * 32; Al = Lb;
    K = DD; n0 = (lid >> 3) * 64; kblk = (lid & 7) * 128;
  } else if (lid < 512) {  // proj: 16 x 8
    const int t = lid - 384;
    W = pw; out = op_; Bl = Lb + 5120 * 32; Al = Lb + 4096 * 32;
    K = DD; n0 = (t >> 3) * 64; kblk = (t & 7) * 128;
  } else if (lid < 1024) {  // fc: 64 x 8
    const int t = lid - 512;
    W = fw; out = of; Bl = Lb + 7168 * 32; Al = Lb + 6144 * 32;
    K = DD; n0 = (t >> 3) * 64; kblk = (t & 7) * 128;
  } else {  // mp: 16 x 32
    const int t = lid - 1024;
    W = mw; out = om; Bl = Lb + 15360 * 32; Al = Lb + 11264 * 32;
    K = 4 * DD; n0 = (t >> 5) * 64; kblk = (t & 31) * 128;
  }
  __shared__ unsigned short dl[64 * 128];  // 16KB
  const int tid = threadIdx.x;
  const int w = tid >> 6, l = tid & 63;
  const int lr16 = l & 15, lg = l >> 4;
  const int nloc = w * 16 + lr16;
  const bf16x8 bfrag = *(const bf16x8*)(Bl + (size_t)(n0 + nloc) * 32 + lg * 8);
#pragma unroll
  for (int kc = 0; kc < 8; ++kc) {
    const bf16x8 afr = *(const bf16x8*)(Al + (size_t)(kblk + kc * 16 + lr16) * 32 + lg * 8);
    f32x4 acc = {};
    acc = __builtin_amdgcn_mfma_f32_16x16x32_bf16(afr, bfrag, acc, 0, 0, 0);
    ushort4 dv;
    dv.x = f2bf(2.f * acc[0]); dv.y = f2bf(2.f * acc[1]);
    dv.z = f2bf(2.f * acc[2]); dv.w = f2bf(2.f * acc[3]);
    const unsigned int byte = ((unsigned)(nloc * 256 + kc * 32 + lg * 8)) ^
                              (((unsigned)nloc & 3u) << 5);
    *(ushort4*)((char*)dl + byte) = dv;
  }
  __syncthreads();
  float4 wv[8];
#pragma unroll
  for (int it = 0; it < 8; ++it) {
    const int flat = it * 1024 + tid * 4;  // over 64*128
    const int row = flat >> 7;
    const int k = flat & 127;
    wv[it] = *(const float4*)(W + (size_t)(n0 + row) * K + kblk + k);
  }
  asm volatile("s_waitcnt vmcnt(0)" ::: "memory");  // all 8 loads issued & landed
#pragma unroll
  for (int it = 0; it < 8; ++it) {
    const int flat = it * 1024 + tid * 4;
    const int row = flat >> 7;
    const int k = flat & 127;
    const unsigned int byte = ((unsigned)(row * 256 + k * 2)) ^
                              (((unsigned)row & 3u) << 5);
    const ushort4 dv = *(const ushort4*)((const char*)dl + byte);
    ushort4 o;
    o.x = f2bf(wv[it].x + bf2f(dv.x));
    o.y = f2bf(wv[it].y + bf2f(dv.y));
    o.z = f2bf(wv[it].z + bf2f(dv.z));
    o.w = f2bf(wv[it].w + bf2f(dv.w));
    *(ushort4*)(out + (size_t)(n0 + row) * K + kblk + k) = o;
  }
}

// ---------------------------------------------------------------- unified bf16 MFMA GEMM
// Single-buffer, templated BK (64 or 128), 4 waves (2x2), XOR-swizzled LDS, XCD chunk swizzle.
// MODE 1: fp32 out = acc+bias+res; MODE 2: gelu->bf16; MODE 3: qkv split.
template <int BMt, int BNt, int BKt, int MODE>
__global__ __launch_bounds__(256) void gemm_t(const unsigned short* __restrict__ A,
                                              const unsigned short* __restrict__ Wt,
                                              const float* __restrict__ bias,
                                              const float* __restrict__ res,
                                              float* __restrict__ Cf,
                                              unsigned short* __restrict__ Cb,
                                              unsigned short* __restrict__ vt,
                                              int M, int N, int K) {
  constexpr int MI2 = BMt / 32, NJ2 = BNt / 32;
  constexpr int SB = BKt * 2;          // row stride bytes
  constexpr int SL = BKt / 8;          // 16B slots per row
  constexpr int RC = 1024 / SB;        // rows per 1KB chunk
  constexpr int CAw = BMt / RC / 4;    // A chunks per wave
  constexpr int CBw = BNt / RC / 4;
  __shared__ unsigned short As[BMt * BKt];
  __shared__ unsigned short Bs[BNt * BKt];
  const int tid = threadIdx.x;
  const int w = tid >> 6, l = tid & 63;
  // XCD-aware chunk swizzle (all grids %8 == 0)
  const int gx = gridDim.x;
  const int bid = blockIdx.y * gx + blockIdx.x;
  const int cpx = (gx * gridDim.y) >> 3;
  const int logical = (bid & 7) * cpx + (bid >> 3);
  const int bm = (logical / gx) * BMt, bn = (logical % gx) * BNt;
  const int wr = w >> 1, wc = w & 1;
  const int lr16 = l & 15, lg = l >> 4, l7 = l & 7;
  const int rin = l / SL;              // row within chunk
  const int slot = l % SL;
  f32x4 acc[MI2][NJ2] = {};
  for (int k0 = 0; k0 < K; k0 += BKt) {
    __syncthreads();
#pragma unroll
    for (int i = 0; i < CAw; ++i) {
      const int ch = w * CAw + i;
      const int row = ch * RC + rin;
      gload_lds16(A + (size_t)(bm + row) * K + k0 + ((slot ^ (row & 7)) * 8),
                  (char*)As + ch * 1024);
    }
#pragma unroll
    for (int i = 0; i < CBw; ++i) {
      const int ch = w * CBw + i;
      const int row = ch * RC + rin;
      gload_lds16(Wt + (size_t)(bn + row) * K + k0 + ((slot ^ (row & 7)) * 8),
                  (char*)Bs + ch * 1024);
    }
    __syncthreads();
#pragma unroll
    for (int kk = 0; kk < BKt / 32; ++kk) {
      bf16x8 af[MI2], bfr[NJ2];
      const int q = (kk * 4 + lg) ^ l7;
#pragma unroll
      for (int mi = 0; mi < MI2; ++mi)
        af[mi] = *(const bf16x8*)((const char*)As +
            (wr * (BMt / 2) + mi * 16 + lr16) * SB + q * 16);
#pragma unroll
      for (int nj = 0; nj < NJ2; ++nj)
        bfr[nj] = *(const bf16x8*)((const char*)Bs +
            (wc * (BNt / 2) + nj * 16 + lr16) * SB + q * 16);
#pragma unroll
      for (int mi = 0; mi < MI2; ++mi)
#pragma unroll
        for (int nj = 0; nj < NJ2; ++nj)
          acc[mi][nj] = __builtin_amdgcn_mfma_f32_16x16x32_bf16(
              af[mi], bfr[nj], acc[mi][nj], 0, 0, 0);
    }
  }
  const int cr = lg * 4;
  const int cc = lr16;
#pragma unroll
  for (int mi = 0; mi < MI2; ++mi) {
    const int gr0 = bm + wr * (BMt / 2) + mi * 16 + cr;
#pragma unroll
    for (int nj = 0; nj < NJ2; ++nj) {
      const int gc = bn + wc * (BNt / 2) + nj * 16 + cc;
      const float bv = bias[gc];
      if (MODE == 3) {
        if (gc < 2048) {
#pragma unroll
          for (int r = 0; r < 4; ++r)
            Cb[(size_t)(gr0 + r) * 2048 + gc] = f2bf(acc[mi][nj][r] + bv);
        } else {
          const int hv = gc - 2048;
          const int b_ = gr0 >> 10, t0 = gr0 & 1023;
          ushort4 u;
          u.x = f2bf(acc[mi][nj][0] + bv); u.y = f2bf(acc[mi][nj][1] + bv);
          u.z = f2bf(acc[mi][nj][2] + bv); u.w = f2bf(acc[mi][nj][3] + bv);
          *(ushort4*)(vt + ((size_t)(b_ * 1024 + hv)) * 1024 + t0) = u;
        }
      } else if (MODE == 1) {
#pragma unroll
        for (int r = 0; r < 4; ++r) {
          const size_t idx = (size_t)(gr0 + r) * N + gc;
          Cf[idx] = acc[mi][nj][r] + bv + res[idx];
        }
      } else {  // MODE 2
#pragma unroll
        for (int r = 0; r < 4; ++r) {
          float v = acc[mi][nj][r] + bv;
          v = 0.5f * v * (1.f + erff(v * 0.70710678118654752f));
          Cb[(size_t)(gr0 + r) * N + gc] = f2bf(v);
        }
      }
    }
  }
}

// ---------------------------------------------------------------- MFMA flash attention
#define SM_SCALE_LOG2E 0.18033688011112042f  // log2(e)/8
__global__ __launch_bounds__(256) void attn3_k(const unsigned short* __restrict__ qk,
                                               const unsigned short* __restrict__ vt,
                                               unsigned short* __restrict__ out) {
  const int qt = 15 - blockIdx.x;  // heavy tiles dispatch first
  const int bh = blockIdx.y;
  const int b = bh >> 4, hh = bh & 15;
  const int tid = threadIdx.x;
  const int w = tid >> 6, l = tid & 63;
  const int lg = l >> 4;
  const int lr = l & 15;

  __shared__ unsigned short Kt[2][64 * 64];
  __shared__ unsigned short Vb[2][64 * 64];
  __shared__ unsigned short Pb[4][16 * 64];

  bf16x8 qf[2];
  {
    const unsigned short* qp =
        qk + ((size_t)(b * TT + qt * 64 + w * 16 + lr)) * 2048 + hh * 64 + lg * 8;
    qf[0] = *(const bf16x8*)(qp);
    qf[1] = *(const bf16x8*)(qp + 32);
  }
  f32x4 oacc[4] = {};
  float mrow[4] = {-1e30f, -1e30f, -1e30f, -1e30f};
  float lrow[4] = {0.f, 0.f, 0.f, 0.f};

  auto stage = [&](int buf, int kt) {
#pragma unroll
    for (int oo = 0; oo < 2; ++oo) {
      const int o = w + oo * 4;
      const int row = o * 8 + (l >> 3);
      const int sc = ((l & 7) ^ (l >> 3)) * 8;
      const unsigned short* ks =
          qk + ((size_t)(b * TT + kt * 64 + row)) * 2048 + 1024 + hh * 64 + sc;
      gload_lds16(ks, (char*)&Kt[buf][0] + o * 1024);
      const unsigned short* vs =
          vt + ((size_t)(bh * 64 + row)) * 1024 + kt * 64 + sc;
      gload_lds16(vs, (char*)&Vb[buf][0] + o * 1024);
    }
  };

  stage(0, 0);
  int cur = 0;
  unsigned short* Pw = &Pb[w][0];
  const int qlocal = w * 16 + lg * 4;

  for (int kt = 0; kt <= qt; ++kt) {
    __syncthreads();
    if (kt < qt) stage(cur ^ 1, kt + 1);
    const unsigned short* Kb_ = &Kt[cur][0];
    const unsigned short* Vb_ = &Vb[cur][0];
    const int effc = lr & 7;

    f32x4 s[4];
#pragma unroll
    for (int j = 0; j < 4; ++j) {
      f32x4 sj = {};
#pragma unroll
      for (int ks = 0; ks < 2; ++ks) {
        const bf16x8 kf = *(const bf16x8*)((const char*)Kb_ + (j * 16 + lr) * 128 +
                                           (((ks * 4 + lg) ^ effc) * 16));
        sj = __builtin_amdgcn_mfma_f32_16x16x32_bf16(qf[ks], kf, sj, 0, 0, 0);
      }
      s[j] = sj;
    }

    const bool last = (kt == qt);
    float tv[4][4];
#pragma unroll
    for (int j = 0; j < 4; ++j)
#pragma unroll
      for (int r = 0; r < 4; ++r) {
        float v = s[j][r] * SM_SCALE_LOG2E;
        if (last && (j * 16 + lr > qlocal + r)) v = -1e30f;
        tv[j][r] = v;
      }
    float corr[4];
#pragma unroll
    for (int r = 0; r < 4; ++r) {
      float mx = fmaxf(fmaxf(tv[0][r], tv[1][r]), fmaxf(tv[2][r], tv[3][r]));
      mx = fmaxf(mx, __shfl_xor(mx, 1));
      mx = fmaxf(mx, __shfl_xor(mx, 2));
      mx = fmaxf(mx, __shfl_xor(mx, 4));
      mx = fmaxf(mx, __shfl_xor(mx, 8));
      const float mn = fmaxf(mrow[r], mx);
      corr[r] = exp2f(mrow[r] - mn);
      mrow[r] = mn;
      lrow[r] *= corr[r];
    }
#pragma unroll
    for (int dt = 0; dt < 4; ++dt) {
      oacc[dt][0] *= corr[0]; oacc[dt][1] *= corr[1];
      oacc[dt][2] *= corr[2]; oacc[dt][3] *= corr[3];
    }
#pragma unroll
    for (int j = 0; j < 4; ++j)
#pragma unroll
      for (int r = 0; r < 4; ++r) {
        const float p = exp2f(tv[j][r] - mrow[r]);
        lrow[r] += p;
        const int q = lg * 4 + r;
        const int kv = j * 16 + lr;
        *(unsigned short*)((char*)Pw + q * 128 + ((kv * 2) ^ ((q & 7) << 4))) = f2bf(p);
      }
    asm volatile("s_waitcnt lgkmcnt(0)" ::: "memory");
    __builtin_amdgcn_sched_barrier(0);

#pragma unroll
    for (int ks = 0; ks < 2; ++ks) {
      const bf16x8 pf = *(const bf16x8*)((const char*)Pw + lr * 128 +
                                         (((ks * 4 + lg) ^ effc) * 16));
#pragma unroll
      for (int dt = 0; dt < 4; ++dt) {
        const bf16x8 vf = *(const bf16x8*)((const char*)Vb_ + (dt * 16 + lr) * 128 +
                                           (((ks * 4 + lg) ^ effc) * 16));
        oacc[dt] = __builtin_amdgcn_mfma_f32_16x16x32_bf16(pf, vf, oacc[dt], 0, 0, 0);
      }
    }
    cur ^= 1;
  }

#pragma unroll
  for (int r = 0; r < 4; ++r) {
    float lv = lrow[r];
    lv += __shfl_xor(lv, 1);
    lv += __shfl_xor(lv, 2);
    lv += __shfl_xor(lv, 4);
    lv += __shfl_xor(lv, 8);
    lrow[r] = 1.f / lv;
  }
  unsigned short* ob = out + ((size_t)(b * TT + qt * 64 + w * 16 + lg * 4)) * 1024 + hh * 64 + lr;
#pragma unroll
  for (int r = 0; r < 4; ++r)
#pragma unroll
    for (int dt = 0; dt < 4; ++dt)
      ob[(size_t)r * 1024 + dt * 16] = f2bf(oacc[dt][r] * lrow[r]);
}

// ---------------------------------------------------------------- host
extern "C" void kernel_launch(void* const* d_in, const int* in_sizes, int n_in,
                              void* d_out, int out_size, void* d_ws, size_t ws_size,
                              hipStream_t stream) {
  (void)in_sizes; (void)n_in; (void)out_size; (void)ws_size;
  const int* ids = (const int*)d_in[0];
  const float* wte = (const float*)d_in[1];
  const float* wpe = (const float*)d_in[2];
  const float* ln1w = (const float*)d_in[3];
  const float* ln1b = (const float*)d_in[4];
  const float* attnw = (const float*)d_in[5];
  const float* attnb = (const float*)d_in[6];
  const float* attnla = (const float*)d_in[7];
  const float* attnlb = (const float*)d_in[8];
  const float* projw = (const float*)d_in[9];
  const float* projb = (const float*)d_in[10];
  const float* projla = (const float*)d_in[11];
  const float* projlb = (const float*)d_in[12];
  const float* ln2w = (const float*)d_in[13];
  const float* ln2b = (const float*)d_in[14];
  const float* fcw = (const float*)d_in[15];
  const float* fcb = (const float*)d_in[16];
  const float* fcla = (const float*)d_in[17];
  const float* fclb = (const float*)d_in[18];
  const float* mpw = (const float*)d_in[19];
  const float* mpb = (const float*)d_in[20];
  const float* mpla = (const float*)d_in[21];
  const float* mplb = (const float*)d_in[22];
  const float* lnfw = (const float*)d_in[23];
  const float* lnfb = (const float*)d_in[24];

  char* ws = (char*)d_ws;
  float* h = (float*)ws;                        ws += (size_t)MM * DD * 4;       // 8MB
  unsigned short* x = (unsigned short*)ws;      ws += (size_t)MM * DD * 2;       // 4MB
  unsigned short* qkb = (unsigned short*)ws;    ws += (size_t)MM * 2 * DD * 2;   // 8MB
  unsigned short* vtb = (unsigned short*)ws;    ws += (size_t)MM * DD * 2;       // 4MB
  unsigned short* ho = (unsigned short*)ws;     ws += (size_t)MM * DD * 2;       // 4MB
  unsigned short* hm = (unsigned short*)ws;     ws += (size_t)MM * 4 * DD * 2;   // 16MB
  unsigned short* wqkv = (unsigned short*)ws;   ws += (size_t)3 * DD * DD * 2;   // 6MB (reused per layer)
  unsigned short* wproj = (unsigned short*)ws;  ws += (size_t)DD * DD * 2;       // 2MB
  unsigned short* wfc = (unsigned short*)ws;    ws += (size_t)4 * DD * DD * 2;   // 8MB
  unsigned short* wmp = (unsigned short*)ws;    ws += (size_t)DD * 4 * DD * 2;   // 8MB
  unsigned short* loraP = (unsigned short*)ws;  ws += (size_t)NL * 16384 * 32 * 2;  // 12.6MB

  hipLaunchKernelGGL(embed_k, dim3(MM * DD / 256), dim3(256), 0, stream, ids, wte, wpe, h);

  hipLaunchKernelGGL(cvt_lora_k, dim3(NL * 16384 * 32 / 256), dim3(256), 0, stream,
                     attnla, attnlb, projla, projlb, fcla, fclb, mpla, mplb, loraP);

  for (int l = 0; l < NL; ++l) {
    const float* ab = attnb + (size_t)l * 3 * DD;
    const float* pb = projb + (size_t)l * DD;
    const float* fb = fcb + (size_t)l * 4 * DD;
    const float* mb = mpb + (size_t)l * DD;

    // just-in-time LoRA fold for this layer (weights stay L2/L3-hot for the GEMMs)
    hipLaunchKernelGGL(fusew5_k, dim3(1536), dim3(256), 0, stream,
                       attnw + (size_t)l * 3 * DD * DD, projw + (size_t)l * DD * DD,
                       fcw + (size_t)l * 4 * DD * DD, mpw + (size_t)l * DD * 4 * DD,
                       loraP + (size_t)l * 16384 * 32, wqkv, wproj, wfc, wmp);

    // x = LN1(h)
    hipLaunchKernelGGL(ln_bf_k, dim3(MM), dim3(256), 0, stream, h,
                       ln1w + (size_t)l * DD, ln1b + (size_t)l * DD, x);
    // qkv = x @ wqkv^T + ab -> qkb (Q,K) + vtb (V transposed)   [BK=128]
    hipLaunchKernelGGL((gemm_t<128, 64, 128, 3>), dim3(3 * DD / 64, MM / 128), dim3(256), 0,
                       stream, x, wqkv, ab, (const float*)nullptr, (float*)nullptr,
                       qkb, vtb, MM, 3 * DD, DD);
    // o = attention
    hipLaunchKernelGGL(attn3_k, dim3(TT / 64, NB * NH), dim3(256), 0, stream, qkb, vtb, ho);
    // h = h + o @ wproj^T + pb   [BK=128]
    hipLaunchKernelGGL((gemm_t<64, 64, 128, 1>), dim3(DD / 64, MM / 64), dim3(256), 0,
                       stream, ho, wproj, pb, h, h, (unsigned short*)nullptr,
                       (unsigned short*)nullptr, MM, DD, DD);
    // x = LN2(h)
    hipLaunchKernelGGL(ln_bf_k, dim3(MM), dim3(256), 0, stream, h,
                       ln2w + (size_t)l * DD, ln2b + (size_t)l * DD, x);
    // m = gelu(x @ wfc^T + fb)   [BK=64, grid 4/CU]
    hipLaunchKernelGGL((gemm_t<128, 64, 64, 2>), dim3(4 * DD / 64, MM / 128), dim3(256), 0,
                       stream, x, wfc, fb, (const float*)nullptr, (float*)nullptr, hm,
                       (unsigned short*)nullptr, MM, 4 * DD, DD);
    // h = h + m @ wmp^T + mb   [BK=128]
    hipLaunchKernelGGL((gemm_t<64, 64, 128, 1>), dim3(DD / 64, MM / 64), dim3(256), 0,
                       stream, hm, wmp, mb, h, h, (unsigned short*)nullptr,
                       (unsigned short*)nullptr, MM, DD, 4 * DD);
  }

  hipLaunchKernelGGL(ln_f_k, dim3(MM), dim3(256), 0, stream, h, lnfw, lnfb, (float*)d_out);
}

// Round 12
// 1818.844 us; speedup vs baseline: 1.2947x; 1.0268x over previous
//
#include <hip/hip_runtime.h>
#include <math.h>

#define TT 1024
#define DD 1024
#define NH 16
#define NB 2
#define NL 12
#define RR 32
#define MM (NB * TT)  // 2048

typedef __attribute__((ext_vector_type(8))) short bf16x8;
typedef __attribute__((ext_vector_type(4))) float f32x4;

__device__ __forceinline__ unsigned short f2bf(float f) {
  unsigned int u = __float_as_uint(f);
  u = (u + 0x7FFFu + ((u >> 16) & 1u)) >> 16;
  return (unsigned short)u;
}
__device__ __forceinline__ float bf2f(unsigned short u) {
  return __uint_as_float((unsigned int)u << 16);
}

typedef __attribute__((address_space(1))) void gvoid;
typedef __attribute__((address_space(3))) void lvoid;
__device__ __forceinline__ void gload_lds16(const void* g, void* l) {
  __builtin_amdgcn_global_load_lds((gvoid*)g, (lvoid*)l, 16, 0, 0);
}

// ---------------------------------------------------------------- embed
__global__ __launch_bounds__(256) void embed_k(const int* __restrict__ ids,
                                               const float* __restrict__ wte,
                                               const float* __restrict__ wpe,
                                               float* __restrict__ h) {
  const int i = blockIdx.x * 256 + threadIdx.x;
  const int row = i >> 10;
  const int d = i & 1023;
  const int t = row & (TT - 1);
  const int id = ids[row];
  h[i] = wte[(size_t)id * DD + d] + wpe[(size_t)t * DD + d];
}

// ---------------------------------------------------------------- layernorm (fp32 in, bf16 out)
__global__ __launch_bounds__(256) void ln_bf_k(const float* __restrict__ x,
                                               const float* __restrict__ w,
                                               const float* __restrict__ b,
                                               unsigned short* __restrict__ out) {
  const int row = blockIdx.x;
  const float* xr = x + (size_t)row * DD;
  const float4 v = *(const float4*)(xr + threadIdx.x * 4);
  float s = v.x + v.y + v.z + v.w;
  float ss = v.x * v.x + v.y * v.y + v.z * v.z + v.w * v.w;
#pragma unroll
  for (int off = 32; off > 0; off >>= 1) {
    s += __shfl_down(s, off);
    ss += __shfl_down(ss, off);
  }
  __shared__ float rs[4], rss[4];
  const int wid = threadIdx.x >> 6;
  if ((threadIdx.x & 63) == 0) { rs[wid] = s; rss[wid] = ss; }
  __syncthreads();
  s = rs[0] + rs[1] + rs[2] + rs[3];
  ss = rss[0] + rss[1] + rss[2] + rss[3];
  const float mean = s * (1.f / DD);
  const float var = ss * (1.f / DD) - mean * mean;
  const float rstd = rsqrtf(var + 1e-5f);
  const float4 wv = *(const float4*)(w + threadIdx.x * 4);
  const float4 bv = *(const float4*)(b + threadIdx.x * 4);
  ushort4 o;
  o.x = f2bf((v.x - mean) * rstd * wv.x + bv.x);
  o.y = f2bf((v.y - mean) * rstd * wv.y + bv.y);
  o.z = f2bf((v.z - mean) * rstd * wv.z + bv.z);
  o.w = f2bf((v.w - mean) * rstd * wv.w + bv.w);
  *(ushort4*)(out + (size_t)row * DD + threadIdx.x * 4) = o;
}

// final layernorm fp32 out
__global__ __launch_bounds__(256) void ln_f_k(const float* __restrict__ x,
                                              const float* __restrict__ w,
                                              const float* __restrict__ b,
                                              float* __restrict__ out) {
  const int row = blockIdx.x;
  const float* xr = x + (size_t)row * DD;
  const float4 v = *(const float4*)(xr + threadIdx.x * 4);
  float s = v.x + v.y + v.z + v.w;
  float ss = v.x * v.x + v.y * v.y + v.z * v.z + v.w * v.w;
#pragma unroll
  for (int off = 32; off > 0; off >>= 1) {
    s += __shfl_down(s, off);
    ss += __shfl_down(ss, off);
  }
  __shared__ float rs[4], rss[4];
  const int wid = threadIdx.x >> 6;
  if ((threadIdx.x & 63) == 0) { rs[wid] = s; rss[wid] = ss; }
  __syncthreads();
  s = rs[0] + rs[1] + rs[2] + rs[3];
  ss = rss[0] + rss[1] + rss[2] + rss[3];
  const float mean = s * (1.f / DD);
  const float var = ss * (1.f / DD) - mean * mean;
  const float rstd = rsqrtf(var + 1e-5f);
  const float4 wv = *(const float4*)(w + threadIdx.x * 4);
  const float4 bv = *(const float4*)(b + threadIdx.x * 4);
  float4 o;
  o.x = (v.x - mean) * rstd * wv.x + bv.x;
  o.y = (v.y - mean) * rstd * wv.y + bv.y;
  o.z = (v.z - mean) * rstd * wv.z + bv.z;
  o.w = (v.w - mean) * rstd * wv.w + bv.w;
  *(float4*)(out + (size_t)row * DD + threadIdx.x * 4) = o;
}

// ---------------------------------------------------------------- LoRA cvt: pack all A^T and B as bf16
__global__ __launch_bounds__(256) void cvt_lora_k(
    const float* __restrict__ ala, const float* __restrict__ alb,
    const float* __restrict__ pla, const float* __restrict__ plb,
    const float* __restrict__ fla, const float* __restrict__ flb,
    const float* __restrict__ mla, const float* __restrict__ mlb,
    unsigned short* __restrict__ out) {
  const int g = blockIdx.x * 256 + threadIdx.x;  // over NL*16384*32
  const int layer = g >> 19;
  const int rem = g & 524287;
  const int row = rem >> 5;
  const int r = rem & 31;
  float v;
  if (row < 1024)       v = ala[(size_t)layer * 32 * 1024 + r * 1024 + row];
  else if (row < 4096)  v = alb[(size_t)layer * 3072 * 32 + (row - 1024) * 32 + r];
  else if (row < 5120)  v = pla[(size_t)layer * 32 * 1024 + r * 1024 + (row - 4096)];
  else if (row < 6144)  v = plb[(size_t)layer * 1024 * 32 + (row - 5120) * 32 + r];
  else if (row < 7168)  v = fla[(size_t)layer * 32 * 1024 + r * 1024 + (row - 6144)];
  else if (row < 11264) v = flb[(size_t)layer * 4096 * 32 + (row - 7168) * 32 + r];
  else if (row < 15360) v = mla[(size_t)layer * 32 * 4096 + r * 4096 + (row - 11264)];
  else                  v = mlb[(size_t)layer * 1024 * 32 + (row - 15360) * 32 + r];
  out[g] = f2bf(v);
}

// ---------------------------------------------------------------- LoRA fold v5 (per-layer JIT)
__global__ __launch_bounds__(256) void fusew5_k(
    const float* __restrict__ aw, const float* __restrict__ pw,
    const float* __restrict__ fw, const float* __restrict__ mw,
    const unsigned short* __restrict__ Lb,
    unsigned short* __restrict__ oq, unsigned short* __restrict__ op_,
    unsigned short* __restrict__ of, unsigned short* __restrict__ om) {
  const int lid = blockIdx.x;  // 0..1535
  const float* W;
  unsigned short* out;
  const unsigned short *Bl, *Al;
  int K, n0, kblk;
  if (lid < 384) {
    W = aw; out = oq; Bl = Lb + 1024 * 32; Al = Lb;
    K = DD; n0 = (lid >> 3) * 64; kblk = (lid & 7) * 128;
  } else if (lid < 512) {
    const int t = lid - 384;
    W = pw; out = op_; Bl = Lb + 5120 * 32; Al = Lb + 4096 * 32;
    K = DD; n0 = (t >> 3) * 64; kblk = (t & 7) * 128;
  } else if (lid < 1024) {
    const int t = lid - 512;
    W = fw; out = of; Bl = Lb + 7168 * 32; Al = Lb + 6144 * 32;
    K = DD; n0 = (t >> 3) * 64; kblk = (t & 7) * 128;
  } else {
    const int t = lid - 1024;
    W = mw; out = om; Bl = Lb + 15360 * 32; Al = Lb + 11264 * 32;
    K = 4 * DD; n0 = (t >> 5) * 64; kblk = (t & 31) * 128;
  }
  __shared__ unsigned short dl[64 * 128];  // 16KB
  const int tid = threadIdx.x;
  const int w = tid >> 6, l = tid & 63;
  const int lr16 = l & 15, lg = l >> 4;
  const int nloc = w * 16 + lr16;
  const bf16x8 bfrag = *(const bf16x8*)(Bl + (size_t)(n0 + nloc) * 32 + lg * 8);
#pragma unroll
  for (int kc = 0; kc < 8; ++kc) {
    const bf16x8 afr = *(const bf16x8*)(Al + (size_t)(kblk + kc * 16 + lr16) * 32 + lg * 8);
    f32x4 acc = {};
    acc = __builtin_amdgcn_mfma_f32_16x16x32_bf16(afr, bfrag, acc, 0, 0, 0);
    ushort4 dv;
    dv.x = f2bf(2.f * acc[0]); dv.y = f2bf(2.f * acc[1]);
    dv.z = f2bf(2.f * acc[2]); dv.w = f2bf(2.f * acc[3]);
    const unsigned int byte = ((unsigned)(nloc * 256 + kc * 32 + lg * 8)) ^
                              (((unsigned)nloc & 3u) << 5);
    *(ushort4*)((char*)dl + byte) = dv;
  }
  __syncthreads();
  float4 wv[8];
#pragma unroll
  for (int it = 0; it < 8; ++it) {
    const int flat = it * 1024 + tid * 4;
    const int row = flat >> 7;
    const int k = flat & 127;
    wv[it] = *(const float4*)(W + (size_t)(n0 + row) * K + kblk + k);
  }
  asm volatile("s_waitcnt vmcnt(0)" ::: "memory");
#pragma unroll
  for (int it = 0; it < 8; ++it) {
    const int flat = it * 1024 + tid * 4;
    const int row = flat >> 7;
    const int k = flat & 127;
    const unsigned int byte = ((unsigned)(row * 256 + k * 2)) ^
                              (((unsigned)row & 3u) << 5);
    const ushort4 dv = *(const ushort4*)((const char*)dl + byte);
    ushort4 o;
    o.x = f2bf(wv[it].x + bf2f(dv.x));
    o.y = f2bf(wv[it].y + bf2f(dv.y));
    o.z = f2bf(wv[it].z + bf2f(dv.z));
    o.w = f2bf(wv[it].w + bf2f(dv.w));
    *(ushort4*)(out + (size_t)(n0 + row) * K + kblk + k) = o;
  }
}

// ---------------------------------------------------------------- unified bf16 MFMA GEMM
// Single-buffer, templated BK (64/128/256), 4 waves (2x2), XOR-swizzled LDS, XCD chunk swizzle.
template <int BMt, int BNt, int BKt, int MODE>
__global__ __launch_bounds__(256) void gemm_t(const unsigned short* __restrict__ A,
                                              const unsigned short* __restrict__ Wt,
                                              const float* __restrict__ bias,
                                              const float* __restrict__ res,
                                              float* __restrict__ Cf,
                                              unsigned short* __restrict__ Cb,
                                              unsigned short* __restrict__ vt,
                                              int M, int N, int K) {
  constexpr int MI2 = BMt / 32, NJ2 = BNt / 32;
  constexpr int SB = BKt * 2;          // row stride bytes
  constexpr int SL = BKt / 8;          // 16B slots per row
  constexpr int RC = 1024 / SB;        // rows per 1KB chunk
  constexpr int CAw = BMt / RC / 4;    // A chunks per wave
  constexpr int CBw = BNt / RC / 4;
  __shared__ unsigned short As[BMt * BKt];
  __shared__ unsigned short Bs[BNt * BKt];
  const int tid = threadIdx.x;
  const int w = tid >> 6, l = tid & 63;
  const int gx = gridDim.x;
  const int bid = blockIdx.y * gx + blockIdx.x;
  const int cpx = (gx * gridDim.y) >> 3;
  const int logical = (bid & 7) * cpx + (bid >> 3);
  const int bm = (logical / gx) * BMt, bn = (logical % gx) * BNt;
  const int wr = w >> 1, wc = w & 1;
  const int lr16 = l & 15, lg = l >> 4, l7 = l & 7;
  const int rin = l / SL;
  const int slot = l % SL;
  f32x4 acc[MI2][NJ2] = {};
  for (int k0 = 0; k0 < K; k0 += BKt) {
    __syncthreads();
#pragma unroll
    for (int i = 0; i < CAw; ++i) {
      const int ch = w * CAw + i;
      const int row = ch * RC + rin;
      gload_lds16(A + (size_t)(bm + row) * K + k0 + ((slot ^ (row & 7)) * 8),
                  (char*)As + ch * 1024);
    }
#pragma unroll
    for (int i = 0; i < CBw; ++i) {
      const int ch = w * CBw + i;
      const int row = ch * RC + rin;
      gload_lds16(Wt + (size_t)(bn + row) * K + k0 + ((slot ^ (row & 7)) * 8),
                  (char*)Bs + ch * 1024);
    }
    __syncthreads();
#pragma unroll
    for (int kk = 0; kk < BKt / 32; ++kk) {
      bf16x8 af[MI2], bfr[NJ2];
      const int q = (kk * 4 + lg) ^ l7;
#pragma unroll
      for (int mi = 0; mi < MI2; ++mi)
        af[mi] = *(const bf16x8*)((const char*)As +
            (wr * (BMt / 2) + mi * 16 + lr16) * SB + q * 16);
#pragma unroll
      for (int nj = 0; nj < NJ2; ++nj)
        bfr[nj] = *(const bf16x8*)((const char*)Bs +
            (wc * (BNt / 2) + nj * 16 + lr16) * SB + q * 16);
#pragma unroll
      for (int mi = 0; mi < MI2; ++mi)
#pragma unroll
        for (int nj = 0; nj < NJ2; ++nj)
          acc[mi][nj] = __builtin_amdgcn_mfma_f32_16x16x32_bf16(
              af[mi], bfr[nj], acc[mi][nj], 0, 0, 0);
    }
  }
  const int cr = lg * 4;
  const int cc = lr16;
#pragma unroll
  for (int mi = 0; mi < MI2; ++mi) {
    const int gr0 = bm + wr * (BMt / 2) + mi * 16 + cr;
#pragma unroll
    for (int nj = 0; nj < NJ2; ++nj) {
      const int gc = bn + wc * (BNt / 2) + nj * 16 + cc;
      const float bv = bias[gc];
      if (MODE == 3) {
        if (gc < 2048) {
#pragma unroll
          for (int r = 0; r < 4; ++r)
            Cb[(size_t)(gr0 + r) * 2048 + gc] = f2bf(acc[mi][nj][r] + bv);
        } else {
          const int hv = gc - 2048;
          const int b_ = gr0 >> 10, t0 = gr0 & 1023;
          ushort4 u;
          u.x = f2bf(acc[mi][nj][0] + bv); u.y = f2bf(acc[mi][nj][1] + bv);
          u.z = f2bf(acc[mi][nj][2] + bv); u.w = f2bf(acc[mi][nj][3] + bv);
          *(ushort4*)(vt + ((size_t)(b_ * 1024 + hv)) * 1024 + t0) = u;
        }
      } else if (MODE == 1) {
#pragma unroll
        for (int r = 0; r < 4; ++r) {
          const size_t idx = (size_t)(gr0 + r) * N + gc;
          Cf[idx] = acc[mi][nj][r] + bv + res[idx];
        }
      } else {  // MODE 2
#pragma unroll
        for (int r = 0; r < 4; ++r) {
          float v = acc[mi][nj][r] + bv;
          v = 0.5f * v * (1.f + erff(v * 0.70710678118654752f));
          Cb[(size_t)(gr0 + r) * N + gc] = f2bf(v);
        }
      }
    }
  }
}

// ---------------------------------------------------------------- MFMA flash attention
#define SM_SCALE_LOG2E 0.18033688011112042f  // log2(e)/8
__global__ __launch_bounds__(256) void attn3_k(const unsigned short* __restrict__ qk,
                                               const unsigned short* __restrict__ vt,
                                               unsigned short* __restrict__ out) {
  const int qt = 15 - blockIdx.x;
  const int bh = blockIdx.y;
  const int b = bh >> 4, hh = bh & 15;
  const int tid = threadIdx.x;
  const int w = tid >> 6, l = tid & 63;
  const int lg = l >> 4;
  const int lr = l & 15;

  __shared__ unsigned short Kt[2][64 * 64];
  __shared__ unsigned short Vb[2][64 * 64];
  __shared__ unsigned short Pb[4][16 * 64];

  bf16x8 qf[2];
  {
    const unsigned short* qp =
        qk + ((size_t)(b * TT + qt * 64 + w * 16 + lr)) * 2048 + hh * 64 + lg * 8;
    qf[0] = *(const bf16x8*)(qp);
    qf[1] = *(const bf16x8*)(qp + 32);
  }
  f32x4 oacc[4] = {};
  float mrow[4] = {-1e30f, -1e30f, -1e30f, -1e30f};
  float lrow[4] = {0.f, 0.f, 0.f, 0.f};

  auto stage = [&](int buf, int kt) {
#pragma unroll
    for (int oo = 0; oo < 2; ++oo) {
      const int o = w + oo * 4;
      const int row = o * 8 + (l >> 3);
      const int sc = ((l & 7) ^ (l >> 3)) * 8;
      const unsigned short* ks =
          qk + ((size_t)(b * TT + kt * 64 + row)) * 2048 + 1024 + hh * 64 + sc;
      gload_lds16(ks, (char*)&Kt[buf][0] + o * 1024);
      const unsigned short* vs =
          vt + ((size_t)(bh * 64 + row)) * 1024 + kt * 64 + sc;
      gload_lds16(vs, (char*)&Vb[buf][0] + o * 1024);
    }
  };

  stage(0, 0);
  int cur = 0;
  unsigned short* Pw = &Pb[w][0];
  const int qlocal = w * 16 + lg * 4;

  for (int kt = 0; kt <= qt; ++kt) {
    __syncthreads();
    if (kt < qt) stage(cur ^ 1, kt + 1);
    const unsigned short* Kb_ = &Kt[cur][0];
    const unsigned short* Vb_ = &Vb[cur][0];
    const int effc = lr & 7;

    f32x4 s[4];
#pragma unroll
    for (int j = 0; j < 4; ++j) {
      f32x4 sj = {};
#pragma unroll
      for (int ks = 0; ks < 2; ++ks) {
        const bf16x8 kf = *(const bf16x8*)((const char*)Kb_ + (j * 16 + lr) * 128 +
                                           (((ks * 4 + lg) ^ effc) * 16));
        sj = __builtin_amdgcn_mfma_f32_16x16x32_bf16(qf[ks], kf, sj, 0, 0, 0);
      }
      s[j] = sj;
    }

    const bool last = (kt == qt);
    float tv[4][4];
#pragma unroll
    for (int j = 0; j < 4; ++j)
#pragma unroll
      for (int r = 0; r < 4; ++r) {
        float v = s[j][r] * SM_SCALE_LOG2E;
        if (last && (j * 16 + lr > qlocal + r)) v = -1e30f;
        tv[j][r] = v;
      }
    float corr[4];
#pragma unroll
    for (int r = 0; r < 4; ++r) {
      float mx = fmaxf(fmaxf(tv[0][r], tv[1][r]), fmaxf(tv[2][r], tv[3][r]));
      mx = fmaxf(mx, __shfl_xor(mx, 1));
      mx = fmaxf(mx, __shfl_xor(mx, 2));
      mx = fmaxf(mx, __shfl_xor(mx, 4));
      mx = fmaxf(mx, __shfl_xor(mx, 8));
      const float mn = fmaxf(mrow[r], mx);
      corr[r] = exp2f(mrow[r] - mn);
      mrow[r] = mn;
      lrow[r] *= corr[r];
    }
#pragma unroll
    for (int dt = 0; dt < 4; ++dt) {
      oacc[dt][0] *= corr[0]; oacc[dt][1] *= corr[1];
      oacc[dt][2] *= corr[2]; oacc[dt][3] *= corr[3];
    }
#pragma unroll
    for (int j = 0; j < 4; ++j)
#pragma unroll
      for (int r = 0; r < 4; ++r) {
        const float p = exp2f(tv[j][r] - mrow[r]);
        lrow[r] += p;
        const int q = lg * 4 + r;
        const int kv = j * 16 + lr;
        *(unsigned short*)((char*)Pw + q * 128 + ((kv * 2) ^ ((q & 7) << 4))) = f2bf(p);
      }
    asm volatile("s_waitcnt lgkmcnt(0)" ::: "memory");
    __builtin_amdgcn_sched_barrier(0);

#pragma unroll
    for (int ks = 0; ks < 2; ++ks) {
      const bf16x8 pf = *(const bf16x8*)((const char*)Pw + lr * 128 +
                                         (((ks * 4 + lg) ^ effc) * 16));
#pragma unroll
      for (int dt = 0; dt < 4; ++dt) {
        const bf16x8 vf = *(const bf16x8*)((const char*)Vb_ + (dt * 16 + lr) * 128 +
                                           (((ks * 4 + lg) ^ effc) * 16));
        oacc[dt] = __builtin_amdgcn_mfma_f32_16x16x32_bf16(pf, vf, oacc[dt], 0, 0, 0);
      }
    }
    cur ^= 1;
  }

#pragma unroll
  for (int r = 0; r < 4; ++r) {
    float lv = lrow[r];
    lv += __shfl_xor(lv, 1);
    lv += __shfl_xor(lv, 2);
    lv += __shfl_xor(lv, 4);
    lv += __shfl_xor(lv, 8);
    lrow[r] = 1.f / lv;
  }
  unsigned short* ob = out + ((size_t)(b * TT + qt * 64 + w * 16 + lg * 4)) * 1024 + hh * 64 + lr;
#pragma unroll
  for (int r = 0; r < 4; ++r)
#pragma unroll
    for (int dt = 0; dt < 4; ++dt)
      ob[(size_t)r * 1024 + dt * 16] = f2bf(oacc[dt][r] * lrow[r]);
}

// ---------------------------------------------------------------- host
extern "C" void kernel_launch(void* const* d_in, const int* in_sizes, int n_in,
                              void* d_out, int out_size, void* d_ws, size_t ws_size,
                              hipStream_t stream) {
  (void)in_sizes; (void)n_in; (void)out_size; (void)ws_size;
  const int* ids = (const int*)d_in[0];
  const float* wte = (const float*)d_in[1];
  const float* wpe = (const float*)d_in[2];
  const float* ln1w = (const float*)d_in[3];
  const float* ln1b = (const float*)d_in[4];
  const float* attnw = (const float*)d_in[5];
  const float* attnb = (const float*)d_in[6];
  const float* attnla = (const float*)d_in[7];
  const float* attnlb = (const float*)d_in[8];
  const float* projw = (const float*)d_in[9];
  const float* projb = (const float*)d_in[10];
  const float* projla = (const float*)d_in[11];
  const float* projlb = (const float*)d_in[12];
  const float* ln2w = (const float*)d_in[13];
  const float* ln2b = (const float*)d_in[14];
  const float* fcw = (const float*)d_in[15];
  const float* fcb = (const float*)d_in[16];
  const float* fcla = (const float*)d_in[17];
  const float* fclb = (const float*)d_in[18];
  const float* mpw = (const float*)d_in[19];
  const float* mpb = (const float*)d_in[20];
  const float* mpla = (const float*)d_in[21];
  const float* mplb = (const float*)d_in[22];
  const float* lnfw = (const float*)d_in[23];
  const float* lnfb = (const float*)d_in[24];

  char* ws = (char*)d_ws;
  float* h = (float*)ws;                        ws += (size_t)MM * DD * 4;       // 8MB
  unsigned short* x = (unsigned short*)ws;      ws += (size_t)MM * DD * 2;       // 4MB
  unsigned short* qkb = (unsigned short*)ws;    ws += (size_t)MM * 2 * DD * 2;   // 8MB
  unsigned short* vtb = (unsigned short*)ws;    ws += (size_t)MM * DD * 2;       // 4MB
  unsigned short* ho = (unsigned short*)ws;     ws += (size_t)MM * DD * 2;       // 4MB
  unsigned short* hm = (unsigned short*)ws;     ws += (size_t)MM * 4 * DD * 2;   // 16MB
  unsigned short* wqkv = (unsigned short*)ws;   ws += (size_t)3 * DD * DD * 2;   // 6MB (reused per layer)
  unsigned short* wproj = (unsigned short*)ws;  ws += (size_t)DD * DD * 2;       // 2MB
  unsigned short* wfc = (unsigned short*)ws;    ws += (size_t)4 * DD * DD * 2;   // 8MB
  unsigned short* wmp = (unsigned short*)ws;    ws += (size_t)DD * 4 * DD * 2;   // 8MB
  unsigned short* loraP = (unsigned short*)ws;  ws += (size_t)NL * 16384 * 32 * 2;  // 12.6MB

  hipLaunchKernelGGL(embed_k, dim3(MM * DD / 256), dim3(256), 0, stream, ids, wte, wpe, h);

  hipLaunchKernelGGL(cvt_lora_k, dim3(NL * 16384 * 32 / 256), dim3(256), 0, stream,
                     attnla, attnlb, projla, projlb, fcla, fclb, mpla, mplb, loraP);

  for (int l = 0; l < NL; ++l) {
    const float* ab = attnb + (size_t)l * 3 * DD;
    const float* pb = projb + (size_t)l * DD;
    const float* fb = fcb + (size_t)l * 4 * DD;
    const float* mb = mpb + (size_t)l * DD;

    // just-in-time LoRA fold for this layer (weights stay L2/L3-hot for the GEMMs)
    hipLaunchKernelGGL(fusew5_k, dim3(1536), dim3(256), 0, stream,
                       attnw + (size_t)l * 3 * DD * DD, projw + (size_t)l * DD * DD,
                       fcw + (size_t)l * 4 * DD * DD, mpw + (size_t)l * DD * 4 * DD,
                       loraP + (size_t)l * 16384 * 32, wqkv, wproj, wfc, wmp);

    // x = LN1(h)
    hipLaunchKernelGGL(ln_bf_k, dim3(MM), dim3(256), 0, stream, h,
                       ln1w + (size_t)l * DD, ln1b + (size_t)l * DD, x);
    // qkv = x @ wqkv^T + ab -> qkb (Q,K) + vtb (V transposed)   [BK=128]
    hipLaunchKernelGGL((gemm_t<128, 64, 128, 3>), dim3(3 * DD / 64, MM / 128), dim3(256), 0,
                       stream, x, wqkv, ab, (const float*)nullptr, (float*)nullptr,
                       qkb, vtb, MM, 3 * DD, DD);
    // o = attention
    hipLaunchKernelGGL(attn3_k, dim3(TT / 64, NB * NH), dim3(256), 0, stream, qkb, vtb, ho);
    // h = h + o @ wproj^T + pb   [BK=256]
    hipLaunchKernelGGL((gemm_t<64, 64, 256, 1>), dim3(DD / 64, MM / 64), dim3(256), 0,
                       stream, ho, wproj, pb, h, h, (unsigned short*)nullptr,
                       (unsigned short*)nullptr, MM, DD, DD);
    // x = LN2(h)
    hipLaunchKernelGGL(ln_bf_k, dim3(MM), dim3(256), 0, stream, h,
                       ln2w + (size_t)l * DD, ln2b + (size_t)l * DD, x);
    // m = gelu(x @ wfc^T + fb)   [128x128 tile, BK=128]
    hipLaunchKernelGGL((gemm_t<128, 128, 128, 2>), dim3(4 * DD / 128, MM / 128), dim3(256), 0,
                       stream, x, wfc, fb, (const float*)nullptr, (float*)nullptr, hm,
                       (unsigned short*)nullptr, MM, 4 * DD, DD);
    // h = h + m @ wmp^T + mb   [BK=256]
    hipLaunchKernelGGL((gemm_t<64, 64, 256, 1>), dim3(DD / 64, MM / 64), dim3(256), 0,
                       stream, hm, wmp, mb, h, h, (unsigned short*)nullptr,
                       (unsigned short*)nullptr, MM, DD, 4 * DD);
  }

  hipLaunchKernelGGL(ln_f_k, dim3(MM), dim3(256), 0, stream, h, lnfw, lnfb, (float*)d_out);
}

// Round 13
// 1784.968 us; speedup vs baseline: 1.3192x; 1.0190x over previous
//
#include <hip/hip_runtime.h>
#include <math.h>

#define TT 1024
#define DD 1024
#define NH 16
#define NB 2
#define NL 12
#define RR 32
#define MM (NB * TT)  // 2048

typedef __attribute__((ext_vector_type(8))) short bf16x8;
typedef __attribute__((ext_vector_type(4))) float f32x4;

__device__ __forceinline__ unsigned short f2bf(float f) {
  unsigned int u = __float_as_uint(f);
  u = (u + 0x7FFFu + ((u >> 16) & 1u)) >> 16;
  return (unsigned short)u;
}
__device__ __forceinline__ float bf2f(unsigned short u) {
  return __uint_as_float((unsigned int)u << 16);
}

typedef __attribute__((address_space(1))) void gvoid;
typedef __attribute__((address_space(3))) void lvoid;
__device__ __forceinline__ void gload_lds16(const void* g, void* l) {
  __builtin_amdgcn_global_load_lds((gvoid*)g, (lvoid*)l, 16, 0, 0);
}

// ---------------------------------------------------------------- embed + LoRA cvt (merged, independent)
__global__ __launch_bounds__(256) void embed_cvt_k(
    const int* __restrict__ ids, const float* __restrict__ wte,
    const float* __restrict__ wpe, float* __restrict__ h,
    const float* __restrict__ ala, const float* __restrict__ alb,
    const float* __restrict__ pla, const float* __restrict__ plb,
    const float* __restrict__ fla, const float* __restrict__ flb,
    const float* __restrict__ mla, const float* __restrict__ mlb,
    unsigned short* __restrict__ out) {
  if (blockIdx.x < MM * DD / 256) {
    const int i = blockIdx.x * 256 + threadIdx.x;
    const int row = i >> 10;
    const int d = i & 1023;
    const int t = row & (TT - 1);
    const int id = ids[row];
    h[i] = wte[(size_t)id * DD + d] + wpe[(size_t)t * DD + d];
    return;
  }
  const int g = (blockIdx.x - MM * DD / 256) * 256 + threadIdx.x;  // over NL*16384*32
  const int layer = g >> 19;
  const int rem = g & 524287;
  const int row = rem >> 5;
  const int r = rem & 31;
  float v;
  if (row < 1024)       v = ala[(size_t)layer * 32 * 1024 + r * 1024 + row];
  else if (row < 4096)  v = alb[(size_t)layer * 3072 * 32 + (row - 1024) * 32 + r];
  else if (row < 5120)  v = pla[(size_t)layer * 32 * 1024 + r * 1024 + (row - 4096)];
  else if (row < 6144)  v = plb[(size_t)layer * 1024 * 32 + (row - 5120) * 32 + r];
  else if (row < 7168)  v = fla[(size_t)layer * 32 * 1024 + r * 1024 + (row - 6144)];
  else if (row < 11264) v = flb[(size_t)layer * 4096 * 32 + (row - 7168) * 32 + r];
  else if (row < 15360) v = mla[(size_t)layer * 32 * 4096 + r * 4096 + (row - 11264)];
  else                  v = mlb[(size_t)layer * 1024 * 32 + (row - 15360) * 32 + r];
  out[g] = f2bf(v);
}

// ---------------------------------------------------------------- layernorm (fp32 in, bf16 out)
__global__ __launch_bounds__(256) void ln_bf_k(const float* __restrict__ x,
                                               const float* __restrict__ w,
                                               const float* __restrict__ b,
                                               unsigned short* __restrict__ out) {
  const int row = blockIdx.x;
  const float* xr = x + (size_t)row * DD;
  const float4 v = *(const float4*)(xr + threadIdx.x * 4);
  float s = v.x + v.y + v.z + v.w;
  float ss = v.x * v.x + v.y * v.y + v.z * v.z + v.w * v.w;
#pragma unroll
  for (int off = 32; off > 0; off >>= 1) {
    s += __shfl_down(s, off);
    ss += __shfl_down(ss, off);
  }
  __shared__ float rs[4], rss[4];
  const int wid = threadIdx.x >> 6;
  if ((threadIdx.x & 63) == 0) { rs[wid] = s; rss[wid] = ss; }
  __syncthreads();
  s = rs[0] + rs[1] + rs[2] + rs[3];
  ss = rss[0] + rss[1] + rss[2] + rss[3];
  const float mean = s * (1.f / DD);
  const float var = ss * (1.f / DD) - mean * mean;
  const float rstd = rsqrtf(var + 1e-5f);
  const float4 wv = *(const float4*)(w + threadIdx.x * 4);
  const float4 bv = *(const float4*)(b + threadIdx.x * 4);
  ushort4 o;
  o.x = f2bf((v.x - mean) * rstd * wv.x + bv.x);
  o.y = f2bf((v.y - mean) * rstd * wv.y + bv.y);
  o.z = f2bf((v.z - mean) * rstd * wv.z + bv.z);
  o.w = f2bf((v.w - mean) * rstd * wv.w + bv.w);
  *(ushort4*)(out + (size_t)row * DD + threadIdx.x * 4) = o;
}

// final layernorm fp32 out
__global__ __launch_bounds__(256) void ln_f_k(const float* __restrict__ x,
                                              const float* __restrict__ w,
                                              const float* __restrict__ b,
                                              float* __restrict__ out) {
  const int row = blockIdx.x;
  const float* xr = x + (size_t)row * DD;
  const float4 v = *(const float4*)(xr + threadIdx.x * 4);
  float s = v.x + v.y + v.z + v.w;
  float ss = v.x * v.x + v.y * v.y + v.z * v.z + v.w * v.w;
#pragma unroll
  for (int off = 32; off > 0; off >>= 1) {
    s += __shfl_down(s, off);
    ss += __shfl_down(ss, off);
  }
  __shared__ float rs[4], rss[4];
  const int wid = threadIdx.x >> 6;
  if ((threadIdx.x & 63) == 0) { rs[wid] = s; rss[wid] = ss; }
  __syncthreads();
  s = rs[0] + rs[1] + rs[2] + rs[3];
  ss = rss[0] + rss[1] + rss[2] + rss[3];
  const float mean = s * (1.f / DD);
  const float var = ss * (1.f / DD) - mean * mean;
  const float rstd = rsqrtf(var + 1e-5f);
  const float4 wv = *(const float4*)(w + threadIdx.x * 4);
  const float4 bv = *(const float4*)(b + threadIdx.x * 4);
  float4 o;
  o.x = (v.x - mean) * rstd * wv.x + bv.x;
  o.y = (v.y - mean) * rstd * wv.y + bv.y;
  o.z = (v.z - mean) * rstd * wv.z + bv.z;
  o.w = (v.w - mean) * rstd * wv.w + bv.w;
  *(float4*)(out + (size_t)row * DD + threadIdx.x * 4) = o;
}

// ---------------------------------------------------------------- merged: LoRA fold (per-layer JIT) + LN1
// blocks [0,1536): fold  |  blocks [1536, 1536+2048): LN1 row = blockIdx.x-1536
__global__ __launch_bounds__(256) void fold_ln_k(
    const float* __restrict__ aw, const float* __restrict__ pw,
    const float* __restrict__ fw, const float* __restrict__ mw,
    const unsigned short* __restrict__ Lb,
    unsigned short* __restrict__ oq, unsigned short* __restrict__ op_,
    unsigned short* __restrict__ of, unsigned short* __restrict__ om,
    const float* __restrict__ hln, const float* __restrict__ lnw,
    const float* __restrict__ lnb, unsigned short* __restrict__ xout) {
  __shared__ unsigned short dl[64 * 128];  // 16KB (fold); LN reuses first 32B
  const int tid = threadIdx.x;
  if (blockIdx.x >= 1536) {
    // ---- LN1 path
    const int row = blockIdx.x - 1536;
    const float* xr = hln + (size_t)row * DD;
    const float4 v = *(const float4*)(xr + tid * 4);
    float s = v.x + v.y + v.z + v.w;
    float ss = v.x * v.x + v.y * v.y + v.z * v.z + v.w * v.w;
#pragma unroll
    for (int off = 32; off > 0; off >>= 1) {
      s += __shfl_down(s, off);
      ss += __shfl_down(ss, off);
    }
    float* red = (float*)dl;
    const int wid = tid >> 6;
    if ((tid & 63) == 0) { red[wid] = s; red[4 + wid] = ss; }
    __syncthreads();
    s = red[0] + red[1] + red[2] + red[3];
    ss = red[4] + red[5] + red[6] + red[7];
    const float mean = s * (1.f / DD);
    const float var = ss * (1.f / DD) - mean * mean;
    const float rstd = rsqrtf(var + 1e-5f);
    const float4 wv = *(const float4*)(lnw + tid * 4);
    const float4 bv = *(const float4*)(lnb + tid * 4);
    ushort4 o;
    o.x = f2bf((v.x - mean) * rstd * wv.x + bv.x);
    o.y = f2bf((v.y - mean) * rstd * wv.y + bv.y);
    o.z = f2bf((v.z - mean) * rstd * wv.z + bv.z);
    o.w = f2bf((v.w - mean) * rstd * wv.w + bv.w);
    *(ushort4*)(xout + (size_t)row * DD + tid * 4) = o;
    return;
  }
  // ---- fold path
  const int lid = blockIdx.x;  // 0..1535
  const float* W;
  unsigned short* out;
  const unsigned short *Bl, *Al;
  int K, n0, kblk;
  if (lid < 384) {
    W = aw; out = oq; Bl = Lb + 1024 * 32; Al = Lb;
    K = DD; n0 = (lid >> 3) * 64; kblk = (lid & 7) * 128;
  } else if (lid < 512) {
    const int t = lid - 384;
    W = pw; out = op_; Bl = Lb + 5120 * 32; Al = Lb + 4096 * 32;
    K = DD; n0 = (t >> 3) * 64; kblk = (t & 7) * 128;
  } else if (lid < 1024) {
    const int t = lid - 512;
    W = fw; out = of; Bl = Lb + 7168 * 32; Al = Lb + 6144 * 32;
    K = DD; n0 = (t >> 3) * 64; kblk = (t & 7) * 128;
  } else {
    const int t = lid - 1024;
    W = mw; out = om; Bl = Lb + 15360 * 32; Al = Lb + 11264 * 32;
    K = 4 * DD; n0 = (t >> 5) * 64; kblk = (t & 31) * 128;
  }
  const int w = tid >> 6, l = tid & 63;
  const int lr16 = l & 15, lg = l >> 4;
  const int nloc = w * 16 + lr16;
  const bf16x8 bfrag = *(const bf16x8*)(Bl + (size_t)(n0 + nloc) * 32 + lg * 8);
#pragma unroll
  for (int kc = 0; kc < 8; ++kc) {
    const bf16x8 afr = *(const bf16x8*)(Al + (size_t)(kblk + kc * 16 + lr16) * 32 + lg * 8);
    f32x4 acc = {};
    acc = __builtin_amdgcn_mfma_f32_16x16x32_bf16(afr, bfrag, acc, 0, 0, 0);
    ushort4 dv;
    dv.x = f2bf(2.f * acc[0]); dv.y = f2bf(2.f * acc[1]);
    dv.z = f2bf(2.f * acc[2]); dv.w = f2bf(2.f * acc[3]);
    const unsigned int byte = ((unsigned)(nloc * 256 + kc * 32 + lg * 8)) ^
                              (((unsigned)nloc & 3u) << 5);
    *(ushort4*)((char*)dl + byte) = dv;
  }
  __syncthreads();
  float4 wv[8];
#pragma unroll
  for (int it = 0; it < 8; ++it) {
    const int flat = it * 1024 + tid * 4;
    const int row = flat >> 7;
    const int k = flat & 127;
    wv[it] = *(const float4*)(W + (size_t)(n0 + row) * K + kblk + k);
  }
  asm volatile("s_waitcnt vmcnt(0)" ::: "memory");
#pragma unroll
  for (int it = 0; it < 8; ++it) {
    const int flat = it * 1024 + tid * 4;
    const int row = flat >> 7;
    const int k = flat & 127;
    const unsigned int byte = ((unsigned)(row * 256 + k * 2)) ^
                              (((unsigned)row & 3u) << 5);
    const ushort4 dv = *(const ushort4*)((const char*)dl + byte);
    ushort4 o;
    o.x = f2bf(wv[it].x + bf2f(dv.x));
    o.y = f2bf(wv[it].y + bf2f(dv.y));
    o.z = f2bf(wv[it].z + bf2f(dv.z));
    o.w = f2bf(wv[it].w + bf2f(dv.w));
    *(ushort4*)(out + (size_t)(n0 + row) * K + kblk + k) = o;
  }
}

// ---------------------------------------------------------------- unified bf16 MFMA GEMM
// Single-buffer, templated BK (64/128/256), 4 waves (2x2), XOR-swizzled LDS, XCD chunk swizzle.
template <int BMt, int BNt, int BKt, int MODE>
__global__ __launch_bounds__(256) void gemm_t(const unsigned short* __restrict__ A,
                                              const unsigned short* __restrict__ Wt,
                                              const float* __restrict__ bias,
                                              const float* __restrict__ res,
                                              float* __restrict__ Cf,
                                              unsigned short* __restrict__ Cb,
                                              unsigned short* __restrict__ vt,
                                              int M, int N, int K) {
  constexpr int MI2 = BMt / 32, NJ2 = BNt / 32;
  constexpr int SB = BKt * 2;          // row stride bytes
  constexpr int SL = BKt / 8;          // 16B slots per row
  constexpr int RC = 1024 / SB;        // rows per 1KB chunk
  constexpr int CAw = BMt / RC / 4;    // A chunks per wave
  constexpr int CBw = BNt / RC / 4;
  __shared__ unsigned short As[BMt * BKt];
  __shared__ unsigned short Bs[BNt * BKt];
  const int tid = threadIdx.x;
  const int w = tid >> 6, l = tid & 63;
  const int gx = gridDim.x;
  const int bid = blockIdx.y * gx + blockIdx.x;
  const int cpx = (gx * gridDim.y) >> 3;
  const int logical = (bid & 7) * cpx + (bid >> 3);
  const int bm = (logical / gx) * BMt, bn = (logical % gx) * BNt;
  const int wr = w >> 1, wc = w & 1;
  const int lr16 = l & 15, lg = l >> 4, l7 = l & 7;
  const int rin = l / SL;
  const int slot = l % SL;
  f32x4 acc[MI2][NJ2] = {};
  for (int k0 = 0; k0 < K; k0 += BKt) {
    __syncthreads();
#pragma unroll
    for (int i = 0; i < CAw; ++i) {
      const int ch = w * CAw + i;
      const int row = ch * RC + rin;
      gload_lds16(A + (size_t)(bm + row) * K + k0 + ((slot ^ (row & 7)) * 8),
                  (char*)As + ch * 1024);
    }
#pragma unroll
    for (int i = 0; i < CBw; ++i) {
      const int ch = w * CBw + i;
      const int row = ch * RC + rin;
      gload_lds16(Wt + (size_t)(bn + row) * K + k0 + ((slot ^ (row & 7)) * 8),
                  (char*)Bs + ch * 1024);
    }
    __syncthreads();
#pragma unroll
    for (int kk = 0; kk < BKt / 32; ++kk) {
      bf16x8 af[MI2], bfr[NJ2];
      const int q = (kk * 4 + lg) ^ l7;
#pragma unroll
      for (int mi = 0; mi < MI2; ++mi)
        af[mi] = *(const bf16x8*)((const char*)As +
            (wr * (BMt / 2) + mi * 16 + lr16) * SB + q * 16);
#pragma unroll
      for (int nj = 0; nj < NJ2; ++nj)
        bfr[nj] = *(const bf16x8*)((const char*)Bs +
            (wc * (BNt / 2) + nj * 16 + lr16) * SB + q * 16);
#pragma unroll
      for (int mi = 0; mi < MI2; ++mi)
#pragma unroll
        for (int nj = 0; nj < NJ2; ++nj)
          acc[mi][nj] = __builtin_amdgcn_mfma_f32_16x16x32_bf16(
              af[mi], bfr[nj], acc[mi][nj], 0, 0, 0);
    }
  }
  const int cr = lg * 4;
  const int cc = lr16;
#pragma unroll
  for (int mi = 0; mi < MI2; ++mi) {
    const int gr0 = bm + wr * (BMt / 2) + mi * 16 + cr;
#pragma unroll
    for (int nj = 0; nj < NJ2; ++nj) {
      const int gc = bn + wc * (BNt / 2) + nj * 16 + cc;
      const float bv = bias[gc];
      if (MODE == 3) {
        if (gc < 2048) {
#pragma unroll
          for (int r = 0; r < 4; ++r)
            Cb[(size_t)(gr0 + r) * 2048 + gc] = f2bf(acc[mi][nj][r] + bv);
        } else {
          const int hv = gc - 2048;
          const int b_ = gr0 >> 10, t0 = gr0 & 1023;
          ushort4 u;
          u.x = f2bf(acc[mi][nj][0] + bv); u.y = f2bf(acc[mi][nj][1] + bv);
          u.z = f2bf(acc[mi][nj][2] + bv); u.w = f2bf(acc[mi][nj][3] + bv);
          *(ushort4*)(vt + ((size_t)(b_ * 1024 + hv)) * 1024 + t0) = u;
        }
      } else if (MODE == 1) {
#pragma unroll
        for (int r = 0; r < 4; ++r) {
          const size_t idx = (size_t)(gr0 + r) * N + gc;
          Cf[idx] = acc[mi][nj][r] + bv + res[idx];
        }
      } else {  // MODE 2
#pragma unroll
        for (int r = 0; r < 4; ++r) {
          float v = acc[mi][nj][r] + bv;
          v = 0.5f * v * (1.f + erff(v * 0.70710678118654752f));
          Cb[(size_t)(gr0 + r) * N + gc] = f2bf(v);
        }
      }
    }
  }
}

// ---------------------------------------------------------------- MFMA flash attention
#define SM_SCALE_LOG2E 0.18033688011112042f  // log2(e)/8
__global__ __launch_bounds__(256) void attn3_k(const unsigned short* __restrict__ qk,
                                               const unsigned short* __restrict__ vt,
                                               unsigned short* __restrict__ out) {
  const int qt = 15 - blockIdx.x;
  const int bh = blockIdx.y;
  const int b = bh >> 4, hh = bh & 15;
  const int tid = threadIdx.x;
  const int w = tid >> 6, l = tid & 63;
  const int lg = l >> 4;
  const int lr = l & 15;

  __shared__ unsigned short Kt[2][64 * 64];
  __shared__ unsigned short Vb[2][64 * 64];
  __shared__ unsigned short Pb[4][16 * 64];

  bf16x8 qf[2];
  {
    const unsigned short* qp =
        qk + ((size_t)(b * TT + qt * 64 + w * 16 + lr)) * 2048 + hh * 64 + lg * 8;
    qf[0] = *(const bf16x8*)(qp);
    qf[1] = *(const bf16x8*)(qp + 32);
  }
  f32x4 oacc[4] = {};
  float mrow[4] = {-1e30f, -1e30f, -1e30f, -1e30f};
  float lrow[4] = {0.f, 0.f, 0.f, 0.f};

  auto stage = [&](int buf, int kt) {
#pragma unroll
    for (int oo = 0; oo < 2; ++oo) {
      const int o = w + oo * 4;
      const int row = o * 8 + (l >> 3);
      const int sc = ((l & 7) ^ (l >> 3)) * 8;
      const unsigned short* ks =
          qk + ((size_t)(b * TT + kt * 64 + row)) * 2048 + 1024 + hh * 64 + sc;
      gload_lds16(ks, (char*)&Kt[buf][0] + o * 1024);
      const unsigned short* vs =
          vt + ((size_t)(bh * 64 + row)) * 1024 + kt * 64 + sc;
      gload_lds16(vs, (char*)&Vb[buf][0] + o * 1024);
    }
  };

  stage(0, 0);
  int cur = 0;
  unsigned short* Pw = &Pb[w][0];
  const int qlocal = w * 16 + lg * 4;

  for (int kt = 0; kt <= qt; ++kt) {
    __syncthreads();
    if (kt < qt) stage(cur ^ 1, kt + 1);
    const unsigned short* Kb_ = &Kt[cur][0];
    const unsigned short* Vb_ = &Vb[cur][0];
    const int effc = lr & 7;

    f32x4 s[4];
#pragma unroll
    for (int j = 0; j < 4; ++j) {
      f32x4 sj = {};
#pragma unroll
      for (int ks = 0; ks < 2; ++ks) {
        const bf16x8 kf = *(const bf16x8*)((const char*)Kb_ + (j * 16 + lr) * 128 +
                                           (((ks * 4 + lg) ^ effc) * 16));
        sj = __builtin_amdgcn_mfma_f32_16x16x32_bf16(qf[ks], kf, sj, 0, 0, 0);
      }
      s[j] = sj;
    }

    const bool last = (kt == qt);
    float tv[4][4];
#pragma unroll
    for (int j = 0; j < 4; ++j)
#pragma unroll
      for (int r = 0; r < 4; ++r) {
        float v = s[j][r] * SM_SCALE_LOG2E;
        if (last && (j * 16 + lr > qlocal + r)) v = -1e30f;
        tv[j][r] = v;
      }
    float corr[4];
#pragma unroll
    for (int r = 0; r < 4; ++r) {
      float mx = fmaxf(fmaxf(tv[0][r], tv[1][r]), fmaxf(tv[2][r], tv[3][r]));
      mx = fmaxf(mx, __shfl_xor(mx, 1));
      mx = fmaxf(mx, __shfl_xor(mx, 2));
      mx = fmaxf(mx, __shfl_xor(mx, 4));
      mx = fmaxf(mx, __shfl_xor(mx, 8));
      const float mn = fmaxf(mrow[r], mx);
      corr[r] = exp2f(mrow[r] - mn);
      mrow[r] = mn;
      lrow[r] *= corr[r];
    }
#pragma unroll
    for (int dt = 0; dt < 4; ++dt) {
      oacc[dt][0] *= corr[0]; oacc[dt][1] *= corr[1];
      oacc[dt][2] *= corr[2]; oacc[dt][3] *= corr[3];
    }
#pragma unroll
    for (int j = 0; j < 4; ++j)
#pragma unroll
      for (int r = 0; r < 4; ++r) {
        const float p = exp2f(tv[j][r] - mrow[r]);
        lrow[r] += p;
        const int q = lg * 4 + r;
        const int kv = j * 16 + lr;
        *(unsigned short*)((char*)Pw + q * 128 + ((kv * 2) ^ ((q & 7) << 4))) = f2bf(p);
      }
    asm volatile("s_waitcnt lgkmcnt(0)" ::: "memory");
    __builtin_amdgcn_sched_barrier(0);

#pragma unroll
    for (int ks = 0; ks < 2; ++ks) {
      const bf16x8 pf = *(const bf16x8*)((const char*)Pw + lr * 128 +
                                         (((ks * 4 + lg) ^ effc) * 16));
#pragma unroll
      for (int dt = 0; dt < 4; ++dt) {
        const bf16x8 vf = *(const bf16x8*)((const char*)Vb_ + (dt * 16 + lr) * 128 +
                                           (((ks * 4 + lg) ^ effc) * 16));
        oacc[dt] = __builtin_amdgcn_mfma_f32_16x16x32_bf16(pf, vf, oacc[dt], 0, 0, 0);
      }
    }
    cur ^= 1;
  }

#pragma unroll
  for (int r = 0; r < 4; ++r) {
    float lv = lrow[r];
    lv += __shfl_xor(lv, 1);
    lv += __shfl_xor(lv, 2);
    lv += __shfl_xor(lv, 4);
    lv += __shfl_xor(lv, 8);
    lrow[r] = 1.f / lv;
  }
  unsigned short* ob = out + ((size_t)(b * TT + qt * 64 + w * 16 + lg * 4)) * 1024 + hh * 64 + lr;
#pragma unroll
  for (int r = 0; r < 4; ++r)
#pragma unroll
    for (int dt = 0; dt < 4; ++dt)
      ob[(size_t)r * 1024 + dt * 16] = f2bf(oacc[dt][r] * lrow[r]);
}

// ---------------------------------------------------------------- host
extern "C" void kernel_launch(void* const* d_in, const int* in_sizes, int n_in,
                              void* d_out, int out_size, void* d_ws, size_t ws_size,
                              hipStream_t stream) {
  (void)in_sizes; (void)n_in; (void)out_size; (void)ws_size;
  const int* ids = (const int*)d_in[0];
  const float* wte = (const float*)d_in[1];
  const float* wpe = (const float*)d_in[2];
  const float* ln1w = (const float*)d_in[3];
  const float* ln1b = (const float*)d_in[4];
  const float* attnw = (const float*)d_in[5];
  const float* attnb = (const float*)d_in[6];
  const float* attnla = (const float*)d_in[7];
  const float* attnlb = (const float*)d_in[8];
  const float* projw = (const float*)d_in[9];
  const float* projb = (const float*)d_in[10];
  const float* projla = (const float*)d_in[11];
  const float* projlb = (const float*)d_in[12];
  const float* ln2w = (const float*)d_in[13];
  const float* ln2b = (const float*)d_in[14];
  const float* fcw = (const float*)d_in[15];
  const float* fcb = (const float*)d_in[16];
  const float* fcla = (const float*)d_in[17];
  const float* fclb = (const float*)d_in[18];
  const float* mpw = (const float*)d_in[19];
  const float* mpb = (const float*)d_in[20];
  const float* mpla = (const float*)d_in[21];
  const float* mplb = (const float*)d_in[22];
  const float* lnfw = (const float*)d_in[23];
  const float* lnfb = (const float*)d_in[24];

  char* ws = (char*)d_ws;
  float* h = (float*)ws;                        ws += (size_t)MM * DD * 4;       // 8MB
  unsigned short* x = (unsigned short*)ws;      ws += (size_t)MM * DD * 2;       // 4MB
  unsigned short* qkb = (unsigned short*)ws;    ws += (size_t)MM * 2 * DD * 2;   // 8MB
  unsigned short* vtb = (unsigned short*)ws;    ws += (size_t)MM * DD * 2;       // 4MB
  unsigned short* ho = (unsigned short*)ws;     ws += (size_t)MM * DD * 2;       // 4MB
  unsigned short* hm = (unsigned short*)ws;     ws += (size_t)MM * 4 * DD * 2;   // 16MB
  unsigned short* wqkv = (unsigned short*)ws;   ws += (size_t)3 * DD * DD * 2;   // 6MB (reused per layer)
  unsigned short* wproj = (unsigned short*)ws;  ws += (size_t)DD * DD * 2;       // 2MB
  unsigned short* wfc = (unsigned short*)ws;    ws += (size_t)4 * DD * DD * 2;   // 8MB
  unsigned short* wmp = (unsigned short*)ws;    ws += (size_t)DD * 4 * DD * 2;   // 8MB
  unsigned short* loraP = (unsigned short*)ws;  ws += (size_t)NL * 16384 * 32 * 2;  // 12.6MB

  // embed + LoRA pack (independent) in one launch
  hipLaunchKernelGGL(embed_cvt_k, dim3(MM * DD / 256 + NL * 16384 * 32 / 256), dim3(256),
                     0, stream, ids, wte, wpe, h,
                     attnla, attnlb, projla, projlb, fcla, fclb, mpla, mplb, loraP);

  for (int l = 0; l < NL; ++l) {
    const float* ab = attnb + (size_t)l * 3 * DD;
    const float* pb = projb + (size_t)l * DD;
    const float* fb = fcb + (size_t)l * 4 * DD;
    const float* mb = mpb + (size_t)l * DD;

    // [JIT LoRA fold (this layer) || LN1(h)] in one launch
    hipLaunchKernelGGL(fold_ln_k, dim3(1536 + MM), dim3(256), 0, stream,
                       attnw + (size_t)l * 3 * DD * DD, projw + (size_t)l * DD * DD,
                       fcw + (size_t)l * 4 * DD * DD, mpw + (size_t)l * DD * 4 * DD,
                       loraP + (size_t)l * 16384 * 32, wqkv, wproj, wfc, wmp,
                       h, ln1w + (size_t)l * DD, ln1b + (size_t)l * DD, x);

    // qkv = x @ wqkv^T + ab -> qkb (Q,K) + vtb (V transposed)   [BK=128]
    hipLaunchKernelGGL((gemm_t<128, 64, 128, 3>), dim3(3 * DD / 64, MM / 128), dim3(256), 0,
                       stream, x, wqkv, ab, (const float*)nullptr, (float*)nullptr,
                       qkb, vtb, MM, 3 * DD, DD);
    // o = attention
    hipLaunchKernelGGL(attn3_k, dim3(TT / 64, NB * NH), dim3(256), 0, stream, qkb, vtb, ho);
    // h = h + o @ wproj^T + pb   [BK=256]
    hipLaunchKernelGGL((gemm_t<64, 64, 256, 1>), dim3(DD / 64, MM / 64), dim3(256), 0,
                       stream, ho, wproj, pb, h, h, (unsigned short*)nullptr,
                       (unsigned short*)nullptr, MM, DD, DD);
    // x = LN2(h)
    hipLaunchKernelGGL(ln_bf_k, dim3(MM), dim3(256), 0, stream, h,
                       ln2w + (size_t)l * DD, ln2b + (size_t)l * DD, x);
    // m = gelu(x @ wfc^T + fb)   [128x128 tile, BK=128]
    hipLaunchKernelGGL((gemm_t<128, 128, 128, 2>), dim3(4 * DD / 128, MM / 128), dim3(256), 0,
                       stream, x, wfc, fb, (const float*)nullptr, (float*)nullptr, hm,
                       (unsigned short*)nullptr, MM, 4 * DD, DD);
    // h = h + m @ wmp^T + mb   [BK=256]
    hipLaunchKernelGGL((gemm_t<64, 64, 256, 1>), dim3(DD / 64, MM / 64), dim3(256), 0,
                       stream, hm, wmp, mb, h, h, (unsigned short*)nullptr,
                       (unsigned short*)nullptr, MM, DD, 4 * DD);
  }

  hipLaunchKernelGGL(ln_f_k, dim3(MM), dim3(256), 0, stream, h, lnfw, lnfb, (float*)d_out);
}

// Round 14
// 1741.826 us; speedup vs baseline: 1.3519x; 1.0248x over previous
//
#include <hip/hip_runtime.h>
#include <math.h>

#define TT 1024
#define DD 1024
#define NH 16
#define NB 2
#define NL 12
#define RR 32
#define MM (NB * TT)  // 2048

typedef __attribute__((ext_vector_type(8))) short bf16x8;
typedef __attribute__((ext_vector_type(4))) float f32x4;

__device__ __forceinline__ unsigned short f2bf(float f) {
  unsigned int u = __float_as_uint(f);
  u = (u + 0x7FFFu + ((u >> 16) & 1u)) >> 16;
  return (unsigned short)u;
}
__device__ __forceinline__ float bf2f(unsigned short u) {
  return __uint_as_float((unsigned int)u << 16);
}

typedef __attribute__((address_space(1))) void gvoid;
typedef __attribute__((address_space(3))) void lvoid;
__device__ __forceinline__ void gload_lds16(const void* g, void* l) {
  __builtin_amdgcn_global_load_lds((gvoid*)g, (lvoid*)l, 16, 0, 0);
}

// ---------------------------------------------------------------- embed + LoRA cvt (merged, independent)
__global__ __launch_bounds__(256) void embed_cvt_k(
    const int* __restrict__ ids, const float* __restrict__ wte,
    const float* __restrict__ wpe, float* __restrict__ h,
    const float* __restrict__ ala, const float* __restrict__ alb,
    const float* __restrict__ pla, const float* __restrict__ plb,
    const float* __restrict__ fla, const float* __restrict__ flb,
    const float* __restrict__ mla, const float* __restrict__ mlb,
    unsigned short* __restrict__ out) {
  if (blockIdx.x < MM * DD / 256) {
    const int i = blockIdx.x * 256 + threadIdx.x;
    const int row = i >> 10;
    const int d = i & 1023;
    const int t = row & (TT - 1);
    const int id = ids[row];
    h[i] = wte[(size_t)id * DD + d] + wpe[(size_t)t * DD + d];
    return;
  }
  const int g = (blockIdx.x - MM * DD / 256) * 256 + threadIdx.x;  // over NL*16384*32
  const int layer = g >> 19;
  const int rem = g & 524287;
  const int row = rem >> 5;
  const int r = rem & 31;
  float v;
  if (row < 1024)       v = ala[(size_t)layer * 32 * 1024 + r * 1024 + row];
  else if (row < 4096)  v = alb[(size_t)layer * 3072 * 32 + (row - 1024) * 32 + r];
  else if (row < 5120)  v = pla[(size_t)layer * 32 * 1024 + r * 1024 + (row - 4096)];
  else if (row < 6144)  v = plb[(size_t)layer * 1024 * 32 + (row - 5120) * 32 + r];
  else if (row < 7168)  v = fla[(size_t)layer * 32 * 1024 + r * 1024 + (row - 6144)];
  else if (row < 11264) v = flb[(size_t)layer * 4096 * 32 + (row - 7168) * 32 + r];
  else if (row < 15360) v = mla[(size_t)layer * 32 * 4096 + r * 4096 + (row - 11264)];
  else                  v = mlb[(size_t)layer * 1024 * 32 + (row - 15360) * 32 + r];
  out[g] = f2bf(v);
}

// ---------------------------------------------------------------- layernorm (fp32 in, bf16 out)
__global__ __launch_bounds__(256) void ln_bf_k(const float* __restrict__ x,
                                               const float* __restrict__ w,
                                               const float* __restrict__ b,
                                               unsigned short* __restrict__ out) {
  const int row = blockIdx.x;
  const float* xr = x + (size_t)row * DD;
  const float4 v = *(const float4*)(xr + threadIdx.x * 4);
  float s = v.x + v.y + v.z + v.w;
  float ss = v.x * v.x + v.y * v.y + v.z * v.z + v.w * v.w;
#pragma unroll
  for (int off = 32; off > 0; off >>= 1) {
    s += __shfl_down(s, off);
    ss += __shfl_down(ss, off);
  }
  __shared__ float rs[4], rss[4];
  const int wid = threadIdx.x >> 6;
  if ((threadIdx.x & 63) == 0) { rs[wid] = s; rss[wid] = ss; }
  __syncthreads();
  s = rs[0] + rs[1] + rs[2] + rs[3];
  ss = rss[0] + rss[1] + rss[2] + rss[3];
  const float mean = s * (1.f / DD);
  const float var = ss * (1.f / DD) - mean * mean;
  const float rstd = rsqrtf(var + 1e-5f);
  const float4 wv = *(const float4*)(w + threadIdx.x * 4);
  const float4 bv = *(const float4*)(b + threadIdx.x * 4);
  ushort4 o;
  o.x = f2bf((v.x - mean) * rstd * wv.x + bv.x);
  o.y = f2bf((v.y - mean) * rstd * wv.y + bv.y);
  o.z = f2bf((v.z - mean) * rstd * wv.z + bv.z);
  o.w = f2bf((v.w - mean) * rstd * wv.w + bv.w);
  *(ushort4*)(out + (size_t)row * DD + threadIdx.x * 4) = o;
}

// final layernorm fp32 out
__global__ __launch_bounds__(256) void ln_f_k(const float* __restrict__ x,
                                              const float* __restrict__ w,
                                              const float* __restrict__ b,
                                              float* __restrict__ out) {
  const int row = blockIdx.x;
  const float* xr = x + (size_t)row * DD;
  const float4 v = *(const float4*)(xr + threadIdx.x * 4);
  float s = v.x + v.y + v.z + v.w;
  float ss = v.x * v.x + v.y * v.y + v.z * v.z + v.w * v.w;
#pragma unroll
  for (int off = 32; off > 0; off >>= 1) {
    s += __shfl_down(s, off);
    ss += __shfl_down(ss, off);
  }
  __shared__ float rs[4], rss[4];
  const int wid = threadIdx.x >> 6;
  if ((threadIdx.x & 63) == 0) { rs[wid] = s; rss[wid] = ss; }
  __syncthreads();
  s = rs[0] + rs[1] + rs[2] + rs[3];
  ss = rss[4 - 4] + rss[1] + rss[2] + rss[3];
  const float mean = s * (1.f / DD);
  const float var = ss * (1.f / DD) - mean * mean;
  const float rstd = rsqrtf(var + 1e-5f);
  const float4 wv = *(const float4*)(w + threadIdx.x * 4);
  const float4 bv = *(const float4*)(b + threadIdx.x * 4);
  float4 o;
  o.x = (v.x - mean) * rstd * wv.x + bv.x;
  o.y = (v.y - mean) * rstd * wv.y + bv.y;
  o.z = (v.z - mean) * rstd * wv.z + bv.z;
  o.w = (v.w - mean) * rstd * wv.w + bv.w;
  *(float4*)(out + (size_t)row * DD + threadIdx.x * 4) = o;
}

// ---------------------------------------------------------------- merged: LoRA fold (per-layer JIT) + LN1
__global__ __launch_bounds__(256) void fold_ln_k(
    const float* __restrict__ aw, const float* __restrict__ pw,
    const float* __restrict__ fw, const float* __restrict__ mw,
    const unsigned short* __restrict__ Lb,
    unsigned short* __restrict__ oq, unsigned short* __restrict__ op_,
    unsigned short* __restrict__ of, unsigned short* __restrict__ om,
    const float* __restrict__ hln, const float* __restrict__ lnw,
    const float* __restrict__ lnb, unsigned short* __restrict__ xout) {
  __shared__ unsigned short dl[64 * 128];  // 16KB (fold); LN reuses first 32B
  const int tid = threadIdx.x;
  if (blockIdx.x >= 1536) {
    const int row = blockIdx.x - 1536;
    const float* xr = hln + (size_t)row * DD;
    const float4 v = *(const float4*)(xr + tid * 4);
    float s = v.x + v.y + v.z + v.w;
    float ss = v.x * v.x + v.y * v.y + v.z * v.z + v.w * v.w;
#pragma unroll
    for (int off = 32; off > 0; off >>= 1) {
      s += __shfl_down(s, off);
      ss += __shfl_down(ss, off);
    }
    float* red = (float*)dl;
    const int wid = tid >> 6;
    if ((tid & 63) == 0) { red[wid] = s; red[4 + wid] = ss; }
    __syncthreads();
    s = red[0] + red[1] + red[2] + red[3];
    ss = red[4] + red[5] + red[6] + red[7];
    const float mean = s * (1.f / DD);
    const float var = ss * (1.f / DD) - mean * mean;
    const float rstd = rsqrtf(var + 1e-5f);
    const float4 wv = *(const float4*)(lnw + tid * 4);
    const float4 bv = *(const float4*)(lnb + tid * 4);
    ushort4 o;
    o.x = f2bf((v.x - mean) * rstd * wv.x + bv.x);
    o.y = f2bf((v.y - mean) * rstd * wv.y + bv.y);
    o.z = f2bf((v.z - mean) * rstd * wv.z + bv.z);
    o.w = f2bf((v.w - mean) * rstd * wv.w + bv.w);
    *(ushort4*)(xout + (size_t)row * DD + tid * 4) = o;
    return;
  }
  const int lid = blockIdx.x;  // 0..1535
  const float* W;
  unsigned short* out;
  const unsigned short *Bl, *Al;
  int K, n0, kblk;
  if (lid < 384) {
    W = aw; out = oq; Bl = Lb + 1024 * 32; Al = Lb;
    K = DD; n0 = (lid >> 3) * 64; kblk = (lid & 7) * 128;
  } else if (lid < 512) {
    const int t = lid - 384;
    W = pw; out = op_; Bl = Lb + 5120 * 32; Al = Lb + 4096 * 32;
    K = DD; n0 = (t >> 3) * 64; kblk = (t & 7) * 128;
  } else if (lid < 1024) {
    const int t = lid - 512;
    W = fw; out = of; Bl = Lb + 7168 * 32; Al = Lb + 6144 * 32;
    K = DD; n0 = (t >> 3) * 64; kblk = (t & 7) * 128;
  } else {
    const int t = lid - 1024;
    W = mw; out = om; Bl = Lb + 15360 * 32; Al = Lb + 11264 * 32;
    K = 4 * DD; n0 = (t >> 5) * 64; kblk = (t & 31) * 128;
  }
  const int w = tid >> 6, l = tid & 63;
  const int lr16 = l & 15, lg = l >> 4;
  const int nloc = w * 16 + lr16;
  const bf16x8 bfrag = *(const bf16x8*)(Bl + (size_t)(n0 + nloc) * 32 + lg * 8);
#pragma unroll
  for (int kc = 0; kc < 8; ++kc) {
    const bf16x8 afr = *(const bf16x8*)(Al + (size_t)(kblk + kc * 16 + lr16) * 32 + lg * 8);
    f32x4 acc = {};
    acc = __builtin_amdgcn_mfma_f32_16x16x32_bf16(afr, bfrag, acc, 0, 0, 0);
    ushort4 dv;
    dv.x = f2bf(2.f * acc[0]); dv.y = f2bf(2.f * acc[1]);
    dv.z = f2bf(2.f * acc[2]); dv.w = f2bf(2.f * acc[3]);
    const unsigned int byte = ((unsigned)(nloc * 256 + kc * 32 + lg * 8)) ^
                              (((unsigned)nloc & 3u) << 5);
    *(ushort4*)((char*)dl + byte) = dv;
  }
  __syncthreads();
  float4 wv[8];
#pragma unroll
  for (int it = 0; it < 8; ++it) {
    const int flat = it * 1024 + tid * 4;
    const int row = flat >> 7;
    const int k = flat & 127;
    wv[it] = *(const float4*)(W + (size_t)(n0 + row) * K + kblk + k);
  }
  asm volatile("s_waitcnt vmcnt(0)" ::: "memory");
#pragma unroll
  for (int it = 0; it < 8; ++it) {
    const int flat = it * 1024 + tid * 4;
    const int row = flat >> 7;
    const int k = flat & 127;
    const unsigned int byte = ((unsigned)(row * 256 + k * 2)) ^
                              (((unsigned)row & 3u) << 5);
    const ushort4 dv = *(const ushort4*)((const char*)dl + byte);
    ushort4 o;
    o.x = f2bf(wv[it].x + bf2f(dv.x));
    o.y = f2bf(wv[it].y + bf2f(dv.y));
    o.z = f2bf(wv[it].z + bf2f(dv.z));
    o.w = f2bf(wv[it].w + bf2f(dv.w));
    *(ushort4*)(out + (size_t)(n0 + row) * K + kblk + k) = o;
  }
}

// ---------------------------------------------------------------- unified bf16 MFMA GEMM
template <int BMt, int BNt, int BKt, int MODE>
__global__ __launch_bounds__(256) void gemm_t(const unsigned short* __restrict__ A,
                                              const unsigned short* __restrict__ Wt,
                                              const float* __restrict__ bias,
                                              const float* __restrict__ res,
                                              float* __restrict__ Cf,
                                              unsigned short* __restrict__ Cb,
                                              unsigned short* __restrict__ vt,
                                              int M, int N, int K) {
  constexpr int MI2 = BMt / 32, NJ2 = BNt / 32;
  constexpr int SB = BKt * 2;          // row stride bytes
  constexpr int SL = BKt / 8;          // 16B slots per row
  constexpr int RC = 1024 / SB;        // rows per 1KB chunk
  constexpr int CAw = BMt / RC / 4;    // A chunks per wave
  constexpr int CBw = BNt / RC / 4;
  __shared__ unsigned short As[BMt * BKt];
  __shared__ unsigned short Bs[BNt * BKt];
  const int tid = threadIdx.x;
  const int w = tid >> 6, l = tid & 63;
  const int gx = gridDim.x;
  const int bid = blockIdx.y * gx + blockIdx.x;
  const int cpx = (gx * gridDim.y) >> 3;
  const int logical = (bid & 7) * cpx + (bid >> 3);
  const int bm = (logical / gx) * BMt, bn = (logical % gx) * BNt;
  const int wr = w >> 1, wc = w & 1;
  const int lr16 = l & 15, lg = l >> 4, l7 = l & 7;
  const int rin = l / SL;
  const int slot = l % SL;
  f32x4 acc[MI2][NJ2] = {};
  for (int k0 = 0; k0 < K; k0 += BKt) {
    __syncthreads();
#pragma unroll
    for (int i = 0; i < CAw; ++i) {
      const int ch = w * CAw + i;
      const int row = ch * RC + rin;
      gload_lds16(A + (size_t)(bm + row) * K + k0 + ((slot ^ (row & 7)) * 8),
                  (char*)As + ch * 1024);
    }
#pragma unroll
    for (int i = 0; i < CBw; ++i) {
      const int ch = w * CBw + i;
      const int row = ch * RC + rin;
      gload_lds16(Wt + (size_t)(bn + row) * K + k0 + ((slot ^ (row & 7)) * 8),
                  (char*)Bs + ch * 1024);
    }
    __syncthreads();
#pragma unroll
    for (int kk = 0; kk < BKt / 32; ++kk) {
      bf16x8 af[MI2], bfr[NJ2];
      const int q = (kk * 4 + lg) ^ l7;
#pragma unroll
      for (int mi = 0; mi < MI2; ++mi)
        af[mi] = *(const bf16x8*)((const char*)As +
            (wr * (BMt / 2) + mi * 16 + lr16) * SB + q * 16);
#pragma unroll
      for (int nj = 0; nj < NJ2; ++nj)
        bfr[nj] = *(const bf16x8*)((const char*)Bs +
            (wc * (BNt / 2) + nj * 16 + lr16) * SB + q * 16);
#pragma unroll
      for (int mi = 0; mi < MI2; ++mi)
#pragma unroll
        for (int nj = 0; nj < NJ2; ++nj)
          acc[mi][nj] = __builtin_amdgcn_mfma_f32_16x16x32_bf16(
              af[mi], bfr[nj], acc[mi][nj], 0, 0, 0);
    }
  }
  const int cr = lg * 4;
  const int cc = lr16;
#pragma unroll
  for (int mi = 0; mi < MI2; ++mi) {
    const int gr0 = bm + wr * (BMt / 2) + mi * 16 + cr;
#pragma unroll
    for (int nj = 0; nj < NJ2; ++nj) {
      const int gc = bn + wc * (BNt / 2) + nj * 16 + cc;
      const float bv = bias[gc];
      if (MODE == 3) {
        if (gc < 2048) {
#pragma unroll
          for (int r = 0; r < 4; ++r)
            Cb[(size_t)(gr0 + r) * 2048 + gc] = f2bf(acc[mi][nj][r] + bv);
        } else {
          const int hv = gc - 2048;
          const int b_ = gr0 >> 10, t0 = gr0 & 1023;
          ushort4 u;
          u.x = f2bf(acc[mi][nj][0] + bv); u.y = f2bf(acc[mi][nj][1] + bv);
          u.z = f2bf(acc[mi][nj][2] + bv); u.w = f2bf(acc[mi][nj][3] + bv);
          *(ushort4*)(vt + ((size_t)(b_ * 1024 + hv)) * 1024 + t0) = u;
        }
      } else if (MODE == 1) {
#pragma unroll
        for (int r = 0; r < 4; ++r) {
          const size_t idx = (size_t)(gr0 + r) * N + gc;
          Cf[idx] = acc[mi][nj][r] + bv + res[idx];
        }
      } else {  // MODE 2
#pragma unroll
        for (int r = 0; r < 4; ++r) {
          float v = acc[mi][nj][r] + bv;
          v = 0.5f * v * (1.f + erff(v * 0.70710678118654752f));
          Cb[(size_t)(gr0 + r) * N + gc] = f2bf(v);
        }
      }
    }
  }
}

// ---------------------------------------------------------------- MFMA flash attention, KVBLK=128
// qk bf16 [B*T, 2048] (Q|K), vt bf16 [B*H, 64, T], out bf16 [B*T, 1024]
// LDS 80KB = K 2x16K (128Brows, swz ^(kv&7)) + V^T 2x16K (256B rows, swz ^(d&15))
//          + P 4x4K (256B rows, swz ^(q&15)).  2 blocks/CU = grid occupancy.
#define SM_SCALE_LOG2E 0.18033688011112042f  // log2(e)/8
__global__ __launch_bounds__(256) void attn4_k(const unsigned short* __restrict__ qk,
                                               const unsigned short* __restrict__ vt,
                                               unsigned short* __restrict__ out) {
  const int qt = 15 - blockIdx.x;  // heavy tiles first
  const int bh = blockIdx.y;
  const int b = bh >> 4, hh = bh & 15;
  const int tid = threadIdx.x;
  const int w = tid >> 6, l = tid & 63;
  const int lg = l >> 4;
  const int lr = l & 15;

  __shared__ unsigned short Kt[2][128 * 64];
  __shared__ unsigned short Vb[2][64 * 128];
  __shared__ unsigned short Pb[4][16 * 128];

  bf16x8 qf[2];
  {
    const unsigned short* qp =
        qk + ((size_t)(b * TT + qt * 64 + w * 16 + lr)) * 2048 + hh * 64 + lg * 8;
    qf[0] = *(const bf16x8*)(qp);
    qf[1] = *(const bf16x8*)(qp + 32);
  }
  f32x4 oacc[4] = {};
  float mrow[4] = {-1e30f, -1e30f, -1e30f, -1e30f};
  float lrow[4] = {0.f, 0.f, 0.f, 0.f};

  auto stage = [&](int buf, int kt2) {
    // K: 16 chunks of (8 kv-rows x 64 d); wave w -> chunks [w*4, w*4+4)
#pragma unroll
    for (int i = 0; i < 4; ++i) {
      const int ch = w * 4 + i;
      const int row = ch * 8 + (l >> 3);
      const int sc = ((l & 7) ^ (l >> 3)) * 8;
      const unsigned short* ks =
          qk + ((size_t)(b * TT + kt2 * 128 + row)) * 2048 + 1024 + hh * 64 + sc;
      gload_lds16(ks, (char*)&Kt[buf][0] + ch * 1024);
    }
    // V^T: 16 chunks of (4 d-rows x 128 kv)
#pragma unroll
    for (int i = 0; i < 4; ++i) {
      const int ch = w * 4 + i;
      const int row = ch * 4 + (l >> 4);
      const int sc = ((l & 15) ^ (row & 15)) * 8;
      const unsigned short* vs =
          vt + ((size_t)(bh * 64 + row)) * 1024 + kt2 * 128 + sc;
      gload_lds16(vs, (char*)&Vb[buf][0] + ch * 1024);
    }
  };

  const int nkt = (qt >> 1) + 1;
  stage(0, 0);
  int cur = 0;
  unsigned short* Pw = &Pb[w][0];
  const int qlocal = w * 16 + lg * 4;

  for (int kt2 = 0; kt2 < nkt; ++kt2) {
    __syncthreads();
    if (kt2 + 1 < nkt) stage(cur ^ 1, kt2 + 1);
    const unsigned short* Kb_ = &Kt[cur][0];
    const unsigned short* Vb_ = &Vb[cur][0];
    const bool last = (kt2 == nkt - 1);

    // S = Q K^T over 128 kv (8 groups of 16)
    f32x4 s[8];
    __builtin_amdgcn_s_setprio(1);
#pragma unroll
    for (int j = 0; j < 8; ++j) {
      f32x4 sj = {};
#pragma unroll
      for (int ks = 0; ks < 2; ++ks) {
        const bf16x8 kf = *(const bf16x8*)((const char*)Kb_ + (j * 16 + lr) * 128 +
                                           (((ks * 4 + lg) ^ (lr & 7)) * 16));
        sj = __builtin_amdgcn_mfma_f32_16x16x32_bf16(qf[ks], kf, sj, 0, 0, 0);
      }
      s[j] = sj;
    }
    __builtin_amdgcn_s_setprio(0);

    // scale + causal mask (diagonal only in last tile)
#pragma unroll
    for (int j = 0; j < 8; ++j)
#pragma unroll
      for (int r = 0; r < 4; ++r) {
        float v = s[j][r] * SM_SCALE_LOG2E;
        if (last && (kt2 * 128 + j * 16 + lr > qt * 64 + qlocal + r)) v = -1e30f;
        s[j][r] = v;
      }
    float corr[4];
#pragma unroll
    for (int r = 0; r < 4; ++r) {
      float mx = s[0][r];
#pragma unroll
      for (int j = 1; j < 8; ++j) mx = fmaxf(mx, s[j][r]);
      mx = fmaxf(mx, __shfl_xor(mx, 1));
      mx = fmaxf(mx, __shfl_xor(mx, 2));
      mx = fmaxf(mx, __shfl_xor(mx, 4));
      mx = fmaxf(mx, __shfl_xor(mx, 8));
      const float mn = fmaxf(mrow[r], mx);
      corr[r] = exp2f(mrow[r] - mn);
      mrow[r] = mn;
      lrow[r] *= corr[r];
    }
#pragma unroll
    for (int dt = 0; dt < 4; ++dt) {
      oacc[dt][0] *= corr[0]; oacc[dt][1] *= corr[1];
      oacc[dt][2] *= corr[2]; oacc[dt][3] *= corr[3];
    }
#pragma unroll
    for (int j = 0; j < 8; ++j)
#pragma unroll
      for (int r = 0; r < 4; ++r) {
        const float p = exp2f(s[j][r] - mrow[r]);
        lrow[r] += p;
        const int q = lg * 4 + r;
        const int kv = j * 16 + lr;
        *(unsigned short*)((char*)Pw + q * 256 + ((kv * 2) ^ ((q & 15) << 4))) = f2bf(p);
      }
    asm volatile("s_waitcnt lgkmcnt(0)" ::: "memory");
    __builtin_amdgcn_sched_barrier(0);

    // O += P V  (k = 128 kv in 4 slabs of 32)
    __builtin_amdgcn_s_setprio(1);
#pragma unroll
    for (int ks = 0; ks < 4; ++ks) {
      const bf16x8 pf = *(const bf16x8*)((const char*)Pw + lr * 256 +
                                         (((ks * 4 + lg) ^ (lr & 15)) * 16));
#pragma unroll
      for (int dt = 0; dt < 4; ++dt) {
        const bf16x8 vf = *(const bf16x8*)((const char*)Vb_ + (dt * 16 + lr) * 256 +
                                           (((ks * 4 + lg) ^ (lr & 15)) * 16));
        oacc[dt] = __builtin_amdgcn_mfma_f32_16x16x32_bf16(pf, vf, oacc[dt], 0, 0, 0);
      }
    }
    __builtin_amdgcn_s_setprio(0);
    cur ^= 1;
  }

#pragma unroll
  for (int r = 0; r < 4; ++r) {
    float lv = lrow[r];
    lv += __shfl_xor(lv, 1);
    lv += __shfl_xor(lv, 2);
    lv += __shfl_xor(lv, 4);
    lv += __shfl_xor(lv, 8);
    lrow[r] = 1.f / lv;
  }
  unsigned short* ob = out + ((size_t)(b * TT + qt * 64 + w * 16 + lg * 4)) * 1024 + hh * 64 + lr;
#pragma unroll
  for (int r = 0; r < 4; ++r)
#pragma unroll
    for (int dt = 0; dt < 4; ++dt)
      ob[(size_t)r * 1024 + dt * 16] = f2bf(oacc[dt][r] * lrow[r]);
}

// ---------------------------------------------------------------- host
extern "C" void kernel_launch(void* const* d_in, const int* in_sizes, int n_in,
                              void* d_out, int out_size, void* d_ws, size_t ws_size,
                              hipStream_t stream) {
  (void)in_sizes; (void)n_in; (void)out_size; (void)ws_size;
  const int* ids = (const int*)d_in[0];
  const float* wte = (const float*)d_in[1];
  const float* wpe = (const float*)d_in[2];
  const float* ln1w = (const float*)d_in[3];
  const float* ln1b = (const float*)d_in[4];
  const float* attnw = (const float*)d_in[5];
  const float* attnb = (const float*)d_in[6];
  const float* attnla = (const float*)d_in[7];
  const float* attnlb = (const float*)d_in[8];
  const float* projw = (const float*)d_in[9];
  const float* projb = (const float*)d_in[10];
  const float* projla = (const float*)d_in[11];
  const float* projlb = (const float*)d_in[12];
  const float* ln2w = (const float*)d_in[13];
  const float* ln2b = (const float*)d_in[14];
  const float* fcw = (const float*)d_in[15];
  const float* fcb = (const float*)d_in[16];
  const float* fcla = (const float*)d_in[17];
  const float* fclb = (const float*)d_in[18];
  const float* mpw = (const float*)d_in[19];
  const float* mpb = (const float*)d_in[20];
  const float* mpla = (const float*)d_in[21];
  const float* mplb = (const float*)d_in[22];
  const float* lnfw = (const float*)d_in[23];
  const float* lnfb = (const float*)d_in[24];

  char* ws = (char*)d_ws;
  float* h = (float*)ws;                        ws += (size_t)MM * DD * 4;       // 8MB
  unsigned short* x = (unsigned short*)ws;      ws += (size_t)MM * DD * 2;       // 4MB
  unsigned short* qkb = (unsigned short*)ws;    ws += (size_t)MM * 2 * DD * 2;   // 8MB
  unsigned short* vtb = (unsigned short*)ws;    ws += (size_t)MM * DD * 2;       // 4MB
  unsigned short* ho = (unsigned short*)ws;     ws += (size_t)MM * DD * 2;       // 4MB
  unsigned short* hm = (unsigned short*)ws;     ws += (size_t)MM * 4 * DD * 2;   // 16MB
  unsigned short* wqkv = (unsigned short*)ws;   ws += (size_t)3 * DD * DD * 2;   // 6MB (reused per layer)
  unsigned short* wproj = (unsigned short*)ws;  ws += (size_t)DD * DD * 2;       // 2MB
  unsigned short* wfc = (unsigned short*)ws;    ws += (size_t)4 * DD * DD * 2;   // 8MB
  unsigned short* wmp = (unsigned short*)ws;    ws += (size_t)DD * 4 * DD * 2;   // 8MB
  unsigned short* loraP = (unsigned short*)ws;  ws += (size_t)NL * 16384 * 32 * 2;  // 12.6MB

  hipLaunchKernelGGL(embed_cvt_k, dim3(MM * DD / 256 + NL * 16384 * 32 / 256), dim3(256),
                     0, stream, ids, wte, wpe, h,
                     attnla, attnlb, projla, projlb, fcla, fclb, mpla, mplb, loraP);

  for (int l = 0; l < NL; ++l) {
    const float* ab = attnb + (size_t)l * 3 * DD;
    const float* pb = projb + (size_t)l * DD;
    const float* fb = fcb + (size_t)l * 4 * DD;
    const float* mb = mpb + (size_t)l * DD;

    hipLaunchKernelGGL(fold_ln_k, dim3(1536 + MM), dim3(256), 0, stream,
                       attnw + (size_t)l * 3 * DD * DD, projw + (size_t)l * DD * DD,
                       fcw + (size_t)l * 4 * DD * DD, mpw + (size_t)l * DD * 4 * DD,
                       loraP + (size_t)l * 16384 * 32, wqkv, wproj, wfc, wmp,
                       h, ln1w + (size_t)l * DD, ln1b + (size_t)l * DD, x);

    hipLaunchKernelGGL((gemm_t<128, 64, 128, 3>), dim3(3 * DD / 64, MM / 128), dim3(256), 0,
                       stream, x, wqkv, ab, (const float*)nullptr, (float*)nullptr,
                       qkb, vtb, MM, 3 * DD, DD);
    hipLaunchKernelGGL(attn4_k, dim3(TT / 64, NB * NH), dim3(256), 0, stream, qkb, vtb, ho);
    hipLaunchKernelGGL((gemm_t<64, 64, 256, 1>), dim3(DD / 64, MM / 64), dim3(256), 0,
                       stream, ho, wproj, pb, h, h, (unsigned short*)nullptr,
                       (unsigned short*)nullptr, MM, DD, DD);
    hipLaunchKernelGGL(ln_bf_k, dim3(MM), dim3(256), 0, stream, h,
                       ln2w + (size_t)l * DD, ln2b + (size_t)l * DD, x);
    hipLaunchKernelGGL((gemm_t<128, 128, 128, 2>), dim3(4 * DD / 128, MM / 128), dim3(256), 0,
                       stream, x, wfc, fb, (const float*)nullptr, (float*)nullptr, hm,
                       (unsigned short*)nullptr, MM, 4 * DD, DD);
    hipLaunchKernelGGL((gemm_t<64, 64, 256, 1>), dim3(DD / 64, MM / 64), dim3(256), 0,
                       stream, hm, wmp, mb, h, h, (unsigned short*)nullptr,
                       (unsigned short*)nullptr, MM, DD, 4 * DD);
  }

  hipLaunchKernelGGL(ln_f_k, dim3(MM), dim3(256), 0, stream, h, lnfw, lnfb, (float*)d_out);
}